// Round 1
// baseline (6170.290 us; speedup 1.0000x reference)
//
#include <hip/hip_runtime.h>
#include <hip/hip_bf16.h>

// ---------------- problem constants ----------------
constexpr int NN = 100000;   // nodes
constexpr int NE = 1000000;  // edges
constexpr int CH = 64;       // in/hid channels
constexpr int NG = 64;       // graphs
constexpr int PJ = 128;      // projector dim
constexpr float BN_EPS = 1e-5f;

// ws layout (in floats)
constexpr long H1_OFF   = 0;                     // [NN*64] conv1 output (raw, post-max)
constexpr long PART_OFF = 6400000;               // [256*128] BN stat partials
constexpr long SC1_OFF  = PART_OFF + 32768;      // [64]
constexpr long SH1_OFF  = SC1_OFF + 64;          // [64]
constexpr long SC2_OFF  = SH1_OFF + 64;          // [64]
constexpr long SH2_OFF  = SC2_OFF + 64;          // [64]
constexpr long PSUM_OFF = SH2_OFF + 64;          // [64*64] pool mean-sum
constexpr long PMAX_OFF = PSUM_OFF + 4096;       // [64*64] pool max (monotone uint)
constexpr long CNT_OFF  = PMAX_OFF + 4096;       // [64] counts (int)

// d_out layout (floats): z_proj [64*128] | x_node [NN*64] | x_graph [64*128]
constexpr long OUT_XNODE = 8192;
constexpr long OUT_XG    = 8192 + 6400000L;

#define LDS_FENCE() asm volatile("s_waitcnt lgkmcnt(0)" ::: "memory")

__device__ __forceinline__ unsigned fenc(float f) {
    unsigned u = __float_as_uint(f);
    return (u & 0x80000000u) ? ~u : (u | 0x80000000u);
}
__device__ __forceinline__ float fdec(unsigned u) {
    return (u & 0x80000000u) ? __uint_as_float(u & 0x7fffffffu) : __uint_as_float(~u);
}

// ---------------- EdgeConv: wave-per-64-edges, lane-owns-edge ----------------
// x: [NN,64] input features (raw). If NORM, apply y = x*scale + shift on the fly.
// out: [NN,64] pre-zeroed; atomicMax(uint) accumulate of relu(MLP) per dst.
template<bool NORM>
__global__ __launch_bounds__(256) void edgeconv_kernel(
    const float* __restrict__ x,
    const int* __restrict__ src, const int* __restrict__ dst,
    const float* __restrict__ w1, const float* __restrict__ b1,
    const float* __restrict__ w2, const float* __restrict__ b2,
    const float* __restrict__ scale, const float* __restrict__ shift,
    float* __restrict__ out)
{
    __shared__ float mbuf[4][64 * 17];   // per-wave scratch rows, pitch 17 (odd -> conflict-free)
    const int wid  = threadIdx.x >> 6;
    const int lane = threadIdx.x & 63;
    const int tile = blockIdx.x * 4 + wid;
    if (tile >= NE / 64) return;

    const int e = tile * 64 + lane;
    const int s = src[e];
    const int d = dst[e];
    const float4* __restrict__ pi = reinterpret_cast<const float4*>(x + (long)d * 64);
    const float4* __restrict__ pj = reinterpret_cast<const float4*>(x + (long)s * 64);
    float* mrow = &mbuf[wid][lane * 17];

    float acc[64];
    #pragma unroll
    for (int c = 0; c < 64; ++c) acc[c] = b1[c];

    // layer 1: acc[c] += m[k] * w1[k][c], k = 0..127 in 8 chunks of 16
    #pragma unroll 1
    for (int kc = 0; kc < 8; ++kc) {
        float vv[16];
        if (kc < 4) {               // m[k] = n_i[k]
            #pragma unroll
            for (int q = 0; q < 4; ++q) {
                float4 a = pi[kc * 4 + q];
                if (NORM) {
                    const float4 sc = reinterpret_cast<const float4*>(scale)[kc * 4 + q];
                    const float4 sh = reinterpret_cast<const float4*>(shift)[kc * 4 + q];
                    a.x = fmaf(a.x, sc.x, sh.x); a.y = fmaf(a.y, sc.y, sh.y);
                    a.z = fmaf(a.z, sc.z, sh.z); a.w = fmaf(a.w, sc.w, sh.w);
                }
                vv[q * 4 + 0] = a.x; vv[q * 4 + 1] = a.y;
                vv[q * 4 + 2] = a.z; vv[q * 4 + 3] = a.w;
            }
        } else {                    // m[64+k] = n_j[k]-n_i[k] = scale[k]*(x_j-x_i)
            const int kb = kc - 4;
            #pragma unroll
            for (int q = 0; q < 4; ++q) {
                float4 a = pi[kb * 4 + q];
                float4 b = pj[kb * 4 + q];
                float dx = b.x - a.x, dy = b.y - a.y, dz = b.z - a.z, dw = b.w - a.w;
                if (NORM) {
                    const float4 sc = reinterpret_cast<const float4*>(scale)[kb * 4 + q];
                    dx *= sc.x; dy *= sc.y; dz *= sc.z; dw *= sc.w;
                }
                vv[q * 4 + 0] = dx; vv[q * 4 + 1] = dy;
                vv[q * 4 + 2] = dz; vv[q * 4 + 3] = dw;
            }
        }
        #pragma unroll
        for (int j = 0; j < 16; ++j) mrow[j] = vv[j];
        LDS_FENCE();
        #pragma unroll 1
        for (int j = 0; j < 16; ++j) {
            const float mv = mrow[j];                        // lane's own row, conflict-free
            const float* __restrict__ wr = w1 + ((kc << 4) + j) * 64;  // uniform -> s_load
            #pragma unroll
            for (int c = 0; c < 64; ++c) acc[c] = fmaf(mv, wr[c], acc[c]);
        }
        LDS_FENCE();
    }

    // layer 2: acc2[c2] += relu(acc[c]) * w2[c][c2]
    float acc2[64];
    #pragma unroll
    for (int c = 0; c < 64; ++c) acc2[c] = b2[c];
    #pragma unroll
    for (int cc = 0; cc < 4; ++cc) {
        #pragma unroll
        for (int j = 0; j < 16; ++j) mrow[j] = fmaxf(acc[cc * 16 + j], 0.f);
        LDS_FENCE();
        #pragma unroll 1
        for (int j = 0; j < 16; ++j) {
            const float hv = mrow[j];
            const float* __restrict__ wr = w2 + ((cc << 4) + j) * 64;  // uniform -> s_load
            #pragma unroll
            for (int c = 0; c < 64; ++c) acc2[c] = fmaf(hv, wr[c], acc2[c]);
        }
        LDS_FENCE();
    }

    // epilogue: relu + atomic max into dst row (values >= 0, buffer pre-zeroed)
    float* orow = out + (long)d * 64;
    #pragma unroll
    for (int c = 0; c < 64; ++c) {
        const float h2 = fmaxf(acc2[c], 0.f);
        atomicMax(reinterpret_cast<unsigned*>(orow + c), __float_as_uint(h2));
    }
}

// ---------------- BN stats: deterministic two-stage ----------------
__global__ __launch_bounds__(256) void stats_kernel(
    const float* __restrict__ h, float* __restrict__ partial)
{
    __shared__ float red[2][256];
    const int tid = threadIdx.x;
    const int c = tid & 63, r = tid >> 6;
    float s = 0.f, ss = 0.f;
    for (int v = blockIdx.x * 4 + r; v < NN; v += 256 * 4) {
        const float val = h[(long)v * 64 + c];
        s += val; ss += val * val;
    }
    red[0][tid] = s; red[1][tid] = ss;
    __syncthreads();
    if (r == 0) {
        float S = 0.f, SS = 0.f;
        #pragma unroll
        for (int q = 0; q < 4; ++q) { S += red[0][c + q * 64]; SS += red[1][c + q * 64]; }
        partial[blockIdx.x * 128 + c] = S;
        partial[blockIdx.x * 128 + 64 + c] = SS;
    }
}

__global__ void bn_finalize_kernel(
    const float* __restrict__ partial,
    const float* __restrict__ g, const float* __restrict__ b,
    float* __restrict__ scale, float* __restrict__ shift)
{
    const int c = threadIdx.x;   // 64 threads
    float S = 0.f, SS = 0.f;
    for (int bb = 0; bb < 256; ++bb) {
        S += partial[bb * 128 + c];
        SS += partial[bb * 128 + 64 + c];
    }
    const float invN = 1.0f / (float)NN;
    const float mu = S * invN;
    const float var = SS * invN - mu * mu;
    const float sc = g[c] * rsqrtf(var + BN_EPS);
    scale[c] = sc;
    shift[c] = b[c] - mu * sc;
}

// ---------------- node pass: BN2 normalize in place + pooling atomics ----------------
__global__ __launch_bounds__(256) void nodepass_kernel(
    float* __restrict__ xn, const int* __restrict__ batch,
    const float* __restrict__ scale, const float* __restrict__ shift,
    float* __restrict__ poolsum, unsigned* __restrict__ poolmax, int* __restrict__ counts)
{
    const long idx = (long)blockIdx.x * 256 + threadIdx.x;
    const int v = (int)(idx >> 6);
    const int c = (int)(idx & 63);
    const float val = fmaf(xn[idx], scale[c], shift[c]);
    xn[idx] = val;
    const int g = batch[v];
    atomicAdd(poolsum + g * 64 + c, val);
    atomicMax(poolmax + g * 64 + c, fenc(val));
    if (c == 0) atomicAdd(counts + g, 1);
}

// ---------------- final: x_graph + projector MLP + BN + out ----------------
__global__ __launch_bounds__(512) void final_kernel(
    const float* __restrict__ poolsum, const unsigned* __restrict__ poolmax,
    const int* __restrict__ counts,
    const float* __restrict__ p_w1, const float* __restrict__ p_b1,
    const float* __restrict__ p_bng, const float* __restrict__ p_bnb,
    const float* __restrict__ p_w2, const float* __restrict__ p_b2,
    float* __restrict__ out)
{
    __shared__ float xg[64][128];
    __shared__ float znl[64 * 129];
    __shared__ float red[2][512];
    __shared__ float scsh[2][128];
    const int tid = threadIdx.x;

    // phase 1: x_graph = [mean | max], write to out and LDS
    #pragma unroll
    for (int i = 0; i < 16; ++i) {
        const int e2 = tid + i * 512;
        const int g = e2 >> 7, col = e2 & 127;
        float val;
        if (col < 64) {
            const float cnt = fmaxf((float)counts[g], 1.f);
            val = poolsum[g * 64 + col] / cnt;
        } else {
            const unsigned u = poolmax[g * 64 + col - 64];
            val = (u == 0u) ? 0.f : fdec(u);
        }
        xg[g][col] = val;
        out[OUT_XG + e2] = val;
    }
    __syncthreads();

    // phase 2: z = xg @ p_w1 + b1  (thread = (g-group gg, channel t), 16 graphs each)
    const int gg = tid >> 7, t = tid & 127;
    float z[16];
    #pragma unroll
    for (int gi = 0; gi < 16; ++gi) z[gi] = p_b1[t];
    for (int j = 0; j < 128; ++j) {
        const float wv = p_w1[j * 128 + t];
        #pragma unroll
        for (int gi = 0; gi < 16; ++gi) z[gi] = fmaf(xg[gg * 16 + gi][j], wv, z[gi]);
    }

    // BN over 64 graphs per channel t
    float s = 0.f, ss = 0.f;
    #pragma unroll
    for (int gi = 0; gi < 16; ++gi) { s += z[gi]; ss += z[gi] * z[gi]; }
    red[0][tid] = s; red[1][tid] = ss;
    __syncthreads();
    if (gg == 0) {
        float S = 0.f, SS = 0.f;
        #pragma unroll
        for (int q = 0; q < 4; ++q) { S += red[0][t + q * 128]; SS += red[1][t + q * 128]; }
        const float mu = S / 64.f;
        const float var = SS / 64.f - mu * mu;
        const float sc = p_bng[t] * rsqrtf(var + BN_EPS);
        scsh[0][t] = sc;
        scsh[1][t] = p_bnb[t] - mu * sc;
    }
    __syncthreads();
    const float sc = scsh[0][t], sh = scsh[1][t];
    #pragma unroll
    for (int gi = 0; gi < 16; ++gi) {
        const float zn = fmaxf(fmaf(z[gi], sc, sh), 0.f);
        znl[(gg * 16 + gi) * 129 + t] = zn;
    }
    __syncthreads();

    // phase 3: z_proj = zn @ p_w2 + b2
    float zp[16];
    #pragma unroll
    for (int gi = 0; gi < 16; ++gi) zp[gi] = p_b2[t];
    for (int c = 0; c < 128; ++c) {
        const float wv = p_w2[c * 128 + t];
        #pragma unroll
        for (int gi = 0; gi < 16; ++gi) zp[gi] = fmaf(znl[(gg * 16 + gi) * 129 + c], wv, zp[gi]);
    }
    #pragma unroll
    for (int gi = 0; gi < 16; ++gi) out[(gg * 16 + gi) * 128 + t] = zp[gi];
}

// ---------------- launch ----------------
extern "C" void kernel_launch(void* const* d_in, const int* in_sizes, int n_in,
                              void* d_out, int out_size, void* d_ws, size_t ws_size,
                              hipStream_t stream)
{
    const float* x     = (const float*)d_in[0];
    const int*   eidx  = (const int*)d_in[1];
    const int*   batch = (const int*)d_in[2];
    const float* c1w1  = (const float*)d_in[3];
    const float* c1b1  = (const float*)d_in[4];
    const float* c1w2  = (const float*)d_in[5];
    const float* c1b2  = (const float*)d_in[6];
    const float* bn1g  = (const float*)d_in[7];
    const float* bn1b  = (const float*)d_in[8];
    const float* c2w1  = (const float*)d_in[9];
    const float* c2b1  = (const float*)d_in[10];
    const float* c2w2  = (const float*)d_in[11];
    const float* c2b2  = (const float*)d_in[12];
    const float* bn2g  = (const float*)d_in[13];
    const float* bn2b  = (const float*)d_in[14];
    const float* pw1   = (const float*)d_in[15];
    const float* pb1   = (const float*)d_in[16];
    const float* pbng  = (const float*)d_in[17];
    const float* pbnb  = (const float*)d_in[18];
    const float* pw2   = (const float*)d_in[19];
    const float* pb2   = (const float*)d_in[20];

    const int* src = eidx;
    const int* dst = eidx + NE;

    float* ws  = (float*)d_ws;
    float* o   = (float*)d_out;
    float* h1  = ws + H1_OFF;
    float* xnode = o + OUT_XNODE;

    // zero accumulators
    hipMemsetAsync(h1, 0, (size_t)NN * 64 * 4, stream);
    hipMemsetAsync(xnode, 0, (size_t)NN * 64 * 4, stream);
    hipMemsetAsync(ws + PSUM_OFF, 0, (4096 + 4096 + 64) * 4, stream);

    const int convGrid = (NE / 64 + 3) / 4;  // 3907 blocks x 4 waves

    // conv1: x -> h1 (raw post-max)
    edgeconv_kernel<false><<<convGrid, 256, 0, stream>>>(
        x, src, dst, c1w1, c1b1, c1w2, c1b2, nullptr, nullptr, h1);
    // BN1 stats -> scale1/shift1
    stats_kernel<<<256, 256, 0, stream>>>(h1, ws + PART_OFF);
    bn_finalize_kernel<<<1, 64, 0, stream>>>(ws + PART_OFF, bn1g, bn1b,
                                             ws + SC1_OFF, ws + SH1_OFF);
    // conv2: norm(h1) -> xnode (raw post-max)
    edgeconv_kernel<true><<<convGrid, 256, 0, stream>>>(
        h1, src, dst, c2w1, c2b1, c2w2, c2b2, ws + SC1_OFF, ws + SH1_OFF, xnode);
    // BN2 stats -> scale2/shift2
    stats_kernel<<<256, 256, 0, stream>>>(xnode, ws + PART_OFF);
    bn_finalize_kernel<<<1, 64, 0, stream>>>(ws + PART_OFF, bn2g, bn2b,
                                             ws + SC2_OFF, ws + SH2_OFF);
    // normalize x_node in place + pooling
    nodepass_kernel<<<(NN * 64) / 256, 256, 0, stream>>>(
        xnode, batch, ws + SC2_OFF, ws + SH2_OFF,
        ws + PSUM_OFF, (unsigned*)(ws + PMAX_OFF), (int*)(ws + CNT_OFF));
    // x_graph + projector
    final_kernel<<<1, 512, 0, stream>>>(
        ws + PSUM_OFF, (unsigned*)(ws + PMAX_OFF), (int*)(ws + CNT_OFF),
        pw1, pb1, pbng, pbnb, pw2, pb2, o);
}

// Round 2
// 1811.523 us; speedup vs baseline: 3.4061x; 3.4061x over previous
//
#include <hip/hip_runtime.h>
#include <hip/hip_bf16.h>

// ---------------- problem constants ----------------
constexpr int NN = 100000;   // nodes
constexpr int NE = 1000000;  // edges
constexpr int NG = 64;       // graphs
constexpr float BN_EPS = 1e-5f;

// ws layout (in floats)
constexpr long H1_OFF   = 0;                     // [NN*64] conv1 output (raw, post-max)
constexpr long PART_OFF = 6400000;               // [256*128] BN stat partials
constexpr long SC1_OFF  = PART_OFF + 32768;      // [64]
constexpr long SH1_OFF  = SC1_OFF + 64;          // [64]
constexpr long SC2_OFF  = SH1_OFF + 64;          // [64]
constexpr long SH2_OFF  = SC2_OFF + 64;          // [64]
constexpr long PSUM_OFF = SH2_OFF + 64;          // [64*64] pool mean-sum
constexpr long PMAX_OFF = PSUM_OFF + 4096;       // [64*64] pool max (monotone uint)
constexpr long CNT_OFF  = PMAX_OFF + 4096;       // [64] counts (int)
constexpr long SCNT_OFF = CNT_OFF + 64;          // [100000] sort counts (int)
constexpr long CURS_OFF = SCNT_OFF + 100000;     // [100000] sort cursors (int)
constexpr long EORD_OFF = CURS_OFF + 100000;     // [1000000] edge ids sorted by dst (int)

// d_out layout (floats): z_proj [64*128] | x_node [NN*64] | x_graph [64*128]
constexpr long OUT_XNODE = 8192;
constexpr long OUT_XG    = 8192 + 6400000L;

#define LDS_FENCE() asm volatile("s_waitcnt lgkmcnt(0)" ::: "memory")

__device__ __forceinline__ unsigned fenc(float f) {
    unsigned u = __float_as_uint(f);
    return (u & 0x80000000u) ? ~u : (u | 0x80000000u);
}
__device__ __forceinline__ float fdec(unsigned u) {
    return (u & 0x80000000u) ? __uint_as_float(u & 0x7fffffffu) : __uint_as_float(~u);
}

// ---------------- counting sort of edges by dst ----------------
__global__ __launch_bounds__(256) void count_kernel(
    const int* __restrict__ dst, int* __restrict__ cnt)
{
    const int e = blockIdx.x * 256 + threadIdx.x;
    if (e < NE) atomicAdd(cnt + dst[e], 1);
}

__global__ __launch_bounds__(1024) void scan_kernel(
    const int* __restrict__ cnt, int* __restrict__ cursor)
{
    __shared__ int part[1024];
    const int t = threadIdx.x;
    const int CHUNK = 98;  // 1024*98 = 100352 >= NN
    const int base = t * CHUNK;
    int s = 0;
    for (int i = 0; i < CHUNK; ++i) {
        const int v = base + i;
        if (v < NN) s += cnt[v];
    }
    part[t] = s;
    __syncthreads();
    for (int off = 1; off < 1024; off <<= 1) {
        const int v = (t >= off) ? part[t - off] : 0;
        __syncthreads();
        part[t] += v;
        __syncthreads();
    }
    int run = (t == 0) ? 0 : part[t - 1];
    for (int i = 0; i < CHUNK; ++i) {
        const int v = base + i;
        if (v < NN) { cursor[v] = run; run += cnt[v]; }
    }
}

__global__ __launch_bounds__(256) void scatter_kernel(
    const int* __restrict__ dst, int* __restrict__ cursor, int* __restrict__ eord)
{
    const int e = blockIdx.x * 256 + threadIdx.x;
    if (e < NE) {
        const int pos = atomicAdd(cursor + dst[e], 1);
        eord[pos] = e;
    }
}

// ---------------- EdgeConv: wave-per-64-edges (sorted by dst), lane-owns-edge --------
// x: [NN,64] input features (raw). If NORM, apply y = x*scale + shift on the fly.
// out: [NN,64] pre-zeroed; segmented in-wave max, then leader-lane atomicMax(uint).
template<bool NORM>
__global__ __launch_bounds__(256) void edgeconv_kernel(
    const float* __restrict__ x, const int* __restrict__ eord,
    const int* __restrict__ src, const int* __restrict__ dst,
    const float* __restrict__ w1, const float* __restrict__ b1,
    const float* __restrict__ w2, const float* __restrict__ b2,
    const float* __restrict__ scale, const float* __restrict__ shift,
    float* __restrict__ out)
{
    __shared__ float mbuf[4][64 * 17];   // per-wave scratch rows, pitch 17 (odd -> conflict-free)
    const int wid  = threadIdx.x >> 6;
    const int lane = threadIdx.x & 63;
    const int tile = blockIdx.x * 4 + wid;
    if (tile >= NE / 64) return;

    const int e = eord[tile * 64 + lane];
    const int s = src[e];
    const int d = dst[e];
    const float4* __restrict__ pi = reinterpret_cast<const float4*>(x + (long)d * 64);
    const float4* __restrict__ pj = reinterpret_cast<const float4*>(x + (long)s * 64);
    float* mrow = &mbuf[wid][lane * 17];

    float acc[64];
    #pragma unroll
    for (int c = 0; c < 64; ++c) acc[c] = b1[c];

    // layer 1: acc[c] += m[k] * w1[k][c], k = 0..127 in 8 chunks of 16
    #pragma unroll 1
    for (int kc = 0; kc < 8; ++kc) {
        float vv[16];
        if (kc < 4) {               // m[k] = n_i[k]
            #pragma unroll
            for (int q = 0; q < 4; ++q) {
                float4 a = pi[kc * 4 + q];
                if (NORM) {
                    const float4 sc = reinterpret_cast<const float4*>(scale)[kc * 4 + q];
                    const float4 sh = reinterpret_cast<const float4*>(shift)[kc * 4 + q];
                    a.x = fmaf(a.x, sc.x, sh.x); a.y = fmaf(a.y, sc.y, sh.y);
                    a.z = fmaf(a.z, sc.z, sh.z); a.w = fmaf(a.w, sc.w, sh.w);
                }
                vv[q * 4 + 0] = a.x; vv[q * 4 + 1] = a.y;
                vv[q * 4 + 2] = a.z; vv[q * 4 + 3] = a.w;
            }
        } else {                    // m[64+k] = n_j[k]-n_i[k] = scale[k]*(x_j-x_i)
            const int kb = kc - 4;
            #pragma unroll
            for (int q = 0; q < 4; ++q) {
                float4 a = pi[kb * 4 + q];
                float4 b = pj[kb * 4 + q];
                float dx = b.x - a.x, dy = b.y - a.y, dz = b.z - a.z, dw = b.w - a.w;
                if (NORM) {
                    const float4 sc = reinterpret_cast<const float4*>(scale)[kb * 4 + q];
                    dx *= sc.x; dy *= sc.y; dz *= sc.z; dw *= sc.w;
                }
                vv[q * 4 + 0] = dx; vv[q * 4 + 1] = dy;
                vv[q * 4 + 2] = dz; vv[q * 4 + 3] = dw;
            }
        }
        #pragma unroll
        for (int j = 0; j < 16; ++j) mrow[j] = vv[j];
        LDS_FENCE();
        #pragma unroll 1
        for (int j = 0; j < 16; ++j) {
            const float mv = mrow[j];                        // lane's own row, conflict-free
            const float* __restrict__ wr = w1 + ((kc << 4) + j) * 64;  // uniform -> s_load
            #pragma unroll
            for (int c = 0; c < 64; ++c) acc[c] = fmaf(mv, wr[c], acc[c]);
        }
        LDS_FENCE();
    }

    // layer 2: acc2[c2] += relu(acc[c]) * w2[c][c2]
    float acc2[64];
    #pragma unroll
    for (int c = 0; c < 64; ++c) acc2[c] = b2[c];
    #pragma unroll
    for (int cc = 0; cc < 4; ++cc) {
        #pragma unroll
        for (int j = 0; j < 16; ++j) mrow[j] = fmaxf(acc[cc * 16 + j], 0.f);
        LDS_FENCE();
        #pragma unroll 1
        for (int j = 0; j < 16; ++j) {
            const float hv = mrow[j];
            const float* __restrict__ wr = w2 + ((cc << 4) + j) * 64;  // uniform -> s_load
            #pragma unroll
            for (int c = 0; c < 64; ++c) acc2[c] = fmaf(hv, wr[c], acc2[c]);
        }
        LDS_FENCE();
    }

    // final relu
    #pragma unroll
    for (int c = 0; c < 64; ++c) acc2[c] = fmaxf(acc2[c], 0.f);

    // segmented max across lanes (edges sorted by dst -> equal keys contiguous)
    #pragma unroll
    for (int s2 = 1; s2 < 64; s2 <<= 1) {
        const int dn = __shfl_down(d, s2);
        const bool take = ((lane + s2) < 64) && (dn == d);
        #pragma unroll
        for (int c = 0; c < 64; ++c) {
            const float o = __shfl_down(acc2[c], s2);
            acc2[c] = take ? fmaxf(acc2[c], o) : acc2[c];
        }
    }

    // leader lanes flush: one atomic row per distinct dst in this wave
    const int dprev = __shfl_up(d, 1);
    const bool leader = (lane == 0) || (dprev != d);
    if (leader) {
        float* orow = out + (long)d * 64;
        #pragma unroll
        for (int c = 0; c < 64; ++c) {
            atomicMax(reinterpret_cast<unsigned*>(orow + c), __float_as_uint(acc2[c]));
        }
    }
}

// ---------------- BN stats: deterministic two-stage ----------------
__global__ __launch_bounds__(256) void stats_kernel(
    const float* __restrict__ h, float* __restrict__ partial)
{
    __shared__ float red[2][256];
    const int tid = threadIdx.x;
    const int c = tid & 63, r = tid >> 6;
    float s = 0.f, ss = 0.f;
    for (int v = blockIdx.x * 4 + r; v < NN; v += 256 * 4) {
        const float val = h[(long)v * 64 + c];
        s += val; ss += val * val;
    }
    red[0][tid] = s; red[1][tid] = ss;
    __syncthreads();
    if (r == 0) {
        float S = 0.f, SS = 0.f;
        #pragma unroll
        for (int q = 0; q < 4; ++q) { S += red[0][c + q * 64]; SS += red[1][c + q * 64]; }
        partial[blockIdx.x * 128 + c] = S;
        partial[blockIdx.x * 128 + 64 + c] = SS;
    }
}

__global__ void bn_finalize_kernel(
    const float* __restrict__ partial,
    const float* __restrict__ g, const float* __restrict__ b,
    float* __restrict__ scale, float* __restrict__ shift)
{
    const int c = threadIdx.x;   // 64 threads
    float S = 0.f, SS = 0.f;
    for (int bb = 0; bb < 256; ++bb) {
        S += partial[bb * 128 + c];
        SS += partial[bb * 128 + 64 + c];
    }
    const float invN = 1.0f / (float)NN;
    const float mu = S * invN;
    const float var = SS * invN - mu * mu;
    const float sc = g[c] * rsqrtf(var + BN_EPS);
    scale[c] = sc;
    shift[c] = b[c] - mu * sc;
}

// ---------------- node pass: BN2 normalize in place + segmented pooling ----------------
// batch is sorted -> per-thread running (sum,max,count), flush per graph boundary.
constexpr int NPB = 512;  // nodes per block
__global__ __launch_bounds__(256) void nodepass_kernel(
    float* __restrict__ xn, const int* __restrict__ batch,
    const float* __restrict__ scale, const float* __restrict__ shift,
    float* __restrict__ poolsum, unsigned* __restrict__ poolmax, int* __restrict__ counts)
{
    const int base = blockIdx.x * NPB;
    const int r = threadIdx.x >> 6, c = threadIdx.x & 63;
    int curg = -1; float rs = 0.f, rm = -INFINITY; int rc = 0;
    const int vend = (base + NPB < NN) ? base + NPB : NN;
    for (int v = base + r; v < vend; v += 4) {
        const long idx = (long)v * 64 + c;
        const float val = fmaf(xn[idx], scale[c], shift[c]);
        xn[idx] = val;
        const int g = batch[v];   // wave-uniform
        if (g != curg) {
            if (curg >= 0) {
                atomicAdd(poolsum + curg * 64 + c, rs);
                atomicMax(poolmax + curg * 64 + c, fenc(rm));
                if (c == 0) atomicAdd(counts + curg, rc);
            }
            curg = g; rs = 0.f; rm = -INFINITY; rc = 0;
        }
        rs += val; rm = fmaxf(rm, val); ++rc;
    }
    if (curg >= 0) {
        atomicAdd(poolsum + curg * 64 + c, rs);
        atomicMax(poolmax + curg * 64 + c, fenc(rm));
        if (c == 0) atomicAdd(counts + curg, rc);
    }
}

// ---------------- final: x_graph + projector MLP + BN + out ----------------
__global__ __launch_bounds__(512) void final_kernel(
    const float* __restrict__ poolsum, const unsigned* __restrict__ poolmax,
    const int* __restrict__ counts,
    const float* __restrict__ p_w1, const float* __restrict__ p_b1,
    const float* __restrict__ p_bng, const float* __restrict__ p_bnb,
    const float* __restrict__ p_w2, const float* __restrict__ p_b2,
    float* __restrict__ out)
{
    __shared__ float xg[64][128];
    __shared__ float znl[64 * 129];
    __shared__ float red[2][512];
    __shared__ float scsh[2][128];
    const int tid = threadIdx.x;

    // phase 1: x_graph = [mean | max], write to out and LDS
    #pragma unroll
    for (int i = 0; i < 16; ++i) {
        const int e2 = tid + i * 512;
        const int g = e2 >> 7, col = e2 & 127;
        float val;
        if (col < 64) {
            const float cnt = fmaxf((float)counts[g], 1.f);
            val = poolsum[g * 64 + col] / cnt;
        } else {
            const unsigned u = poolmax[g * 64 + col - 64];
            val = (u == 0u) ? 0.f : fdec(u);
        }
        xg[g][col] = val;
        out[OUT_XG + e2] = val;
    }
    __syncthreads();

    // phase 2: z = xg @ p_w1 + b1  (thread = (g-group gg, channel t), 16 graphs each)
    const int gg = tid >> 7, t = tid & 127;
    float z[16];
    #pragma unroll
    for (int gi = 0; gi < 16; ++gi) z[gi] = p_b1[t];
    for (int j = 0; j < 128; ++j) {
        const float wv = p_w1[j * 128 + t];
        #pragma unroll
        for (int gi = 0; gi < 16; ++gi) z[gi] = fmaf(xg[gg * 16 + gi][j], wv, z[gi]);
    }

    // BN over 64 graphs per channel t
    float s = 0.f, ss = 0.f;
    #pragma unroll
    for (int gi = 0; gi < 16; ++gi) { s += z[gi]; ss += z[gi] * z[gi]; }
    red[0][tid] = s; red[1][tid] = ss;
    __syncthreads();
    if (gg == 0) {
        float S = 0.f, SS = 0.f;
        #pragma unroll
        for (int q = 0; q < 4; ++q) { S += red[0][t + q * 128]; SS += red[1][t + q * 128]; }
        const float mu = S / 64.f;
        const float var = SS / 64.f - mu * mu;
        const float sc = p_bng[t] * rsqrtf(var + BN_EPS);
        scsh[0][t] = sc;
        scsh[1][t] = p_bnb[t] - mu * sc;
    }
    __syncthreads();
    const float sc = scsh[0][t], sh = scsh[1][t];
    #pragma unroll
    for (int gi = 0; gi < 16; ++gi) {
        const float zn = fmaxf(fmaf(z[gi], sc, sh), 0.f);
        znl[(gg * 16 + gi) * 129 + t] = zn;
    }
    __syncthreads();

    // phase 3: z_proj = zn @ p_w2 + b2
    float zp[16];
    #pragma unroll
    for (int gi = 0; gi < 16; ++gi) zp[gi] = p_b2[t];
    for (int c = 0; c < 128; ++c) {
        const float wv = p_w2[c * 128 + t];
        #pragma unroll
        for (int gi = 0; gi < 16; ++gi) zp[gi] = fmaf(znl[(gg * 16 + gi) * 129 + c], wv, zp[gi]);
    }
    #pragma unroll
    for (int gi = 0; gi < 16; ++gi) out[(gg * 16 + gi) * 128 + t] = zp[gi];
}

// ---------------- launch ----------------
extern "C" void kernel_launch(void* const* d_in, const int* in_sizes, int n_in,
                              void* d_out, int out_size, void* d_ws, size_t ws_size,
                              hipStream_t stream)
{
    const float* x     = (const float*)d_in[0];
    const int*   eidx  = (const int*)d_in[1];
    const int*   batch = (const int*)d_in[2];
    const float* c1w1  = (const float*)d_in[3];
    const float* c1b1  = (const float*)d_in[4];
    const float* c1w2  = (const float*)d_in[5];
    const float* c1b2  = (const float*)d_in[6];
    const float* bn1g  = (const float*)d_in[7];
    const float* bn1b  = (const float*)d_in[8];
    const float* c2w1  = (const float*)d_in[9];
    const float* c2b1  = (const float*)d_in[10];
    const float* c2w2  = (const float*)d_in[11];
    const float* c2b2  = (const float*)d_in[12];
    const float* bn2g  = (const float*)d_in[13];
    const float* bn2b  = (const float*)d_in[14];
    const float* pw1   = (const float*)d_in[15];
    const float* pb1   = (const float*)d_in[16];
    const float* pbng  = (const float*)d_in[17];
    const float* pbnb  = (const float*)d_in[18];
    const float* pw2   = (const float*)d_in[19];
    const float* pb2   = (const float*)d_in[20];

    const int* src = eidx;
    const int* dst = eidx + NE;

    float* ws  = (float*)d_ws;
    float* o   = (float*)d_out;
    float* h1  = ws + H1_OFF;
    float* xnode = o + OUT_XNODE;
    int* scnt  = (int*)(ws + SCNT_OFF);
    int* curs  = (int*)(ws + CURS_OFF);
    int* eord  = (int*)(ws + EORD_OFF);

    // zero accumulators
    hipMemsetAsync(h1, 0, (size_t)NN * 64 * 4, stream);
    hipMemsetAsync(xnode, 0, (size_t)NN * 64 * 4, stream);
    hipMemsetAsync(ws + PSUM_OFF, 0, (4096 + 4096 + 64) * 4, stream);
    hipMemsetAsync(scnt, 0, (size_t)NN * 4, stream);

    // counting sort of edges by dst (amortized over both convs)
    const int eGrid = (NE + 255) / 256;
    count_kernel<<<eGrid, 256, 0, stream>>>(dst, scnt);
    scan_kernel<<<1, 1024, 0, stream>>>(scnt, curs);
    scatter_kernel<<<eGrid, 256, 0, stream>>>(dst, curs, eord);

    const int convGrid = (NE / 64 + 3) / 4;  // 3907 blocks x 4 waves

    // conv1: x -> h1 (raw post-max)
    edgeconv_kernel<false><<<convGrid, 256, 0, stream>>>(
        x, eord, src, dst, c1w1, c1b1, c1w2, c1b2, nullptr, nullptr, h1);
    // BN1 stats -> scale1/shift1
    stats_kernel<<<256, 256, 0, stream>>>(h1, ws + PART_OFF);
    bn_finalize_kernel<<<1, 64, 0, stream>>>(ws + PART_OFF, bn1g, bn1b,
                                             ws + SC1_OFF, ws + SH1_OFF);
    // conv2: norm(h1) -> xnode (raw post-max)
    edgeconv_kernel<true><<<convGrid, 256, 0, stream>>>(
        h1, eord, src, dst, c2w1, c2b1, c2w2, c2b2, ws + SC1_OFF, ws + SH1_OFF, xnode);
    // BN2 stats -> scale2/shift2
    stats_kernel<<<256, 256, 0, stream>>>(xnode, ws + PART_OFF);
    bn_finalize_kernel<<<1, 64, 0, stream>>>(ws + PART_OFF, bn2g, bn2b,
                                             ws + SC2_OFF, ws + SH2_OFF);
    // normalize x_node in place + segmented pooling
    nodepass_kernel<<<(NN + NPB - 1) / NPB, 256, 0, stream>>>(
        xnode, batch, ws + SC2_OFF, ws + SH2_OFF,
        ws + PSUM_OFF, (unsigned*)(ws + PMAX_OFF), (int*)(ws + CNT_OFF));
    // x_graph + projector
    final_kernel<<<1, 512, 0, stream>>>(
        ws + PSUM_OFF, (unsigned*)(ws + PMAX_OFF), (int*)(ws + CNT_OFF),
        pw1, pb1, pbng, pbnb, pw2, pb2, o);
}

// Round 3
// 722.363 us; speedup vs baseline: 8.5418x; 2.5078x over previous
//
#include <hip/hip_runtime.h>
#include <hip/hip_bf16.h>

// ---------------- problem constants ----------------
constexpr int NN = 100000;   // nodes
constexpr int NE = 1000000;  // edges
constexpr int NG = 64;       // graphs
constexpr float BN_EPS = 1e-5f;
constexpr int NTILES = NE / 32;      // 31250 wave-tiles of 32 edges
constexpr int NREC = NTILES * 2;     // 62500 boundary records

// ws layout (in floats)
constexpr long H1_OFF   = 0;                       // [NN*64] conv1 output (raw)
constexpr long PART_OFF = 6400000;                 // [256*128] BN stat partials
constexpr long SC1_OFF  = PART_OFF + 32768;        // [64]
constexpr long SH1_OFF  = SC1_OFF + 64;
constexpr long SC2_OFF  = SH1_OFF + 64;
constexpr long SH2_OFF  = SC2_OFF + 64;
constexpr long PSUM_OFF = SH2_OFF + 64;            // [64*64]
constexpr long PMAX_OFF = PSUM_OFF + 4096;         // [64*64]
constexpr long CNT_OFF  = PMAX_OFF + 4096;         // [64]
constexpr long SCNT_OFF = CNT_OFF + 64;            // [100000] sort counts
constexpr long CURS_OFF = SCNT_OFF + 100000;       // [100000] sort cursors
constexpr long EORD_OFF = CURS_OFF + 100000;       // [1000000] sorted edge ids
constexpr long WF1_OFF  = EORD_OFF + 1000000;      // 12288 u16 (6144 float slots)
constexpr long WF2_OFF  = WF1_OFF + 6144;          // 12288 u16
constexpr long RECD_OFF = WF2_OFF + 6144;          // [62500] record dst (int), pad->62528
constexpr long RECV_OFF = RECD_OFF + 62528;        // [62500*64] record values

// d_out layout (floats): z_proj [64*128] | x_node [NN*64] | x_graph [64*128]
constexpr long OUT_XNODE = 8192;
constexpr long OUT_XG    = 8192 + 6400000L;

#define LDS_FENCE() asm volatile("s_waitcnt lgkmcnt(0)" ::: "memory")

using bf16x8 = __attribute__((ext_vector_type(8))) short;
using f32x16 = __attribute__((ext_vector_type(16))) float;

__device__ __forceinline__ unsigned short f2bf(float f) {
    return __builtin_bit_cast(unsigned short, __float2bfloat16(f));
}
__device__ __forceinline__ unsigned fenc(float f) {
    unsigned u = __float_as_uint(f);
    return (u & 0x80000000u) ? ~u : (u | 0x80000000u);
}
__device__ __forceinline__ float fdec(unsigned u) {
    return (u & 0x80000000u) ? __uint_as_float(u & 0x7fffffffu) : __uint_as_float(~u);
}

// ---------------- counting sort of edges by dst ----------------
__global__ __launch_bounds__(256) void count_kernel(
    const int* __restrict__ dst, int* __restrict__ cnt)
{
    const int e = blockIdx.x * 256 + threadIdx.x;
    if (e < NE) atomicAdd(cnt + dst[e], 1);
}

__global__ __launch_bounds__(1024) void scan_kernel(
    const int* __restrict__ cnt, int* __restrict__ cursor)
{
    __shared__ int part[1024];
    const int t = threadIdx.x;
    const int CHUNK = 98;  // 1024*98 >= NN
    const int base = t * CHUNK;
    int s = 0;
    for (int i = 0; i < CHUNK; ++i) {
        const int v = base + i;
        if (v < NN) s += cnt[v];
    }
    part[t] = s;
    __syncthreads();
    for (int off = 1; off < 1024; off <<= 1) {
        const int v = (t >= off) ? part[t - off] : 0;
        __syncthreads();
        part[t] += v;
        __syncthreads();
    }
    int run = (t == 0) ? 0 : part[t - 1];
    for (int i = 0; i < CHUNK; ++i) {
        const int v = base + i;
        if (v < NN) { cursor[v] = run; run += cnt[v]; }
    }
}

__global__ __launch_bounds__(256) void scatter_kernel(
    const int* __restrict__ dst, int* __restrict__ cursor, int* __restrict__ eord)
{
    const int e = blockIdx.x * 256 + threadIdx.x;
    if (e < NE) {
        const int pos = atomicAdd(cursor + dst[e], 1);
        eord[pos] = e;
    }
}

// ---------------- weight prep: f32 [K][C] -> fragment-ordered bf16 ----------------
// w1 frags: f = t*8+ks (16 frags), elem = f*512 + lane*8 + i
//   value = w1[(ks*16 + (lane>>5)*8 + i) * 64 + t*32 + (lane&31)]
// w2 frags: f = t*4+ks (8 frags), at offset 8192
__global__ __launch_bounds__(256) void prep_weights(
    const float* __restrict__ w1, const float* __restrict__ w2,
    unsigned short* __restrict__ wf)
{
    const int idx = blockIdx.x * 256 + threadIdx.x;
    if (idx >= 12288) return;
    if (idx < 8192) {
        const int f = idx >> 9, rem = idx & 511, ln = rem >> 3, i = rem & 7;
        const int t = f >> 3, ks = f & 7;
        const int k = ks * 16 + (ln >> 5) * 8 + i, c = t * 32 + (ln & 31);
        wf[idx] = f2bf(w1[k * 64 + c]);
    } else {
        const int j = idx - 8192;
        const int f = j >> 9, rem = j & 511, ln = rem >> 3, i = rem & 7;
        const int t = f >> 2, ks = f & 3;
        const int k = ks * 16 + (ln >> 5) * 8 + i, c = t * 32 + (ln & 31);
        wf[idx] = f2bf(w2[k * 64 + c]);
    }
}

// ---------------- EdgeConv via MFMA: wave = 32 sorted edges ----------------
// Swapped GEMM: C[c][edge] = sum_k W[k][c] * M[k][edge]; C col=lane&31=edge,
// row = (reg&3)+8*(reg>>2)+4*(lane>>5). Atomic-free output: interior segments
// plain-stored, boundary segments -> dense records, fixup kernel combines.
template<bool NORM>
__global__ __launch_bounds__(256) void edgeconv_kernel(
    const float* __restrict__ x, const int* __restrict__ eord,
    const int* __restrict__ src, const int* __restrict__ dst,
    const unsigned short* __restrict__ wfrag,
    const float* __restrict__ b1, const float* __restrict__ b2,
    const float* __restrict__ scale, const float* __restrict__ shift,
    float* __restrict__ out, int* __restrict__ recd, float* __restrict__ recv)
{
    __shared__ unsigned short wlds[12288];       // 24 KB fragment-ordered weights
    __shared__ unsigned short hlds[4][2048];     // 4 KB per wave: h (bf16, swizzled)

    // stage weights (all threads, before any early-out)
    {
        const uint4* wsrc = reinterpret_cast<const uint4*>(wfrag);
        uint4* wdst = reinterpret_cast<uint4*>(wlds);
        #pragma unroll
        for (int i = 0; i < 6; ++i) wdst[threadIdx.x + i * 256] = wsrc[threadIdx.x + i * 256];
    }
    __syncthreads();

    const int wid  = threadIdx.x >> 6;
    const int lane = threadIdx.x & 63;
    const int hi   = lane >> 5;
    const int ln32 = lane & 31;
    const int tile = blockIdx.x * 4 + wid;
    if (tile >= NTILES) return;

    const int e = eord[tile * 32 + ln32];
    const int s = src[e];
    const int d = dst[e];
    const float* __restrict__ xip = x + (long)d * 64;
    const float* __restrict__ xjp = x + (long)s * 64;

    // preload xi half (this lane's 32 channels), normalized if NORM
    float4 xin[8];
    #pragma unroll
    for (int ks = 0; ks < 4; ++ks) {
        #pragma unroll
        for (int q = 0; q < 2; ++q) {
            const int off = ks * 16 + hi * 8 + q * 4;
            float4 a = *reinterpret_cast<const float4*>(xip + off);
            if (NORM) {
                const float4 sc = *reinterpret_cast<const float4*>(scale + off);
                const float4 sh = *reinterpret_cast<const float4*>(shift + off);
                a.x = fmaf(a.x, sc.x, sh.x); a.y = fmaf(a.y, sc.y, sh.y);
                a.z = fmaf(a.z, sc.z, sh.z); a.w = fmaf(a.w, sc.w, sh.w);
            }
            xin[ks * 2 + q] = a;
        }
    }

    // layer-1 accumulators, bias-initialized (C row = (r&3)+8*(r>>2)+4*hi)
    f32x16 c1a, c1b;
    #pragma unroll
    for (int r = 0; r < 16; ++r) {
        const int row = (r & 3) + 8 * (r >> 2) + 4 * hi;
        c1a[r] = b1[row];
        c1b[r] = b1[32 + row];
    }

    // layer 1: K=128 in 8 ksteps
    #pragma unroll
    for (int ks = 0; ks < 8; ++ks) {
        bf16x8 bfr;
        if (ks < 4) {
            const float4 a0 = xin[ks * 2], a1 = xin[ks * 2 + 1];
            bfr[0] = (short)f2bf(a0.x); bfr[1] = (short)f2bf(a0.y);
            bfr[2] = (short)f2bf(a0.z); bfr[3] = (short)f2bf(a0.w);
            bfr[4] = (short)f2bf(a1.x); bfr[5] = (short)f2bf(a1.y);
            bfr[6] = (short)f2bf(a1.z); bfr[7] = (short)f2bf(a1.w);
        } else {
            const int kb = ks - 4;
            const int off = kb * 16 + hi * 8;
            float4 xa = *reinterpret_cast<const float4*>(xjp + off);
            float4 xb = *reinterpret_cast<const float4*>(xjp + off + 4);
            if (NORM) {
                const float4 s0 = *reinterpret_cast<const float4*>(scale + off);
                const float4 s1 = *reinterpret_cast<const float4*>(scale + off + 4);
                const float4 h0 = *reinterpret_cast<const float4*>(shift + off);
                const float4 h1 = *reinterpret_cast<const float4*>(shift + off + 4);
                xa.x = fmaf(xa.x, s0.x, h0.x); xa.y = fmaf(xa.y, s0.y, h0.y);
                xa.z = fmaf(xa.z, s0.z, h0.z); xa.w = fmaf(xa.w, s0.w, h0.w);
                xb.x = fmaf(xb.x, s1.x, h1.x); xb.y = fmaf(xb.y, s1.y, h1.y);
                xb.z = fmaf(xb.z, s1.z, h1.z); xb.w = fmaf(xb.w, s1.w, h1.w);
            }
            const float4 i0 = xin[kb * 2], i1 = xin[kb * 2 + 1];
            bfr[0] = (short)f2bf(xa.x - i0.x); bfr[1] = (short)f2bf(xa.y - i0.y);
            bfr[2] = (short)f2bf(xa.z - i0.z); bfr[3] = (short)f2bf(xa.w - i0.w);
            bfr[4] = (short)f2bf(xb.x - i1.x); bfr[5] = (short)f2bf(xb.y - i1.y);
            bfr[6] = (short)f2bf(xb.z - i1.z); bfr[7] = (short)f2bf(xb.w - i1.w);
        }
        const bf16x8 a0 = *reinterpret_cast<const bf16x8*>(&wlds[(0 * 8 + ks) * 512 + lane * 8]);
        const bf16x8 a1 = *reinterpret_cast<const bf16x8*>(&wlds[(1 * 8 + ks) * 512 + lane * 8]);
        c1a = __builtin_amdgcn_mfma_f32_32x32x16_bf16(a0, bfr, c1a, 0, 0, 0);
        c1b = __builtin_amdgcn_mfma_f32_32x32x16_bf16(a1, bfr, c1b, 0, 0, 0);
    }

    // h = relu(c1) -> bf16 -> hlds[edge][channel] with XOR swizzle
    {
        char* hl = reinterpret_cast<char*>(&hlds[wid][0]);
        #pragma unroll
        for (int t = 0; t < 2; ++t) {
            const f32x16 c = t ? c1b : c1a;
            #pragma unroll
            for (int q = 0; q < 4; ++q) {
                const float h0 = fmaxf(c[4 * q + 0], 0.f);
                const float h1 = fmaxf(c[4 * q + 1], 0.f);
                const float h2 = fmaxf(c[4 * q + 2], 0.f);
                const float h3 = fmaxf(c[4 * q + 3], 0.f);
                uint2 pk;
                pk.x = (unsigned)f2bf(h0) | ((unsigned)f2bf(h1) << 16);
                pk.y = (unsigned)f2bf(h2) | ((unsigned)f2bf(h3) << 16);
                unsigned boff = (unsigned)(ln32 * 128 + (t * 32 + 8 * q + 4 * hi) * 2);
                boff ^= (unsigned)((ln32 & 7) << 4);
                *reinterpret_cast<uint2*>(hl + boff) = pk;
            }
        }
    }
    LDS_FENCE();

    // layer 2: K=64 in 4 ksteps
    f32x16 c2a, c2b;
    #pragma unroll
    for (int r = 0; r < 16; ++r) {
        const int row = (r & 3) + 8 * (r >> 2) + 4 * hi;
        c2a[r] = b2[row];
        c2b[r] = b2[32 + row];
    }
    {
        const char* hl = reinterpret_cast<const char*>(&hlds[wid][0]);
        #pragma unroll
        for (int ks = 0; ks < 4; ++ks) {
            unsigned boff = (unsigned)(ln32 * 128 + ks * 32 + hi * 16);
            boff ^= (unsigned)((ln32 & 7) << 4);
            const bf16x8 b2f = *reinterpret_cast<const bf16x8*>(hl + boff);
            const bf16x8 a0 = *reinterpret_cast<const bf16x8*>(&wlds[8192 + (0 * 4 + ks) * 512 + lane * 8]);
            const bf16x8 a1 = *reinterpret_cast<const bf16x8*>(&wlds[8192 + (1 * 4 + ks) * 512 + lane * 8]);
            c2a = __builtin_amdgcn_mfma_f32_32x32x16_bf16(a0, b2f, c2a, 0, 0, 0);
            c2b = __builtin_amdgcn_mfma_f32_32x32x16_bf16(a1, b2f, c2b, 0, 0, 0);
        }
    }

    // relu
    #pragma unroll
    for (int r = 0; r < 16; ++r) {
        c2a[r] = fmaxf(c2a[r], 0.f);
        c2b[r] = fmaxf(c2b[r], 0.f);
    }

    // segmented max over edges within each 32-lane half (keys = d, sorted)
    #pragma unroll
    for (int st = 1; st < 32; st <<= 1) {
        const int dn = __shfl_down(d, st, 32);
        const bool take = (ln32 + st < 32) && (dn == d);
        #pragma unroll
        for (int r = 0; r < 16; ++r) {
            const float oa = __shfl_down(c2a[r], st, 32);
            const float ob = __shfl_down(c2b[r], st, 32);
            if (take) { c2a[r] = fmaxf(c2a[r], oa); c2b[r] = fmaxf(c2b[r], ob); }
        }
    }
    const int dprev = __shfl_up(d, 1, 32);
    const bool leader = (ln32 == 0) || (d != dprev);
    const unsigned lm = (unsigned)(__ballot(leader) & 0xffffffffull);
    const int L31 = 31 - __builtin_clz(lm);   // leader of segment containing lane 31

    if (leader) {
        // pack rows: regs 4q..4q+3 = channels t*32 + 8q + 4hi + 0..3
        float4 va[4], vb[4];
        #pragma unroll
        for (int q = 0; q < 4; ++q) {
            va[q].x = c2a[4 * q]; va[q].y = c2a[4 * q + 1];
            va[q].z = c2a[4 * q + 2]; va[q].w = c2a[4 * q + 3];
            vb[q].x = c2b[4 * q]; vb[q].y = c2b[4 * q + 1];
            vb[q].z = c2b[4 * q + 2]; vb[q].w = c2b[4 * q + 3];
        }
        if (ln32 != 0 && ln32 != L31) {
            // interior: this wave owns ALL edges of d -> plain store
            float* row = out + (long)d * 64;
            #pragma unroll
            for (int q = 0; q < 4; ++q) {
                *reinterpret_cast<float4*>(row + 8 * q + 4 * hi) = va[q];
                *reinterpret_cast<float4*>(row + 32 + 8 * q + 4 * hi) = vb[q];
            }
        }
        if (ln32 == 0) {
            float* row = recv + (long)(tile * 2) * 64;
            #pragma unroll
            for (int q = 0; q < 4; ++q) {
                *reinterpret_cast<float4*>(row + 8 * q + 4 * hi) = va[q];
                *reinterpret_cast<float4*>(row + 32 + 8 * q + 4 * hi) = vb[q];
            }
            if (hi == 0) recd[tile * 2] = d;
        }
        if (ln32 == L31) {
            float* row = recv + (long)(tile * 2 + 1) * 64;
            #pragma unroll
            for (int q = 0; q < 4; ++q) {
                *reinterpret_cast<float4*>(row + 8 * q + 4 * hi) = va[q];
                *reinterpret_cast<float4*>(row + 32 + 8 * q + 4 * hi) = vb[q];
            }
            if (hi == 0) recd[tile * 2 + 1] = d;
        }
    }
}

// ---------------- fixup: combine boundary records (runs of equal dst) ----------------
__global__ __launch_bounds__(256) void fixup_kernel(
    const int* __restrict__ recd, const float* __restrict__ recv,
    float* __restrict__ out)
{
    const int wid = threadIdx.x >> 6, lane = threadIdx.x & 63;
    const int r = blockIdx.x * 4 + wid;
    if (r >= NREC) return;
    const int d = recd[r];
    int lo = r, hi = r;
    while (lo > 0 && recd[lo - 1] == d) --lo;
    while (hi + 1 < NREC && recd[hi + 1] == d) ++hi;
    float m = 0.f;   // relu outputs >= 0
    for (int rr = lo; rr <= hi; ++rr) m = fmaxf(m, recv[(long)rr * 64 + lane]);
    out[(long)d * 64 + lane] = m;
}

// ---------------- BN stats: deterministic two-stage ----------------
__global__ __launch_bounds__(256) void stats_kernel(
    const float* __restrict__ h, float* __restrict__ partial)
{
    __shared__ float red[2][256];
    const int tid = threadIdx.x;
    const int c = tid & 63, r = tid >> 6;
    float s = 0.f, ss = 0.f;
    for (int v = blockIdx.x * 4 + r; v < NN; v += 256 * 4) {
        const float val = h[(long)v * 64 + c];
        s += val; ss += val * val;
    }
    red[0][tid] = s; red[1][tid] = ss;
    __syncthreads();
    if (r == 0) {
        float S = 0.f, SS = 0.f;
        #pragma unroll
        for (int q = 0; q < 4; ++q) { S += red[0][c + q * 64]; SS += red[1][c + q * 64]; }
        partial[blockIdx.x * 128 + c] = S;
        partial[blockIdx.x * 128 + 64 + c] = SS;
    }
}

__global__ void bn_finalize_kernel(
    const float* __restrict__ partial,
    const float* __restrict__ g, const float* __restrict__ b,
    float* __restrict__ scale, float* __restrict__ shift)
{
    const int c = threadIdx.x;   // 64 threads
    float S = 0.f, SS = 0.f;
    for (int bb = 0; bb < 256; ++bb) {
        S += partial[bb * 128 + c];
        SS += partial[bb * 128 + 64 + c];
    }
    const float invN = 1.0f / (float)NN;
    const float mu = S * invN;
    const float var = SS * invN - mu * mu;
    const float sc = g[c] * rsqrtf(var + BN_EPS);
    scale[c] = sc;
    shift[c] = b[c] - mu * sc;
}

// ---------------- node pass: BN2 normalize in place + segmented pooling ----------------
constexpr int NPB = 512;  // nodes per block
__global__ __launch_bounds__(256) void nodepass_kernel(
    float* __restrict__ xn, const int* __restrict__ batch,
    const float* __restrict__ scale, const float* __restrict__ shift,
    float* __restrict__ poolsum, unsigned* __restrict__ poolmax, int* __restrict__ counts)
{
    const int base = blockIdx.x * NPB;
    const int r = threadIdx.x >> 6, c = threadIdx.x & 63;
    int curg = -1; float rs = 0.f, rm = -INFINITY; int rc = 0;
    const int vend = (base + NPB < NN) ? base + NPB : NN;
    for (int v = base + r; v < vend; v += 4) {
        const long idx = (long)v * 64 + c;
        const float val = fmaf(xn[idx], scale[c], shift[c]);
        xn[idx] = val;
        const int g = batch[v];   // wave-uniform
        if (g != curg) {
            if (curg >= 0) {
                atomicAdd(poolsum + curg * 64 + c, rs);
                atomicMax(poolmax + curg * 64 + c, fenc(rm));
                if (c == 0) atomicAdd(counts + curg, rc);
            }
            curg = g; rs = 0.f; rm = -INFINITY; rc = 0;
        }
        rs += val; rm = fmaxf(rm, val); ++rc;
    }
    if (curg >= 0) {
        atomicAdd(poolsum + curg * 64 + c, rs);
        atomicMax(poolmax + curg * 64 + c, fenc(rm));
        if (c == 0) atomicAdd(counts + curg, rc);
    }
}

// ---------------- final: x_graph + projector MLP + BN + out ----------------
__global__ __launch_bounds__(512) void final_kernel(
    const float* __restrict__ poolsum, const unsigned* __restrict__ poolmax,
    const int* __restrict__ counts,
    const float* __restrict__ p_w1, const float* __restrict__ p_b1,
    const float* __restrict__ p_bng, const float* __restrict__ p_bnb,
    const float* __restrict__ p_w2, const float* __restrict__ p_b2,
    float* __restrict__ out)
{
    __shared__ float xg[64][128];
    __shared__ float znl[64 * 129];
    __shared__ float red[2][512];
    __shared__ float scsh[2][128];
    const int tid = threadIdx.x;

    #pragma unroll
    for (int i = 0; i < 16; ++i) {
        const int e2 = tid + i * 512;
        const int g = e2 >> 7, col = e2 & 127;
        float val;
        if (col < 64) {
            const float cnt = fmaxf((float)counts[g], 1.f);
            val = poolsum[g * 64 + col] / cnt;
        } else {
            const unsigned u = poolmax[g * 64 + col - 64];
            val = (u == 0u) ? 0.f : fdec(u);
        }
        xg[g][col] = val;
        out[OUT_XG + e2] = val;
    }
    __syncthreads();

    const int gg = tid >> 7, t = tid & 127;
    float z[16];
    #pragma unroll
    for (int gi = 0; gi < 16; ++gi) z[gi] = p_b1[t];
    for (int j = 0; j < 128; ++j) {
        const float wv = p_w1[j * 128 + t];
        #pragma unroll
        for (int gi = 0; gi < 16; ++gi) z[gi] = fmaf(xg[gg * 16 + gi][j], wv, z[gi]);
    }

    float s = 0.f, ss = 0.f;
    #pragma unroll
    for (int gi = 0; gi < 16; ++gi) { s += z[gi]; ss += z[gi] * z[gi]; }
    red[0][tid] = s; red[1][tid] = ss;
    __syncthreads();
    if (gg == 0) {
        float S = 0.f, SS = 0.f;
        #pragma unroll
        for (int q = 0; q < 4; ++q) { S += red[0][t + q * 128]; SS += red[1][t + q * 128]; }
        const float mu = S / 64.f;
        const float var = SS / 64.f - mu * mu;
        const float sc = p_bng[t] * rsqrtf(var + BN_EPS);
        scsh[0][t] = sc;
        scsh[1][t] = p_bnb[t] - mu * sc;
    }
    __syncthreads();
    const float sc = scsh[0][t], sh = scsh[1][t];
    #pragma unroll
    for (int gi = 0; gi < 16; ++gi) {
        const float zn = fmaxf(fmaf(z[gi], sc, sh), 0.f);
        znl[(gg * 16 + gi) * 129 + t] = zn;
    }
    __syncthreads();

    float zp[16];
    #pragma unroll
    for (int gi = 0; gi < 16; ++gi) zp[gi] = p_b2[t];
    for (int c = 0; c < 128; ++c) {
        const float wv = p_w2[c * 128 + t];
        #pragma unroll
        for (int gi = 0; gi < 16; ++gi) zp[gi] = fmaf(znl[(gg * 16 + gi) * 129 + c], wv, zp[gi]);
    }
    #pragma unroll
    for (int gi = 0; gi < 16; ++gi) out[(gg * 16 + gi) * 128 + t] = zp[gi];
}

// ---------------- launch ----------------
extern "C" void kernel_launch(void* const* d_in, const int* in_sizes, int n_in,
                              void* d_out, int out_size, void* d_ws, size_t ws_size,
                              hipStream_t stream)
{
    const float* x     = (const float*)d_in[0];
    const int*   eidx  = (const int*)d_in[1];
    const int*   batch = (const int*)d_in[2];
    const float* c1w1  = (const float*)d_in[3];
    const float* c1b1  = (const float*)d_in[4];
    const float* c1w2  = (const float*)d_in[5];
    const float* c1b2  = (const float*)d_in[6];
    const float* bn1g  = (const float*)d_in[7];
    const float* bn1b  = (const float*)d_in[8];
    const float* c2w1  = (const float*)d_in[9];
    const float* c2b1  = (const float*)d_in[10];
    const float* c2w2  = (const float*)d_in[11];
    const float* c2b2  = (const float*)d_in[12];
    const float* bn2g  = (const float*)d_in[13];
    const float* bn2b  = (const float*)d_in[14];
    const float* pw1   = (const float*)d_in[15];
    const float* pb1   = (const float*)d_in[16];
    const float* pbng  = (const float*)d_in[17];
    const float* pbnb  = (const float*)d_in[18];
    const float* pw2   = (const float*)d_in[19];
    const float* pb2   = (const float*)d_in[20];

    const int* src = eidx;
    const int* dst = eidx + NE;

    float* ws  = (float*)d_ws;
    float* o   = (float*)d_out;
    float* h1  = ws + H1_OFF;
    float* xnode = o + OUT_XNODE;
    int* scnt  = (int*)(ws + SCNT_OFF);
    int* curs  = (int*)(ws + CURS_OFF);
    int* eord  = (int*)(ws + EORD_OFF);
    unsigned short* wf1 = (unsigned short*)(ws + WF1_OFF);
    unsigned short* wf2 = (unsigned short*)(ws + WF2_OFF);
    int* recd  = (int*)(ws + RECD_OFF);
    float* recv = ws + RECV_OFF;

    // zero accumulators
    hipMemsetAsync(h1, 0, (size_t)NN * 64 * 4, stream);
    hipMemsetAsync(xnode, 0, (size_t)NN * 64 * 4, stream);
    hipMemsetAsync(ws + PSUM_OFF, 0, (4096 + 4096 + 64) * 4, stream);
    hipMemsetAsync(scnt, 0, (size_t)NN * 4, stream);

    // weight prep (both convs)
    prep_weights<<<48, 256, 0, stream>>>(c1w1, c1w2, wf1);
    prep_weights<<<48, 256, 0, stream>>>(c2w1, c2w2, wf2);

    // counting sort of edges by dst
    const int eGrid = (NE + 255) / 256;
    count_kernel<<<eGrid, 256, 0, stream>>>(dst, scnt);
    scan_kernel<<<1, 1024, 0, stream>>>(scnt, curs);
    scatter_kernel<<<eGrid, 256, 0, stream>>>(dst, curs, eord);

    const int convGrid = (NTILES + 3) / 4;
    const int fixGrid  = (NREC + 3) / 4;

    // conv1: x -> h1
    edgeconv_kernel<false><<<convGrid, 256, 0, stream>>>(
        x, eord, src, dst, wf1, c1b1, c1b2, nullptr, nullptr, h1, recd, recv);
    fixup_kernel<<<fixGrid, 256, 0, stream>>>(recd, recv, h1);
    // BN1 stats
    stats_kernel<<<256, 256, 0, stream>>>(h1, ws + PART_OFF);
    bn_finalize_kernel<<<1, 64, 0, stream>>>(ws + PART_OFF, bn1g, bn1b,
                                             ws + SC1_OFF, ws + SH1_OFF);
    // conv2: norm(h1) -> xnode
    edgeconv_kernel<true><<<convGrid, 256, 0, stream>>>(
        h1, eord, src, dst, wf2, c2b1, c2b2, ws + SC1_OFF, ws + SH1_OFF,
        xnode, recd, recv);
    fixup_kernel<<<fixGrid, 256, 0, stream>>>(recd, recv, xnode);
    // BN2 stats
    stats_kernel<<<256, 256, 0, stream>>>(xnode, ws + PART_OFF);
    bn_finalize_kernel<<<1, 64, 0, stream>>>(ws + PART_OFF, bn2g, bn2b,
                                             ws + SC2_OFF, ws + SH2_OFF);
    // normalize x_node + pooling
    nodepass_kernel<<<(NN + NPB - 1) / NPB, 256, 0, stream>>>(
        xnode, batch, ws + SC2_OFF, ws + SH2_OFF,
        ws + PSUM_OFF, (unsigned*)(ws + PMAX_OFF), (int*)(ws + CNT_OFF));
    // x_graph + projector
    final_kernel<<<1, 512, 0, stream>>>(
        ws + PSUM_OFF, (unsigned*)(ws + PMAX_OFF), (int*)(ws + CNT_OFF),
        pw1, pb1, pbng, pbnb, pw2, pb2, o);
}

// Round 4
// 543.015 us; speedup vs baseline: 11.3630x; 1.3303x over previous
//
#include <hip/hip_runtime.h>
#include <hip/hip_bf16.h>

// ---------------- problem constants ----------------
constexpr int NN = 100000;   // nodes
constexpr int NE = 1000000;  // edges
constexpr int NG = 64;       // graphs
constexpr float BN_EPS = 1e-5f;
constexpr int NTILES = NE / 32;      // 31250 wave-tiles of 32 edges
constexpr int NREC = NTILES * 2;     // 62500 boundary records
constexpr int SCAN_NB = (NN + 255) / 256;  // 391 scan blocks

// ws layout (in floats)
constexpr long H1_OFF   = 0;                       // [NN*64] conv1 output (raw)
constexpr long PART_OFF = 6400000;                 // [256*128] BN stat partials / scan bsum
constexpr long SC1_OFF  = PART_OFF + 32768;        // [64]
constexpr long SH1_OFF  = SC1_OFF + 64;
constexpr long SC2_OFF  = SH1_OFF + 64;
constexpr long SH2_OFF  = SC2_OFF + 64;
constexpr long PSUM_OFF = SH2_OFF + 64;            // [64*64]
constexpr long PMAX_OFF = PSUM_OFF + 4096;         // [64*64]
constexpr long CNT_OFF  = PMAX_OFF + 4096;         // [64]
constexpr long SCNT_OFF = CNT_OFF + 64;            // [100000] sort counts
constexpr long CURS_OFF = SCNT_OFF + 100000;       // [100000] sort cursors
constexpr long EORD_OFF = CURS_OFF + 100000;       // [1000000] sorted edge ids
constexpr long WF1_OFF  = EORD_OFF + 1000000;      // 12288 u16 (6144 float slots)
constexpr long WF2_OFF  = WF1_OFF + 6144;          // 12288 u16
constexpr long RECD_OFF = WF2_OFF + 6144;          // [62500] record dst (int), pad->62528
constexpr long RECV_OFF = RECD_OFF + 62528;        // [62500*64] record values

// d_out layout (floats): z_proj [64*128] | x_node [NN*64] | x_graph [64*128]
constexpr long OUT_XNODE = 8192;
constexpr long OUT_XG    = 8192 + 6400000L;

#define LDS_FENCE() asm volatile("s_waitcnt lgkmcnt(0)" ::: "memory")

using bf16x8 = __attribute__((ext_vector_type(8))) short;
using f32x16 = __attribute__((ext_vector_type(16))) float;

__device__ __forceinline__ unsigned short f2bf(float f) {
    return __builtin_bit_cast(unsigned short, __float2bfloat16(f));
}
__device__ __forceinline__ unsigned fenc(float f) {
    unsigned u = __float_as_uint(f);
    return (u & 0x80000000u) ? ~u : (u | 0x80000000u);
}
__device__ __forceinline__ float fdec(unsigned u) {
    return (u & 0x80000000u) ? __uint_as_float(u & 0x7fffffffu) : __uint_as_float(~u);
}

// ---------------- counting sort of edges by dst ----------------
__global__ __launch_bounds__(256) void count_kernel(
    const int* __restrict__ dst, int* __restrict__ cnt)
{
    const int e = blockIdx.x * 256 + threadIdx.x;
    if (e < NE) atomicAdd(cnt + dst[e], 1);
}

// pass 1: per-256-chunk exclusive scan -> cursor, chunk total -> bsum
__global__ __launch_bounds__(256) void scan_local_kernel(
    const int* __restrict__ cnt, int* __restrict__ cursor, int* __restrict__ bsum)
{
    __shared__ int tmp[256];
    const int t = threadIdx.x;
    const int v = blockIdx.x * 256 + t;
    const int c = (v < NN) ? cnt[v] : 0;
    tmp[t] = c;
    __syncthreads();
    for (int off = 1; off < 256; off <<= 1) {
        const int u = (t >= off) ? tmp[t - off] : 0;
        __syncthreads();
        tmp[t] += u;
        __syncthreads();
    }
    if (v < NN) cursor[v] = tmp[t] - c;          // exclusive within chunk
    if (t == 255) bsum[blockIdx.x] = tmp[255];
}

// pass 2: single block exclusive-scans the block sums (SCAN_NB <= 512)
__global__ __launch_bounds__(512) void scan_blocks_kernel(int* __restrict__ bsum)
{
    __shared__ int tmp[512];
    const int t = threadIdx.x;
    const int v = (t < SCAN_NB) ? bsum[t] : 0;
    tmp[t] = v;
    __syncthreads();
    for (int off = 1; off < 512; off <<= 1) {
        const int u = (t >= off) ? tmp[t - off] : 0;
        __syncthreads();
        tmp[t] += u;
        __syncthreads();
    }
    if (t < SCAN_NB) bsum[t] = tmp[t] - v;       // exclusive
}

// pass 3: add block offsets in place
__global__ __launch_bounds__(256) void scan_add_kernel(
    int* __restrict__ cursor, const int* __restrict__ bsum)
{
    const int v = blockIdx.x * 256 + threadIdx.x;
    if (v < NN) cursor[v] += bsum[blockIdx.x];
}

__global__ __launch_bounds__(256) void scatter_kernel(
    const int* __restrict__ dst, int* __restrict__ cursor, int* __restrict__ eord)
{
    const int e = blockIdx.x * 256 + threadIdx.x;
    if (e < NE) {
        const int pos = atomicAdd(cursor + dst[e], 1);
        eord[pos] = e;
    }
}

// ---------------- weight prep: f32 [K][C] -> fragment-ordered bf16 ----------------
__global__ __launch_bounds__(256) void prep_weights(
    const float* __restrict__ w1, const float* __restrict__ w2,
    unsigned short* __restrict__ wf)
{
    const int idx = blockIdx.x * 256 + threadIdx.x;
    if (idx >= 12288) return;
    if (idx < 8192) {
        const int f = idx >> 9, rem = idx & 511, ln = rem >> 3, i = rem & 7;
        const int t = f >> 3, ks = f & 7;
        const int k = ks * 16 + (ln >> 5) * 8 + i, c = t * 32 + (ln & 31);
        wf[idx] = f2bf(w1[k * 64 + c]);
    } else {
        const int j = idx - 8192;
        const int f = j >> 9, rem = j & 511, ln = rem >> 3, i = rem & 7;
        const int t = f >> 2, ks = f & 3;
        const int k = ks * 16 + (ln >> 5) * 8 + i, c = t * 32 + (ln & 31);
        wf[idx] = f2bf(w2[k * 64 + c]);
    }
}

// ---------------- EdgeConv via MFMA: wave = 32 sorted edges ----------------
template<bool NORM>
__global__ __launch_bounds__(256) void edgeconv_kernel(
    const float* __restrict__ x, const int* __restrict__ eord,
    const int* __restrict__ src, const int* __restrict__ dst,
    const unsigned short* __restrict__ wfrag,
    const float* __restrict__ b1, const float* __restrict__ b2,
    const float* __restrict__ scale, const float* __restrict__ shift,
    float* __restrict__ out, int* __restrict__ recd, float* __restrict__ recv)
{
    __shared__ unsigned short wlds[12288];       // 24 KB fragment-ordered weights
    __shared__ unsigned short hlds[4][2048];     // 4 KB per wave: h (bf16, swizzled)

    {
        const uint4* wsrc = reinterpret_cast<const uint4*>(wfrag);
        uint4* wdst = reinterpret_cast<uint4*>(wlds);
        #pragma unroll
        for (int i = 0; i < 6; ++i) wdst[threadIdx.x + i * 256] = wsrc[threadIdx.x + i * 256];
    }
    __syncthreads();

    const int wid  = threadIdx.x >> 6;
    const int lane = threadIdx.x & 63;
    const int hi   = lane >> 5;
    const int ln32 = lane & 31;
    const int tile = blockIdx.x * 4 + wid;
    if (tile >= NTILES) return;

    const int e = eord[tile * 32 + ln32];
    const int s = src[e];
    const int d = dst[e];
    const float* __restrict__ xip = x + (long)d * 64;
    const float* __restrict__ xjp = x + (long)s * 64;

    float4 xin[8];
    #pragma unroll
    for (int ks = 0; ks < 4; ++ks) {
        #pragma unroll
        for (int q = 0; q < 2; ++q) {
            const int off = ks * 16 + hi * 8 + q * 4;
            float4 a = *reinterpret_cast<const float4*>(xip + off);
            if (NORM) {
                const float4 sc = *reinterpret_cast<const float4*>(scale + off);
                const float4 sh = *reinterpret_cast<const float4*>(shift + off);
                a.x = fmaf(a.x, sc.x, sh.x); a.y = fmaf(a.y, sc.y, sh.y);
                a.z = fmaf(a.z, sc.z, sh.z); a.w = fmaf(a.w, sc.w, sh.w);
            }
            xin[ks * 2 + q] = a;
        }
    }

    f32x16 c1a, c1b;
    #pragma unroll
    for (int r = 0; r < 16; ++r) {
        const int row = (r & 3) + 8 * (r >> 2) + 4 * hi;
        c1a[r] = b1[row];
        c1b[r] = b1[32 + row];
    }

    #pragma unroll
    for (int ks = 0; ks < 8; ++ks) {
        bf16x8 bfr;
        if (ks < 4) {
            const float4 a0 = xin[ks * 2], a1 = xin[ks * 2 + 1];
            bfr[0] = (short)f2bf(a0.x); bfr[1] = (short)f2bf(a0.y);
            bfr[2] = (short)f2bf(a0.z); bfr[3] = (short)f2bf(a0.w);
            bfr[4] = (short)f2bf(a1.x); bfr[5] = (short)f2bf(a1.y);
            bfr[6] = (short)f2bf(a1.z); bfr[7] = (short)f2bf(a1.w);
        } else {
            const int kb = ks - 4;
            const int off = kb * 16 + hi * 8;
            float4 xa = *reinterpret_cast<const float4*>(xjp + off);
            float4 xb = *reinterpret_cast<const float4*>(xjp + off + 4);
            if (NORM) {
                const float4 s0 = *reinterpret_cast<const float4*>(scale + off);
                const float4 s1 = *reinterpret_cast<const float4*>(scale + off + 4);
                const float4 h0 = *reinterpret_cast<const float4*>(shift + off);
                const float4 h1 = *reinterpret_cast<const float4*>(shift + off + 4);
                xa.x = fmaf(xa.x, s0.x, h0.x); xa.y = fmaf(xa.y, s0.y, h0.y);
                xa.z = fmaf(xa.z, s0.z, h0.z); xa.w = fmaf(xa.w, s0.w, h0.w);
                xb.x = fmaf(xb.x, s1.x, h1.x); xb.y = fmaf(xb.y, s1.y, h1.y);
                xb.z = fmaf(xb.z, s1.z, h1.z); xb.w = fmaf(xb.w, s1.w, h1.w);
            }
            const float4 i0 = xin[kb * 2], i1 = xin[kb * 2 + 1];
            bfr[0] = (short)f2bf(xa.x - i0.x); bfr[1] = (short)f2bf(xa.y - i0.y);
            bfr[2] = (short)f2bf(xa.z - i0.z); bfr[3] = (short)f2bf(xa.w - i0.w);
            bfr[4] = (short)f2bf(xb.x - i1.x); bfr[5] = (short)f2bf(xb.y - i1.y);
            bfr[6] = (short)f2bf(xb.z - i1.z); bfr[7] = (short)f2bf(xb.w - i1.w);
        }
        const bf16x8 a0 = *reinterpret_cast<const bf16x8*>(&wlds[(0 * 8 + ks) * 512 + lane * 8]);
        const bf16x8 a1 = *reinterpret_cast<const bf16x8*>(&wlds[(1 * 8 + ks) * 512 + lane * 8]);
        c1a = __builtin_amdgcn_mfma_f32_32x32x16_bf16(a0, bfr, c1a, 0, 0, 0);
        c1b = __builtin_amdgcn_mfma_f32_32x32x16_bf16(a1, bfr, c1b, 0, 0, 0);
    }

    {
        char* hl = reinterpret_cast<char*>(&hlds[wid][0]);
        #pragma unroll
        for (int t = 0; t < 2; ++t) {
            const f32x16 c = t ? c1b : c1a;
            #pragma unroll
            for (int q = 0; q < 4; ++q) {
                const float h0 = fmaxf(c[4 * q + 0], 0.f);
                const float h1 = fmaxf(c[4 * q + 1], 0.f);
                const float h2 = fmaxf(c[4 * q + 2], 0.f);
                const float h3 = fmaxf(c[4 * q + 3], 0.f);
                uint2 pk;
                pk.x = (unsigned)f2bf(h0) | ((unsigned)f2bf(h1) << 16);
                pk.y = (unsigned)f2bf(h2) | ((unsigned)f2bf(h3) << 16);
                unsigned boff = (unsigned)(ln32 * 128 + (t * 32 + 8 * q + 4 * hi) * 2);
                boff ^= (unsigned)((ln32 & 7) << 4);
                *reinterpret_cast<uint2*>(hl + boff) = pk;
            }
        }
    }
    LDS_FENCE();

    f32x16 c2a, c2b;
    #pragma unroll
    for (int r = 0; r < 16; ++r) {
        const int row = (r & 3) + 8 * (r >> 2) + 4 * hi;
        c2a[r] = b2[row];
        c2b[r] = b2[32 + row];
    }
    {
        const char* hl = reinterpret_cast<const char*>(&hlds[wid][0]);
        #pragma unroll
        for (int ks = 0; ks < 4; ++ks) {
            unsigned boff = (unsigned)(ln32 * 128 + ks * 32 + hi * 16);
            boff ^= (unsigned)((ln32 & 7) << 4);
            const bf16x8 b2f = *reinterpret_cast<const bf16x8*>(hl + boff);
            const bf16x8 a0 = *reinterpret_cast<const bf16x8*>(&wlds[8192 + (0 * 4 + ks) * 512 + lane * 8]);
            const bf16x8 a1 = *reinterpret_cast<const bf16x8*>(&wlds[8192 + (1 * 4 + ks) * 512 + lane * 8]);
            c2a = __builtin_amdgcn_mfma_f32_32x32x16_bf16(a0, b2f, c2a, 0, 0, 0);
            c2b = __builtin_amdgcn_mfma_f32_32x32x16_bf16(a1, b2f, c2b, 0, 0, 0);
        }
    }

    #pragma unroll
    for (int r = 0; r < 16; ++r) {
        c2a[r] = fmaxf(c2a[r], 0.f);
        c2b[r] = fmaxf(c2b[r], 0.f);
    }

    #pragma unroll
    for (int st = 1; st < 32; st <<= 1) {
        const int dn = __shfl_down(d, st, 32);
        const bool take = (ln32 + st < 32) && (dn == d);
        #pragma unroll
        for (int r = 0; r < 16; ++r) {
            const float oa = __shfl_down(c2a[r], st, 32);
            const float ob = __shfl_down(c2b[r], st, 32);
            if (take) { c2a[r] = fmaxf(c2a[r], oa); c2b[r] = fmaxf(c2b[r], ob); }
        }
    }
    const int dprev = __shfl_up(d, 1, 32);
    const bool leader = (ln32 == 0) || (d != dprev);
    const unsigned lm = (unsigned)(__ballot(leader) & 0xffffffffull);
    const int L31 = 31 - __builtin_clz(lm);

    if (leader) {
        float4 va[4], vb[4];
        #pragma unroll
        for (int q = 0; q < 4; ++q) {
            va[q].x = c2a[4 * q]; va[q].y = c2a[4 * q + 1];
            va[q].z = c2a[4 * q + 2]; va[q].w = c2a[4 * q + 3];
            vb[q].x = c2b[4 * q]; vb[q].y = c2b[4 * q + 1];
            vb[q].z = c2b[4 * q + 2]; vb[q].w = c2b[4 * q + 3];
        }
        if (ln32 != 0 && ln32 != L31) {
            float* row = out + (long)d * 64;
            #pragma unroll
            for (int q = 0; q < 4; ++q) {
                *reinterpret_cast<float4*>(row + 8 * q + 4 * hi) = va[q];
                *reinterpret_cast<float4*>(row + 32 + 8 * q + 4 * hi) = vb[q];
            }
        }
        if (ln32 == 0) {
            float* row = recv + (long)(tile * 2) * 64;
            #pragma unroll
            for (int q = 0; q < 4; ++q) {
                *reinterpret_cast<float4*>(row + 8 * q + 4 * hi) = va[q];
                *reinterpret_cast<float4*>(row + 32 + 8 * q + 4 * hi) = vb[q];
            }
            if (hi == 0) recd[tile * 2] = d;
        }
        if (ln32 == L31) {
            float* row = recv + (long)(tile * 2 + 1) * 64;
            #pragma unroll
            for (int q = 0; q < 4; ++q) {
                *reinterpret_cast<float4*>(row + 8 * q + 4 * hi) = va[q];
                *reinterpret_cast<float4*>(row + 32 + 8 * q + 4 * hi) = vb[q];
            }
            if (hi == 0) recd[tile * 2 + 1] = d;
        }
    }
}

// ---------------- fixup: combine boundary records (runs of equal dst) ----------------
__global__ __launch_bounds__(256) void fixup_kernel(
    const int* __restrict__ recd, const float* __restrict__ recv,
    float* __restrict__ out)
{
    const int wid = threadIdx.x >> 6, lane = threadIdx.x & 63;
    const int r = blockIdx.x * 4 + wid;
    if (r >= NREC) return;
    const int d = recd[r];
    int lo = r, hi = r;
    while (lo > 0 && recd[lo - 1] == d) --lo;
    while (hi + 1 < NREC && recd[hi + 1] == d) ++hi;
    float m = 0.f;
    for (int rr = lo; rr <= hi; ++rr) m = fmaxf(m, recv[(long)rr * 64 + lane]);
    out[(long)d * 64 + lane] = m;
}

// ---------------- BN stats: deterministic two-stage ----------------
__global__ __launch_bounds__(256) void stats_kernel(
    const float* __restrict__ h, float* __restrict__ partial)
{
    __shared__ float red[2][256];
    const int tid = threadIdx.x;
    const int c = tid & 63, r = tid >> 6;
    float s = 0.f, ss = 0.f;
    for (int v = blockIdx.x * 4 + r; v < NN; v += 256 * 4) {
        const float val = h[(long)v * 64 + c];
        s += val; ss += val * val;
    }
    red[0][tid] = s; red[1][tid] = ss;
    __syncthreads();
    if (r == 0) {
        float S = 0.f, SS = 0.f;
        #pragma unroll
        for (int q = 0; q < 4; ++q) { S += red[0][c + q * 64]; SS += red[1][c + q * 64]; }
        partial[blockIdx.x * 128 + c] = S;
        partial[blockIdx.x * 128 + 64 + c] = SS;
    }
}

__global__ void bn_finalize_kernel(
    const float* __restrict__ partial,
    const float* __restrict__ g, const float* __restrict__ b,
    float* __restrict__ scale, float* __restrict__ shift)
{
    const int c = threadIdx.x;
    float S = 0.f, SS = 0.f;
    for (int bb = 0; bb < 256; ++bb) {
        S += partial[bb * 128 + c];
        SS += partial[bb * 128 + 64 + c];
    }
    const float invN = 1.0f / (float)NN;
    const float mu = S * invN;
    const float var = SS * invN - mu * mu;
    const float sc = g[c] * rsqrtf(var + BN_EPS);
    scale[c] = sc;
    shift[c] = b[c] - mu * sc;
}

// ---------------- node pass: BN2 normalize in place + segmented pooling ----------------
constexpr int NPB = 512;
__global__ __launch_bounds__(256) void nodepass_kernel(
    float* __restrict__ xn, const int* __restrict__ batch,
    const float* __restrict__ scale, const float* __restrict__ shift,
    float* __restrict__ poolsum, unsigned* __restrict__ poolmax, int* __restrict__ counts)
{
    const int base = blockIdx.x * NPB;
    const int r = threadIdx.x >> 6, c = threadIdx.x & 63;
    int curg = -1; float rs = 0.f, rm = -INFINITY; int rc = 0;
    const int vend = (base + NPB < NN) ? base + NPB : NN;
    for (int v = base + r; v < vend; v += 4) {
        const long idx = (long)v * 64 + c;
        const float val = fmaf(xn[idx], scale[c], shift[c]);
        xn[idx] = val;
        const int g = batch[v];
        if (g != curg) {
            if (curg >= 0) {
                atomicAdd(poolsum + curg * 64 + c, rs);
                atomicMax(poolmax + curg * 64 + c, fenc(rm));
                if (c == 0) atomicAdd(counts + curg, rc);
            }
            curg = g; rs = 0.f; rm = -INFINITY; rc = 0;
        }
        rs += val; rm = fmaxf(rm, val); ++rc;
    }
    if (curg >= 0) {
        atomicAdd(poolsum + curg * 64 + c, rs);
        atomicMax(poolmax + curg * 64 + c, fenc(rm));
        if (c == 0) atomicAdd(counts + curg, rc);
    }
}

// ---------------- final: x_graph + projector MLP + BN + out ----------------
__global__ __launch_bounds__(512) void final_kernel(
    const float* __restrict__ poolsum, const unsigned* __restrict__ poolmax,
    const int* __restrict__ counts,
    const float* __restrict__ p_w1, const float* __restrict__ p_b1,
    const float* __restrict__ p_bng, const float* __restrict__ p_bnb,
    const float* __restrict__ p_w2, const float* __restrict__ p_b2,
    float* __restrict__ out)
{
    __shared__ float xg[64][128];
    __shared__ float znl[64 * 129];
    __shared__ float red[2][512];
    __shared__ float scsh[2][128];
    const int tid = threadIdx.x;

    #pragma unroll
    for (int i = 0; i < 16; ++i) {
        const int e2 = tid + i * 512;
        const int g = e2 >> 7, col = e2 & 127;
        float val;
        if (col < 64) {
            const float cnt = fmaxf((float)counts[g], 1.f);
            val = poolsum[g * 64 + col] / cnt;
        } else {
            const unsigned u = poolmax[g * 64 + col - 64];
            val = (u == 0u) ? 0.f : fdec(u);
        }
        xg[g][col] = val;
        out[OUT_XG + e2] = val;
    }
    __syncthreads();

    const int gg = tid >> 7, t = tid & 127;
    float z[16];
    #pragma unroll
    for (int gi = 0; gi < 16; ++gi) z[gi] = p_b1[t];
    for (int j = 0; j < 128; ++j) {
        const float wv = p_w1[j * 128 + t];
        #pragma unroll
        for (int gi = 0; gi < 16; ++gi) z[gi] = fmaf(xg[gg * 16 + gi][j], wv, z[gi]);
    }

    float s = 0.f, ss = 0.f;
    #pragma unroll
    for (int gi = 0; gi < 16; ++gi) { s += z[gi]; ss += z[gi] * z[gi]; }
    red[0][tid] = s; red[1][tid] = ss;
    __syncthreads();
    if (gg == 0) {
        float S = 0.f, SS = 0.f;
        #pragma unroll
        for (int q = 0; q < 4; ++q) { S += red[0][t + q * 128]; SS += red[1][t + q * 128]; }
        const float mu = S / 64.f;
        const float var = SS / 64.f - mu * mu;
        const float sc = p_bng[t] * rsqrtf(var + BN_EPS);
        scsh[0][t] = sc;
        scsh[1][t] = p_bnb[t] - mu * sc;
    }
    __syncthreads();
    const float sc = scsh[0][t], sh = scsh[1][t];
    #pragma unroll
    for (int gi = 0; gi < 16; ++gi) {
        const float zn = fmaxf(fmaf(z[gi], sc, sh), 0.f);
        znl[(gg * 16 + gi) * 129 + t] = zn;
    }
    __syncthreads();

    float zp[16];
    #pragma unroll
    for (int gi = 0; gi < 16; ++gi) zp[gi] = p_b2[t];
    for (int c = 0; c < 128; ++c) {
        const float wv = p_w2[c * 128 + t];
        #pragma unroll
        for (int gi = 0; gi < 16; ++gi) zp[gi] = fmaf(znl[(gg * 16 + gi) * 129 + c], wv, zp[gi]);
    }
    #pragma unroll
    for (int gi = 0; gi < 16; ++gi) out[(gg * 16 + gi) * 128 + t] = zp[gi];
}

// ---------------- launch ----------------
extern "C" void kernel_launch(void* const* d_in, const int* in_sizes, int n_in,
                              void* d_out, int out_size, void* d_ws, size_t ws_size,
                              hipStream_t stream)
{
    const float* x     = (const float*)d_in[0];
    const int*   eidx  = (const int*)d_in[1];
    const int*   batch = (const int*)d_in[2];
    const float* c1w1  = (const float*)d_in[3];
    const float* c1b1  = (const float*)d_in[4];
    const float* c1w2  = (const float*)d_in[5];
    const float* c1b2  = (const float*)d_in[6];
    const float* bn1g  = (const float*)d_in[7];
    const float* bn1b  = (const float*)d_in[8];
    const float* c2w1  = (const float*)d_in[9];
    const float* c2b1  = (const float*)d_in[10];
    const float* c2w2  = (const float*)d_in[11];
    const float* c2b2  = (const float*)d_in[12];
    const float* bn2g  = (const float*)d_in[13];
    const float* bn2b  = (const float*)d_in[14];
    const float* pw1   = (const float*)d_in[15];
    const float* pb1   = (const float*)d_in[16];
    const float* pbng  = (const float*)d_in[17];
    const float* pbnb  = (const float*)d_in[18];
    const float* pw2   = (const float*)d_in[19];
    const float* pb2   = (const float*)d_in[20];

    const int* src = eidx;
    const int* dst = eidx + NE;

    float* ws  = (float*)d_ws;
    float* o   = (float*)d_out;
    float* h1  = ws + H1_OFF;
    float* xnode = o + OUT_XNODE;
    int* scnt  = (int*)(ws + SCNT_OFF);
    int* curs  = (int*)(ws + CURS_OFF);
    int* eord  = (int*)(ws + EORD_OFF);
    int* bsum  = (int*)(ws + PART_OFF);    // reuse stats-partial region (free until stats)
    unsigned short* wf1 = (unsigned short*)(ws + WF1_OFF);
    unsigned short* wf2 = (unsigned short*)(ws + WF2_OFF);
    int* recd  = (int*)(ws + RECD_OFF);
    float* recv = ws + RECV_OFF;

    // zero accumulators
    hipMemsetAsync(h1, 0, (size_t)NN * 64 * 4, stream);
    hipMemsetAsync(xnode, 0, (size_t)NN * 64 * 4, stream);
    hipMemsetAsync(ws + PSUM_OFF, 0, (4096 + 4096 + 64) * 4, stream);
    hipMemsetAsync(scnt, 0, (size_t)NN * 4, stream);

    // weight prep (both convs)
    prep_weights<<<48, 256, 0, stream>>>(c1w1, c1w2, wf1);
    prep_weights<<<48, 256, 0, stream>>>(c2w1, c2w2, wf2);

    // counting sort of edges by dst (hierarchical scan)
    const int eGrid = (NE + 255) / 256;
    count_kernel<<<eGrid, 256, 0, stream>>>(dst, scnt);
    scan_local_kernel<<<SCAN_NB, 256, 0, stream>>>(scnt, curs, bsum);
    scan_blocks_kernel<<<1, 512, 0, stream>>>(bsum);
    scan_add_kernel<<<SCAN_NB, 256, 0, stream>>>(curs, bsum);
    scatter_kernel<<<eGrid, 256, 0, stream>>>(dst, curs, eord);

    const int convGrid = (NTILES + 3) / 4;
    const int fixGrid  = (NREC + 3) / 4;

    // conv1: x -> h1
    edgeconv_kernel<false><<<convGrid, 256, 0, stream>>>(
        x, eord, src, dst, wf1, c1b1, c1b2, nullptr, nullptr, h1, recd, recv);
    fixup_kernel<<<fixGrid, 256, 0, stream>>>(recd, recv, h1);
    // BN1 stats
    stats_kernel<<<256, 256, 0, stream>>>(h1, ws + PART_OFF);
    bn_finalize_kernel<<<1, 64, 0, stream>>>(ws + PART_OFF, bn1g, bn1b,
                                             ws + SC1_OFF, ws + SH1_OFF);
    // conv2: norm(h1) -> xnode
    edgeconv_kernel<true><<<convGrid, 256, 0, stream>>>(
        h1, eord, src, dst, wf2, c2b1, c2b2, ws + SC1_OFF, ws + SH1_OFF,
        xnode, recd, recv);
    fixup_kernel<<<fixGrid, 256, 0, stream>>>(recd, recv, xnode);
    // BN2 stats
    stats_kernel<<<256, 256, 0, stream>>>(xnode, ws + PART_OFF);
    bn_finalize_kernel<<<1, 64, 0, stream>>>(ws + PART_OFF, bn2g, bn2b,
                                             ws + SC2_OFF, ws + SH2_OFF);
    // normalize x_node + pooling
    nodepass_kernel<<<(NN + NPB - 1) / NPB, 256, 0, stream>>>(
        xnode, batch, ws + SC2_OFF, ws + SH2_OFF,
        ws + PSUM_OFF, (unsigned*)(ws + PMAX_OFF), (int*)(ws + CNT_OFF));
    // x_graph + projector
    final_kernel<<<1, 512, 0, stream>>>(
        ws + PSUM_OFF, (unsigned*)(ws + PMAX_OFF), (int*)(ws + CNT_OFF),
        pw1, pb1, pbng, pbnb, pw2, pb2, o);
}

// Round 5
// 509.033 us; speedup vs baseline: 12.1216x; 1.0668x over previous
//
#include <hip/hip_runtime.h>
#include <hip/hip_bf16.h>

// ---------------- problem constants ----------------
constexpr int NN = 100000;   // nodes
constexpr int NE = 1000000;  // edges
constexpr int NG = 64;       // graphs
constexpr float BN_EPS = 1e-5f;
constexpr int NTILES = NE / 32;      // 31250 wave-tiles of 32 edges
constexpr int NNTILES = NN / 32;     // 3125 node tiles
constexpr int NREC = NTILES * 2;     // 62500 boundary records
constexpr int SCAN_NB = (NN + 255) / 256;  // 391 scan blocks

// ws layout (in floats)
constexpr long H1_OFF   = 0;                       // [NN*64] conv1 output (raw)
constexpr long PART_OFF = 6400000;                 // [256*128] BN stat partials / scan bsum
constexpr long SC1_OFF  = PART_OFF + 32768;        // [64]
constexpr long SH1_OFF  = SC1_OFF + 64;
constexpr long SC2_OFF  = SH1_OFF + 64;
constexpr long SH2_OFF  = SC2_OFF + 64;
constexpr long PSUM_OFF = SH2_OFF + 64;            // [64*64]
constexpr long PMAX_OFF = PSUM_OFF + 4096;         // [64*64]
constexpr long CNT_OFF  = PMAX_OFF + 4096;         // [64]
constexpr long SCNT_OFF = CNT_OFF + 64;            // [100000] sort counts
constexpr long CURS_OFF = SCNT_OFF + 100000;       // [100000] sort cursors
constexpr long SEDG_OFF = CURS_OFF + 100000;       // [NE int2] sorted (src,dst) = 2M floats
constexpr long WF1_OFF  = SEDG_OFF + 2000000;      // 12288 u16 = 6144 float slots
constexpr long WF2_OFF  = WF1_OFF + 6144;          // 12288 u16
constexpr long RECD_OFF = WF2_OFF + 6144;          // [62500] record dst (int), pad->62528
constexpr long RECV_OFF = RECD_OFF + 62528;        // [62500*64] record values
constexpr long P_OFF    = RECV_OFF + 4000000;      // [NN*64 bf16] = 3.2M floats
constexpr long Q_OFF    = P_OFF + 3200000;         // [NN*64 bf16]

// d_out layout (floats): z_proj [64*128] | x_node [NN*64] | x_graph [64*128]
constexpr long OUT_XNODE = 8192;
constexpr long OUT_XG    = 8192 + 6400000L;

using bf16x8 = __attribute__((ext_vector_type(8))) short;
using f32x16 = __attribute__((ext_vector_type(16))) float;

__device__ __forceinline__ unsigned short f2bf(float f) {
    return __builtin_bit_cast(unsigned short, __float2bfloat16(f));
}
__device__ __forceinline__ unsigned fenc(float f) {
    unsigned u = __float_as_uint(f);
    return (u & 0x80000000u) ? ~u : (u | 0x80000000u);
}
__device__ __forceinline__ float fdec(unsigned u) {
    return (u & 0x80000000u) ? __uint_as_float(u & 0x7fffffffu) : __uint_as_float(~u);
}
// (P_dword, Q_dword) -> relu(P+Q) packed bf16 dword
__device__ __forceinline__ unsigned addrelu_pack(unsigned p, unsigned q) {
    const float pl = __uint_as_float(p << 16), ph = __uint_as_float(p & 0xffff0000u);
    const float ql = __uint_as_float(q << 16), qh = __uint_as_float(q & 0xffff0000u);
    const float lo = fmaxf(pl + ql, 0.f), hi = fmaxf(ph + qh, 0.f);
    return (unsigned)f2bf(lo) | ((unsigned)f2bf(hi) << 16);
}

// ---------------- counting sort of edges by dst ----------------
__global__ __launch_bounds__(256) void count_kernel(
    const int* __restrict__ dst, int* __restrict__ cnt)
{
    const int e = blockIdx.x * 256 + threadIdx.x;
    if (e < NE) atomicAdd(cnt + dst[e], 1);
}

__global__ __launch_bounds__(256) void scan_local_kernel(
    const int* __restrict__ cnt, int* __restrict__ cursor, int* __restrict__ bsum)
{
    __shared__ int tmp[256];
    const int t = threadIdx.x;
    const int v = blockIdx.x * 256 + t;
    const int c = (v < NN) ? cnt[v] : 0;
    tmp[t] = c;
    __syncthreads();
    for (int off = 1; off < 256; off <<= 1) {
        const int u = (t >= off) ? tmp[t - off] : 0;
        __syncthreads();
        tmp[t] += u;
        __syncthreads();
    }
    if (v < NN) cursor[v] = tmp[t] - c;
    if (t == 255) bsum[blockIdx.x] = tmp[255];
}

__global__ __launch_bounds__(512) void scan_blocks_kernel(int* __restrict__ bsum)
{
    __shared__ int tmp[512];
    const int t = threadIdx.x;
    const int v = (t < SCAN_NB) ? bsum[t] : 0;
    tmp[t] = v;
    __syncthreads();
    for (int off = 1; off < 512; off <<= 1) {
        const int u = (t >= off) ? tmp[t - off] : 0;
        __syncthreads();
        tmp[t] += u;
        __syncthreads();
    }
    if (t < SCAN_NB) bsum[t] = tmp[t] - v;
}

__global__ __launch_bounds__(256) void scan_add_kernel(
    int* __restrict__ cursor, const int* __restrict__ bsum)
{
    const int v = blockIdx.x * 256 + threadIdx.x;
    if (v < NN) cursor[v] += bsum[blockIdx.x];
}

// scatter: materialize dst-sorted (src,dst) pairs -> conv reads are sequential
__global__ __launch_bounds__(256) void scatter_kernel(
    const int* __restrict__ src, const int* __restrict__ dst,
    int* __restrict__ cursor, int2* __restrict__ sedge)
{
    const int e = blockIdx.x * 256 + threadIdx.x;
    if (e < NE) {
        const int d = dst[e];
        const int pos = atomicAdd(cursor + d, 1);
        sedge[pos] = make_int2(src[e], d);
    }
}

// ---------------- weight prep: fragment-ordered bf16 ----------------
// sec 0: Wp = W1a - W1b (8 frags), sec 1: Wq = W1b (8), sec 2: W2 (8)
// frag f = t*4+ks; elem = f*512 + ln*8 + i; A[m=ln&31][k=(ln>>5)*8+i], k_abs=ks*16+..., c=t*32+m
__global__ __launch_bounds__(256) void prep_weights(
    const float* __restrict__ w1, const float* __restrict__ w2,
    unsigned short* __restrict__ wf)
{
    const int idx = blockIdx.x * 256 + threadIdx.x;
    if (idx >= 12288) return;
    const int sec = idx >> 12;
    const int j = idx & 4095;
    const int f = j >> 9, rem = j & 511, ln = rem >> 3, i = rem & 7;
    const int t = f >> 2, ks = f & 3;
    const int k = ks * 16 + (ln >> 5) * 8 + i, c = t * 32 + (ln & 31);
    float v;
    if (sec == 0)      v = w1[k * 64 + c] - w1[(64 + k) * 64 + c];
    else if (sec == 1) v = w1[(64 + k) * 64 + c];
    else               v = w2[k * 64 + c];
    wf[idx] = f2bf(v);
}

// ---------------- node GEMM: P = (W1a-W1b)x + b1, Q = W1b x  (bf16 out) -------------
template<bool NORM>
__global__ __launch_bounds__(256) void nodegemm_kernel(
    const float* __restrict__ x,
    const unsigned short* __restrict__ wfrag,   // Wp at 0, Wq at 4096
    const float* __restrict__ b1,
    const float* __restrict__ scale, const float* __restrict__ shift,
    unsigned short* __restrict__ P, unsigned short* __restrict__ Q)
{
    __shared__ unsigned short wlds[8192];  // 16 KB: Wp | Wq fragments
    {
        const uint4* wsrc = reinterpret_cast<const uint4*>(wfrag);
        uint4* wdst = reinterpret_cast<uint4*>(wlds);
        #pragma unroll
        for (int i = 0; i < 4; ++i) wdst[threadIdx.x + i * 256] = wsrc[threadIdx.x + i * 256];
    }
    __syncthreads();

    const int wid = threadIdx.x >> 6, lane = threadIdx.x & 63;
    const int hi = lane >> 5, ln32 = lane & 31;
    const int tile = blockIdx.x * 4 + wid;
    if (tile >= NNTILES) return;
    const int node = tile * 32 + ln32;
    const float* __restrict__ xr = x + (long)node * 64;

    f32x16 cpa, cpb, cqa, cqb;
    #pragma unroll
    for (int r = 0; r < 16; ++r) {
        const int row = (r & 3) + 8 * (r >> 2) + 4 * hi;
        cpa[r] = b1[row]; cpb[r] = b1[32 + row];
        cqa[r] = 0.f;     cqb[r] = 0.f;
    }

    #pragma unroll
    for (int ks = 0; ks < 4; ++ks) {
        const int off = ks * 16 + hi * 8;
        float4 a = *reinterpret_cast<const float4*>(xr + off);
        float4 b = *reinterpret_cast<const float4*>(xr + off + 4);
        if (NORM) {
            const float4 s0 = *reinterpret_cast<const float4*>(scale + off);
            const float4 s1 = *reinterpret_cast<const float4*>(scale + off + 4);
            const float4 h0 = *reinterpret_cast<const float4*>(shift + off);
            const float4 h1 = *reinterpret_cast<const float4*>(shift + off + 4);
            a.x = fmaf(a.x, s0.x, h0.x); a.y = fmaf(a.y, s0.y, h0.y);
            a.z = fmaf(a.z, s0.z, h0.z); a.w = fmaf(a.w, s0.w, h0.w);
            b.x = fmaf(b.x, s1.x, h1.x); b.y = fmaf(b.y, s1.y, h1.y);
            b.z = fmaf(b.z, s1.z, h1.z); b.w = fmaf(b.w, s1.w, h1.w);
        }
        bf16x8 bfr;
        bfr[0] = (short)f2bf(a.x); bfr[1] = (short)f2bf(a.y);
        bfr[2] = (short)f2bf(a.z); bfr[3] = (short)f2bf(a.w);
        bfr[4] = (short)f2bf(b.x); bfr[5] = (short)f2bf(b.y);
        bfr[6] = (short)f2bf(b.z); bfr[7] = (short)f2bf(b.w);
        const bf16x8 ap0 = *reinterpret_cast<const bf16x8*>(&wlds[(0 * 4 + ks) * 512 + lane * 8]);
        const bf16x8 ap1 = *reinterpret_cast<const bf16x8*>(&wlds[(1 * 4 + ks) * 512 + lane * 8]);
        const bf16x8 aq0 = *reinterpret_cast<const bf16x8*>(&wlds[4096 + (0 * 4 + ks) * 512 + lane * 8]);
        const bf16x8 aq1 = *reinterpret_cast<const bf16x8*>(&wlds[4096 + (1 * 4 + ks) * 512 + lane * 8]);
        cpa = __builtin_amdgcn_mfma_f32_32x32x16_bf16(ap0, bfr, cpa, 0, 0, 0);
        cpb = __builtin_amdgcn_mfma_f32_32x32x16_bf16(ap1, bfr, cpb, 0, 0, 0);
        cqa = __builtin_amdgcn_mfma_f32_32x32x16_bf16(aq0, bfr, cqa, 0, 0, 0);
        cqb = __builtin_amdgcn_mfma_f32_32x32x16_bf16(aq1, bfr, cqb, 0, 0, 0);
    }

    // store bf16 rows: lane holds channels t*32 + 8*g2 + 4*hi + {0..3} in regs 4*g2..4*g2+3
    unsigned short* Pr = P + (long)node * 64;
    unsigned short* Qr = Q + (long)node * 64;
    #pragma unroll
    for (int t = 0; t < 2; ++t) {
        const f32x16 cp = t ? cpb : cpa;
        const f32x16 cq = t ? cqb : cqa;
        #pragma unroll
        for (int g2 = 0; g2 < 4; ++g2) {
            uint2 up, uq;
            up.x = (unsigned)f2bf(cp[4 * g2 + 0]) | ((unsigned)f2bf(cp[4 * g2 + 1]) << 16);
            up.y = (unsigned)f2bf(cp[4 * g2 + 2]) | ((unsigned)f2bf(cp[4 * g2 + 3]) << 16);
            uq.x = (unsigned)f2bf(cq[4 * g2 + 0]) | ((unsigned)f2bf(cq[4 * g2 + 1]) << 16);
            uq.y = (unsigned)f2bf(cq[4 * g2 + 2]) | ((unsigned)f2bf(cq[4 * g2 + 3]) << 16);
            const int co = t * 32 + 8 * g2 + 4 * hi;
            *reinterpret_cast<uint2*>(Pr + co) = up;
            *reinterpret_cast<uint2*>(Qr + co) = uq;
        }
    }
}

// ---------------- EdgeConv layer-2: wave = 32 sorted edges ----------------
// h_e = relu(P[d] + Q[s]); out = relu(h @ W2 + b2); segmented max; atomic-free stores.
__global__ __launch_bounds__(256) void edgeconv_kernel(
    const unsigned short* __restrict__ P, const unsigned short* __restrict__ Q,
    const int2* __restrict__ sedge,
    const unsigned short* __restrict__ w2frag,   // W2 section (4096 u16)
    const float* __restrict__ b2,
    float* __restrict__ out, int* __restrict__ recd, float* __restrict__ recv)
{
    __shared__ unsigned short wlds[4096];        // 8 KB W2 fragments
    {
        const uint4* wsrc = reinterpret_cast<const uint4*>(w2frag);
        uint4* wdst = reinterpret_cast<uint4*>(wlds);
        #pragma unroll
        for (int i = 0; i < 2; ++i) wdst[threadIdx.x + i * 256] = wsrc[threadIdx.x + i * 256];
    }
    __syncthreads();

    const int wid  = threadIdx.x >> 6;
    const int lane = threadIdx.x & 63;
    const int hi   = lane >> 5;
    const int ln32 = lane & 31;
    const int tile = blockIdx.x * 4 + wid;
    if (tile >= NTILES) return;

    const int2 sd = sedge[tile * 32 + ln32];
    const int s = sd.x, d = sd.y;
    const unsigned short* __restrict__ Pr = P + (long)d * 64;
    const unsigned short* __restrict__ Qr = Q + (long)s * 64;

    f32x16 c2a, c2b;
    #pragma unroll
    for (int r = 0; r < 16; ++r) {
        const int row = (r & 3) + 8 * (r >> 2) + 4 * hi;
        c2a[r] = b2[row];
        c2b[r] = b2[32 + row];
    }

    #pragma unroll
    for (int ks = 0; ks < 4; ++ks) {
        const int co = ks * 16 + hi * 8;
        const uint4 pu = *reinterpret_cast<const uint4*>(Pr + co);
        const uint4 qu = *reinterpret_cast<const uint4*>(Qr + co);
        uint4 hr;
        hr.x = addrelu_pack(pu.x, qu.x);
        hr.y = addrelu_pack(pu.y, qu.y);
        hr.z = addrelu_pack(pu.z, qu.z);
        hr.w = addrelu_pack(pu.w, qu.w);
        const bf16x8 bfr = __builtin_bit_cast(bf16x8, hr);
        const bf16x8 a0 = *reinterpret_cast<const bf16x8*>(&wlds[(0 * 4 + ks) * 512 + lane * 8]);
        const bf16x8 a1 = *reinterpret_cast<const bf16x8*>(&wlds[(1 * 4 + ks) * 512 + lane * 8]);
        c2a = __builtin_amdgcn_mfma_f32_32x32x16_bf16(a0, bfr, c2a, 0, 0, 0);
        c2b = __builtin_amdgcn_mfma_f32_32x32x16_bf16(a1, bfr, c2b, 0, 0, 0);
    }

    #pragma unroll
    for (int r = 0; r < 16; ++r) {
        c2a[r] = fmaxf(c2a[r], 0.f);
        c2b[r] = fmaxf(c2b[r], 0.f);
    }

    // segmented max over edges within each 32-lane half (keys = d, sorted)
    #pragma unroll
    for (int st = 1; st < 32; st <<= 1) {
        const int dn = __shfl_down(d, st, 32);
        const bool take = (ln32 + st < 32) && (dn == d);
        #pragma unroll
        for (int r = 0; r < 16; ++r) {
            const float oa = __shfl_down(c2a[r], st, 32);
            const float ob = __shfl_down(c2b[r], st, 32);
            if (take) { c2a[r] = fmaxf(c2a[r], oa); c2b[r] = fmaxf(c2b[r], ob); }
        }
    }
    const int dprev = __shfl_up(d, 1, 32);
    const bool leader = (ln32 == 0) || (d != dprev);
    const unsigned lm = (unsigned)(__ballot(leader) & 0xffffffffull);
    const int L31 = 31 - __builtin_clz(lm);

    if (leader) {
        float4 va[4], vb[4];
        #pragma unroll
        for (int q = 0; q < 4; ++q) {
            va[q].x = c2a[4 * q]; va[q].y = c2a[4 * q + 1];
            va[q].z = c2a[4 * q + 2]; va[q].w = c2a[4 * q + 3];
            vb[q].x = c2b[4 * q]; vb[q].y = c2b[4 * q + 1];
            vb[q].z = c2b[4 * q + 2]; vb[q].w = c2b[4 * q + 3];
        }
        if (ln32 != 0 && ln32 != L31) {
            float* row = out + (long)d * 64;
            #pragma unroll
            for (int q = 0; q < 4; ++q) {
                *reinterpret_cast<float4*>(row + 8 * q + 4 * hi) = va[q];
                *reinterpret_cast<float4*>(row + 32 + 8 * q + 4 * hi) = vb[q];
            }
        }
        if (ln32 == 0) {
            float* row = recv + (long)(tile * 2) * 64;
            #pragma unroll
            for (int q = 0; q < 4; ++q) {
                *reinterpret_cast<float4*>(row + 8 * q + 4 * hi) = va[q];
                *reinterpret_cast<float4*>(row + 32 + 8 * q + 4 * hi) = vb[q];
            }
            if (hi == 0) recd[tile * 2] = d;
        }
        if (ln32 == L31) {
            float* row = recv + (long)(tile * 2 + 1) * 64;
            #pragma unroll
            for (int q = 0; q < 4; ++q) {
                *reinterpret_cast<float4*>(row + 8 * q + 4 * hi) = va[q];
                *reinterpret_cast<float4*>(row + 32 + 8 * q + 4 * hi) = vb[q];
            }
            if (hi == 0) recd[tile * 2 + 1] = d;
        }
    }
}

// ---------------- fixup: combine boundary records (runs of equal dst) ----------------
__global__ __launch_bounds__(256) void fixup_kernel(
    const int* __restrict__ recd, const float* __restrict__ recv,
    float* __restrict__ out)
{
    const int wid = threadIdx.x >> 6, lane = threadIdx.x & 63;
    const int r = blockIdx.x * 4 + wid;
    if (r >= NREC) return;
    const int d = recd[r];
    int lo = r, hi = r;
    while (lo > 0 && recd[lo - 1] == d) --lo;
    while (hi + 1 < NREC && recd[hi + 1] == d) ++hi;
    float m = 0.f;
    for (int rr = lo; rr <= hi; ++rr) m = fmaxf(m, recv[(long)rr * 64 + lane]);
    out[(long)d * 64 + lane] = m;
}

// ---------------- BN stats: deterministic two-stage ----------------
__global__ __launch_bounds__(256) void stats_kernel(
    const float* __restrict__ h, float* __restrict__ partial)
{
    __shared__ float red[2][256];
    const int tid = threadIdx.x;
    const int c = tid & 63, r = tid >> 6;
    float s = 0.f, ss = 0.f;
    for (int v = blockIdx.x * 4 + r; v < NN; v += 256 * 4) {
        const float val = h[(long)v * 64 + c];
        s += val; ss += val * val;
    }
    red[0][tid] = s; red[1][tid] = ss;
    __syncthreads();
    if (r == 0) {
        float S = 0.f, SS = 0.f;
        #pragma unroll
        for (int q = 0; q < 4; ++q) { S += red[0][c + q * 64]; SS += red[1][c + q * 64]; }
        partial[blockIdx.x * 128 + c] = S;
        partial[blockIdx.x * 128 + 64 + c] = SS;
    }
}

__global__ void bn_finalize_kernel(
    const float* __restrict__ partial,
    const float* __restrict__ g, const float* __restrict__ b,
    float* __restrict__ scale, float* __restrict__ shift)
{
    const int c = threadIdx.x;
    float S = 0.f, SS = 0.f;
    for (int bb = 0; bb < 256; ++bb) {
        S += partial[bb * 128 + c];
        SS += partial[bb * 128 + 64 + c];
    }
    const float invN = 1.0f / (float)NN;
    const float mu = S * invN;
    const float var = SS * invN - mu * mu;
    const float sc = g[c] * rsqrtf(var + BN_EPS);
    scale[c] = sc;
    shift[c] = b[c] - mu * sc;
}

// ---------------- node pass: BN2 normalize in place + segmented pooling ----------------
constexpr int NPB = 512;
__global__ __launch_bounds__(256) void nodepass_kernel(
    float* __restrict__ xn, const int* __restrict__ batch,
    const float* __restrict__ scale, const float* __restrict__ shift,
    float* __restrict__ poolsum, unsigned* __restrict__ poolmax, int* __restrict__ counts)
{
    const int base = blockIdx.x * NPB;
    const int r = threadIdx.x >> 6, c = threadIdx.x & 63;
    int curg = -1; float rs = 0.f, rm = -INFINITY; int rc = 0;
    const int vend = (base + NPB < NN) ? base + NPB : NN;
    for (int v = base + r; v < vend; v += 4) {
        const long idx = (long)v * 64 + c;
        const float val = fmaf(xn[idx], scale[c], shift[c]);
        xn[idx] = val;
        const int g = batch[v];
        if (g != curg) {
            if (curg >= 0) {
                atomicAdd(poolsum + curg * 64 + c, rs);
                atomicMax(poolmax + curg * 64 + c, fenc(rm));
                if (c == 0) atomicAdd(counts + curg, rc);
            }
            curg = g; rs = 0.f; rm = -INFINITY; rc = 0;
        }
        rs += val; rm = fmaxf(rm, val); ++rc;
    }
    if (curg >= 0) {
        atomicAdd(poolsum + curg * 64 + c, rs);
        atomicMax(poolmax + curg * 64 + c, fenc(rm));
        if (c == 0) atomicAdd(counts + curg, rc);
    }
}

// ---------------- final: x_graph + projector MLP + BN + out ----------------
__global__ __launch_bounds__(512) void final_kernel(
    const float* __restrict__ poolsum, const unsigned* __restrict__ poolmax,
    const int* __restrict__ counts,
    const float* __restrict__ p_w1, const float* __restrict__ p_b1,
    const float* __restrict__ p_bng, const float* __restrict__ p_bnb,
    const float* __restrict__ p_w2, const float* __restrict__ p_b2,
    float* __restrict__ out)
{
    __shared__ float xg[64][128];
    __shared__ float znl[64 * 129];
    __shared__ float red[2][512];
    __shared__ float scsh[2][128];
    const int tid = threadIdx.x;

    #pragma unroll
    for (int i = 0; i < 16; ++i) {
        const int e2 = tid + i * 512;
        const int g = e2 >> 7, col = e2 & 127;
        float val;
        if (col < 64) {
            const float cnt = fmaxf((float)counts[g], 1.f);
            val = poolsum[g * 64 + col] / cnt;
        } else {
            const unsigned u = poolmax[g * 64 + col - 64];
            val = (u == 0u) ? 0.f : fdec(u);
        }
        xg[g][col] = val;
        out[OUT_XG + e2] = val;
    }
    __syncthreads();

    const int gg = tid >> 7, t = tid & 127;
    float z[16];
    #pragma unroll
    for (int gi = 0; gi < 16; ++gi) z[gi] = p_b1[t];
    for (int j = 0; j < 128; ++j) {
        const float wv = p_w1[j * 128 + t];
        #pragma unroll
        for (int gi = 0; gi < 16; ++gi) z[gi] = fmaf(xg[gg * 16 + gi][j], wv, z[gi]);
    }

    float s = 0.f, ss = 0.f;
    #pragma unroll
    for (int gi = 0; gi < 16; ++gi) { s += z[gi]; ss += z[gi] * z[gi]; }
    red[0][tid] = s; red[1][tid] = ss;
    __syncthreads();
    if (gg == 0) {
        float S = 0.f, SS = 0.f;
        #pragma unroll
        for (int q = 0; q < 4; ++q) { S += red[0][t + q * 128]; SS += red[1][t + q * 128]; }
        const float mu = S / 64.f;
        const float var = SS / 64.f - mu * mu;
        const float sc = p_bng[t] * rsqrtf(var + BN_EPS);
        scsh[0][t] = sc;
        scsh[1][t] = p_bnb[t] - mu * sc;
    }
    __syncthreads();
    const float sc = scsh[0][t], sh = scsh[1][t];
    #pragma unroll
    for (int gi = 0; gi < 16; ++gi) {
        const float zn = fmaxf(fmaf(z[gi], sc, sh), 0.f);
        znl[(gg * 16 + gi) * 129 + t] = zn;
    }
    __syncthreads();

    float zp[16];
    #pragma unroll
    for (int gi = 0; gi < 16; ++gi) zp[gi] = p_b2[t];
    for (int c = 0; c < 128; ++c) {
        const float wv = p_w2[c * 128 + t];
        #pragma unroll
        for (int gi = 0; gi < 16; ++gi) zp[gi] = fmaf(znl[(gg * 16 + gi) * 129 + c], wv, zp[gi]);
    }
    #pragma unroll
    for (int gi = 0; gi < 16; ++gi) out[(gg * 16 + gi) * 128 + t] = zp[gi];
}

// ---------------- launch ----------------
extern "C" void kernel_launch(void* const* d_in, const int* in_sizes, int n_in,
                              void* d_out, int out_size, void* d_ws, size_t ws_size,
                              hipStream_t stream)
{
    const float* x     = (const float*)d_in[0];
    const int*   eidx  = (const int*)d_in[1];
    const int*   batch = (const int*)d_in[2];
    const float* c1w1  = (const float*)d_in[3];
    const float* c1b1  = (const float*)d_in[4];
    const float* c1w2  = (const float*)d_in[5];
    const float* c1b2  = (const float*)d_in[6];
    const float* bn1g  = (const float*)d_in[7];
    const float* bn1b  = (const float*)d_in[8];
    const float* c2w1  = (const float*)d_in[9];
    const float* c2b1  = (const float*)d_in[10];
    const float* c2w2  = (const float*)d_in[11];
    const float* c2b2  = (const float*)d_in[12];
    const float* bn2g  = (const float*)d_in[13];
    const float* bn2b  = (const float*)d_in[14];
    const float* pw1   = (const float*)d_in[15];
    const float* pb1   = (const float*)d_in[16];
    const float* pbng  = (const float*)d_in[17];
    const float* pbnb  = (const float*)d_in[18];
    const float* pw2   = (const float*)d_in[19];
    const float* pb2   = (const float*)d_in[20];

    const int* src = eidx;
    const int* dst = eidx + NE;

    float* ws  = (float*)d_ws;
    float* o   = (float*)d_out;
    float* h1  = ws + H1_OFF;
    float* xnode = o + OUT_XNODE;
    int* scnt  = (int*)(ws + SCNT_OFF);
    int* curs  = (int*)(ws + CURS_OFF);
    int2* sedge = (int2*)(ws + SEDG_OFF);
    int* bsum  = (int*)(ws + PART_OFF);    // reuse stats-partial region
    unsigned short* wf1 = (unsigned short*)(ws + WF1_OFF);
    unsigned short* wf2 = (unsigned short*)(ws + WF2_OFF);
    int* recd  = (int*)(ws + RECD_OFF);
    float* recv = ws + RECV_OFF;
    unsigned short* Pb = (unsigned short*)(ws + P_OFF);
    unsigned short* Qb = (unsigned short*)(ws + Q_OFF);

    // zero accumulators
    hipMemsetAsync(h1, 0, (size_t)NN * 64 * 4, stream);
    hipMemsetAsync(xnode, 0, (size_t)NN * 64 * 4, stream);
    hipMemsetAsync(ws + PSUM_OFF, 0, (4096 + 4096 + 64) * 4, stream);
    hipMemsetAsync(scnt, 0, (size_t)NN * 4, stream);

    // weight prep (both convs)
    prep_weights<<<48, 256, 0, stream>>>(c1w1, c1w2, wf1);
    prep_weights<<<48, 256, 0, stream>>>(c2w1, c2w2, wf2);

    // counting sort of edges by dst (hierarchical scan), materializing (src,dst) pairs
    const int eGrid = (NE + 255) / 256;
    count_kernel<<<eGrid, 256, 0, stream>>>(dst, scnt);
    scan_local_kernel<<<SCAN_NB, 256, 0, stream>>>(scnt, curs, bsum);
    scan_blocks_kernel<<<1, 512, 0, stream>>>(bsum);
    scan_add_kernel<<<SCAN_NB, 256, 0, stream>>>(curs, bsum);
    scatter_kernel<<<eGrid, 256, 0, stream>>>(src, dst, curs, sedge);

    const int ngGrid   = (NNTILES + 3) / 4;
    const int convGrid = (NTILES + 3) / 4;
    const int fixGrid  = (NREC + 3) / 4;

    // conv1: node GEMM (P,Q) then edge pass -> h1
    nodegemm_kernel<false><<<ngGrid, 256, 0, stream>>>(
        x, wf1, c1b1, nullptr, nullptr, Pb, Qb);
    edgeconv_kernel<<<convGrid, 256, 0, stream>>>(
        Pb, Qb, sedge, wf1 + 8192, c1b2, h1, recd, recv);
    fixup_kernel<<<fixGrid, 256, 0, stream>>>(recd, recv, h1);
    // BN1 stats
    stats_kernel<<<256, 256, 0, stream>>>(h1, ws + PART_OFF);
    bn_finalize_kernel<<<1, 64, 0, stream>>>(ws + PART_OFF, bn1g, bn1b,
                                             ws + SC1_OFF, ws + SH1_OFF);
    // conv2: node GEMM on normalized h1, then edge pass -> xnode
    nodegemm_kernel<true><<<ngGrid, 256, 0, stream>>>(
        h1, wf2, c2b1, ws + SC1_OFF, ws + SH1_OFF, Pb, Qb);
    edgeconv_kernel<<<convGrid, 256, 0, stream>>>(
        Pb, Qb, sedge, wf2 + 8192, c2b2, xnode, recd, recv);
    fixup_kernel<<<fixGrid, 256, 0, stream>>>(recd, recv, xnode);
    // BN2 stats
    stats_kernel<<<256, 256, 0, stream>>>(xnode, ws + PART_OFF);
    bn_finalize_kernel<<<1, 64, 0, stream>>>(ws + PART_OFF, bn2g, bn2b,
                                             ws + SC2_OFF, ws + SH2_OFF);
    // normalize x_node + pooling
    nodepass_kernel<<<(NN + NPB - 1) / NPB, 256, 0, stream>>>(
        xnode, batch, ws + SC2_OFF, ws + SH2_OFF,
        ws + PSUM_OFF, (unsigned*)(ws + PMAX_OFF), (int*)(ws + CNT_OFF));
    // x_graph + projector
    final_kernel<<<1, 512, 0, stream>>>(
        ws + PSUM_OFF, (unsigned*)(ws + PMAX_OFF), (int*)(ws + CNT_OFF),
        pw1, pb1, pbng, pbnb, pw2, pb2, o);
}

// Round 6
// 439.641 us; speedup vs baseline: 14.0348x; 1.1578x over previous
//
#include <hip/hip_runtime.h>
#include <hip/hip_bf16.h>

// ---------------- problem constants ----------------
constexpr int NN = 100000;   // nodes
constexpr int NE = 1000000;  // edges
constexpr int NG = 64;       // graphs
constexpr float BN_EPS = 1e-5f;
constexpr int NTILES = NE / 32;      // 31250 wave-tiles of 32 edges
constexpr int NNTILES = NN / 32;     // 3125 node tiles
constexpr int NREC = NTILES * 2;     // 62500 boundary records

// two-level binned counting sort
constexpr int NBUK = 98;             // buckets of 1024 nodes (dst >> 10)
constexpr int BINB = 256;            // binning blocks
constexpr int BCHUNK = (NE + BINB - 1) / BINB;  // 3907 edges per block
constexpr int TABN = NBUK * BINB;    // 25088 scan-table entries

// ws layout (in floats)
constexpr long H1_OFF   = 0;                       // [NN*64] conv1 out; first 2M = ebin staging
constexpr long PART_OFF = 6400000;                 // [256*128] BN stat partials
constexpr long SC1_OFF  = PART_OFF + 32768;        // [64]
constexpr long SH1_OFF  = SC1_OFF + 64;
constexpr long SC2_OFF  = SH1_OFF + 64;
constexpr long SH2_OFF  = SC2_OFF + 64;
constexpr long PSUM_OFF = SH2_OFF + 64;            // [64*64]
constexpr long PMAX_OFF = PSUM_OFF + 4096;         // [64*64]
constexpr long CNT_OFF  = PMAX_OFF + 4096;         // [64]
constexpr long TAB_OFF  = CNT_OFF + 64;            // [25088] bin scan table (int)
constexpr long SEDG_OFF = TAB_OFF + 100000;        // [NE int2] sorted (src,dst) = 2M floats
constexpr long WF1_OFF  = SEDG_OFF + 2000000;      // 12288 u16 = 6144 float slots
constexpr long WF2_OFF  = WF1_OFF + 6144;          // 12288 u16
constexpr long RECD_OFF = WF2_OFF + 6144;          // [62500] record dst (int), pad->62528
constexpr long RECV_OFF = RECD_OFF + 62528;        // [62500*64] record values
constexpr long P_OFF    = RECV_OFF + 4000000;      // [NN*64 bf16] = 3.2M floats
constexpr long Q_OFF    = P_OFF + 3200000;         // [NN*64 bf16]

// d_out layout (floats): z_proj [64*128] | x_node [NN*64] | x_graph [64*128]
constexpr long OUT_XNODE = 8192;
constexpr long OUT_XG    = 8192 + 6400000L;

using bf16x8 = __attribute__((ext_vector_type(8))) short;
using f32x16 = __attribute__((ext_vector_type(16))) float;

__device__ __forceinline__ unsigned short f2bf(float f) {
    return __builtin_bit_cast(unsigned short, __float2bfloat16(f));
}
__device__ __forceinline__ unsigned fenc(float f) {
    unsigned u = __float_as_uint(f);
    return (u & 0x80000000u) ? ~u : (u | 0x80000000u);
}
__device__ __forceinline__ float fdec(unsigned u) {
    return (u & 0x80000000u) ? __uint_as_float(u & 0x7fffffffu) : __uint_as_float(~u);
}
// (P_dword, Q_dword) -> relu(P+Q) packed bf16 dword
__device__ __forceinline__ unsigned addrelu_pack(unsigned p, unsigned q) {
    const float pl = __uint_as_float(p << 16), ph = __uint_as_float(p & 0xffff0000u);
    const float ql = __uint_as_float(q << 16), qh = __uint_as_float(q & 0xffff0000u);
    const float lo = fmaxf(pl + ql, 0.f), hi = fmaxf(ph + qh, 0.f);
    return (unsigned)f2bf(lo) | ((unsigned)f2bf(hi) << 16);
}

// ---------------- two-level binned counting sort ----------------
// pass A: per-block bucket histogram (LDS), table[k*BINB + b] = count
__global__ __launch_bounds__(256) void bin_hist_kernel(
    const int* __restrict__ dst, int* __restrict__ tab)
{
    __shared__ int cnt[NBUK];
    const int t = threadIdx.x, b = blockIdx.x;
    if (t < NBUK) cnt[t] = 0;
    __syncthreads();
    const int lo = b * BCHUNK;
    const int hi = (lo + BCHUNK < NE) ? lo + BCHUNK : NE;
    for (int e = lo + t; e < hi; e += 256) atomicAdd(&cnt[dst[e] >> 10], 1);
    __syncthreads();
    if (t < NBUK) tab[t * BINB + b] = cnt[t];
}

// pass B: exclusive scan of the 25088-entry table in place (one block)
__global__ __launch_bounds__(1024) void scan_tab_kernel(int* __restrict__ tab)
{
    __shared__ int part[1024];
    const int t = threadIdx.x;
    constexpr int VPT = 25;  // 1024*25 >= TABN
    int vals[VPT];
    const int base = t * VPT;
    int s = 0;
    #pragma unroll
    for (int i = 0; i < VPT; ++i) {
        const int idx = base + i;
        const int v = (idx < TABN) ? tab[idx] : 0;
        vals[i] = v; s += v;
    }
    part[t] = s;
    __syncthreads();
    for (int off = 1; off < 1024; off <<= 1) {
        const int u = (t >= off) ? part[t - off] : 0;
        __syncthreads();
        part[t] += u;
        __syncthreads();
    }
    int run = (t == 0) ? 0 : part[t - 1];
    #pragma unroll
    for (int i = 0; i < VPT; ++i) {
        const int idx = base + i;
        if (idx < TABN) { const int v = vals[i]; tab[idx] = run; run += v; }
    }
}

// pass C: scatter edges into per-(bucket,block) contiguous runs (clustered writes)
__global__ __launch_bounds__(256) void bin_scatter_kernel(
    const int* __restrict__ src, const int* __restrict__ dst,
    const int* __restrict__ tab, int2* __restrict__ ebin)
{
    __shared__ int basec[NBUK];
    __shared__ int cur[NBUK];
    const int t = threadIdx.x, b = blockIdx.x;
    if (t < NBUK) { basec[t] = tab[t * BINB + b]; cur[t] = 0; }
    __syncthreads();
    const int lo = b * BCHUNK;
    const int hi = (lo + BCHUNK < NE) ? lo + BCHUNK : NE;
    for (int e = lo + t; e < hi; e += 256) {
        const int d = dst[e];
        const int k = d >> 10;
        const int pos = basec[k] + atomicAdd(&cur[k], 1);
        ebin[pos] = make_int2(src[e], d);
    }
}

// pass D: per-bucket counting sort over 1024 local node slots -> fully dst-sorted
__global__ __launch_bounds__(256) void bucket_sort_kernel(
    const int2* __restrict__ ebin, const int* __restrict__ tab,
    int2* __restrict__ sedge)
{
    __shared__ int hist[1024];
    __shared__ int part[256];
    const int t = threadIdx.x, k = blockIdx.x;
    const int start = tab[k * BINB];
    const int end = (k == NBUK - 1) ? NE : tab[(k + 1) * BINB];
    #pragma unroll
    for (int i = 0; i < 4; ++i) hist[t * 4 + i] = 0;
    __syncthreads();
    for (int e = start + t; e < end; e += 256) atomicAdd(&hist[ebin[e].y & 1023], 1);
    __syncthreads();
    const int v0 = hist[t*4], v1 = hist[t*4+1], v2 = hist[t*4+2], v3 = hist[t*4+3];
    part[t] = v0 + v1 + v2 + v3;
    __syncthreads();
    for (int off = 1; off < 256; off <<= 1) {
        const int u = (t >= off) ? part[t - off] : 0;
        __syncthreads();
        part[t] += u;
        __syncthreads();
    }
    int run = (t == 0) ? 0 : part[t - 1];
    hist[t*4]   = run;
    hist[t*4+1] = run + v0;
    hist[t*4+2] = run + v0 + v1;
    hist[t*4+3] = run + v0 + v1 + v2;
    __syncthreads();
    for (int e = start + t; e < end; e += 256) {
        const int2 v = ebin[e];
        const int pos = start + atomicAdd(&hist[v.y & 1023], 1);
        sedge[pos] = v;
    }
}

// ---------------- weight prep: fragment-ordered bf16 ----------------
// sec 0: Wp = W1a - W1b (8 frags), sec 1: Wq = W1b (8), sec 2: W2 (8)
__global__ __launch_bounds__(256) void prep_weights(
    const float* __restrict__ w1, const float* __restrict__ w2,
    unsigned short* __restrict__ wf)
{
    const int idx = blockIdx.x * 256 + threadIdx.x;
    if (idx >= 12288) return;
    const int sec = idx >> 12;
    const int j = idx & 4095;
    const int f = j >> 9, rem = j & 511, ln = rem >> 3, i = rem & 7;
    const int t = f >> 2, ks = f & 3;
    const int k = ks * 16 + (ln >> 5) * 8 + i, c = t * 32 + (ln & 31);
    float v;
    if (sec == 0)      v = w1[k * 64 + c] - w1[(64 + k) * 64 + c];
    else if (sec == 1) v = w1[(64 + k) * 64 + c];
    else               v = w2[k * 64 + c];
    wf[idx] = f2bf(v);
}

// ---------------- node GEMM: P = (W1a-W1b)x + b1, Q = W1b x  (bf16 out) -------------
template<bool NORM>
__global__ __launch_bounds__(256) void nodegemm_kernel(
    const float* __restrict__ x,
    const unsigned short* __restrict__ wfrag,
    const float* __restrict__ b1,
    const float* __restrict__ scale, const float* __restrict__ shift,
    unsigned short* __restrict__ P, unsigned short* __restrict__ Q)
{
    __shared__ unsigned short wlds[8192];
    {
        const uint4* wsrc = reinterpret_cast<const uint4*>(wfrag);
        uint4* wdst = reinterpret_cast<uint4*>(wlds);
        #pragma unroll
        for (int i = 0; i < 4; ++i) wdst[threadIdx.x + i * 256] = wsrc[threadIdx.x + i * 256];
    }
    __syncthreads();

    const int wid = threadIdx.x >> 6, lane = threadIdx.x & 63;
    const int hi = lane >> 5, ln32 = lane & 31;
    const int tile = blockIdx.x * 4 + wid;
    if (tile >= NNTILES) return;
    const int node = tile * 32 + ln32;
    const float* __restrict__ xr = x + (long)node * 64;

    f32x16 cpa, cpb, cqa, cqb;
    #pragma unroll
    for (int r = 0; r < 16; ++r) {
        const int row = (r & 3) + 8 * (r >> 2) + 4 * hi;
        cpa[r] = b1[row]; cpb[r] = b1[32 + row];
        cqa[r] = 0.f;     cqb[r] = 0.f;
    }

    #pragma unroll
    for (int ks = 0; ks < 4; ++ks) {
        const int off = ks * 16 + hi * 8;
        float4 a = *reinterpret_cast<const float4*>(xr + off);
        float4 b = *reinterpret_cast<const float4*>(xr + off + 4);
        if (NORM) {
            const float4 s0 = *reinterpret_cast<const float4*>(scale + off);
            const float4 s1 = *reinterpret_cast<const float4*>(scale + off + 4);
            const float4 h0 = *reinterpret_cast<const float4*>(shift + off);
            const float4 h1 = *reinterpret_cast<const float4*>(shift + off + 4);
            a.x = fmaf(a.x, s0.x, h0.x); a.y = fmaf(a.y, s0.y, h0.y);
            a.z = fmaf(a.z, s0.z, h0.z); a.w = fmaf(a.w, s0.w, h0.w);
            b.x = fmaf(b.x, s1.x, h1.x); b.y = fmaf(b.y, s1.y, h1.y);
            b.z = fmaf(b.z, s1.z, h1.z); b.w = fmaf(b.w, s1.w, h1.w);
        }
        bf16x8 bfr;
        bfr[0] = (short)f2bf(a.x); bfr[1] = (short)f2bf(a.y);
        bfr[2] = (short)f2bf(a.z); bfr[3] = (short)f2bf(a.w);
        bfr[4] = (short)f2bf(b.x); bfr[5] = (short)f2bf(b.y);
        bfr[6] = (short)f2bf(b.z); bfr[7] = (short)f2bf(b.w);
        const bf16x8 ap0 = *reinterpret_cast<const bf16x8*>(&wlds[(0 * 4 + ks) * 512 + lane * 8]);
        const bf16x8 ap1 = *reinterpret_cast<const bf16x8*>(&wlds[(1 * 4 + ks) * 512 + lane * 8]);
        const bf16x8 aq0 = *reinterpret_cast<const bf16x8*>(&wlds[4096 + (0 * 4 + ks) * 512 + lane * 8]);
        const bf16x8 aq1 = *reinterpret_cast<const bf16x8*>(&wlds[4096 + (1 * 4 + ks) * 512 + lane * 8]);
        cpa = __builtin_amdgcn_mfma_f32_32x32x16_bf16(ap0, bfr, cpa, 0, 0, 0);
        cpb = __builtin_amdgcn_mfma_f32_32x32x16_bf16(ap1, bfr, cpb, 0, 0, 0);
        cqa = __builtin_amdgcn_mfma_f32_32x32x16_bf16(aq0, bfr, cqa, 0, 0, 0);
        cqb = __builtin_amdgcn_mfma_f32_32x32x16_bf16(aq1, bfr, cqb, 0, 0, 0);
    }

    unsigned short* Pr = P + (long)node * 64;
    unsigned short* Qr = Q + (long)node * 64;
    #pragma unroll
    for (int t = 0; t < 2; ++t) {
        const f32x16 cp = t ? cpb : cpa;
        const f32x16 cq = t ? cqb : cqa;
        #pragma unroll
        for (int g2 = 0; g2 < 4; ++g2) {
            uint2 up, uq;
            up.x = (unsigned)f2bf(cp[4 * g2 + 0]) | ((unsigned)f2bf(cp[4 * g2 + 1]) << 16);
            up.y = (unsigned)f2bf(cp[4 * g2 + 2]) | ((unsigned)f2bf(cp[4 * g2 + 3]) << 16);
            uq.x = (unsigned)f2bf(cq[4 * g2 + 0]) | ((unsigned)f2bf(cq[4 * g2 + 1]) << 16);
            uq.y = (unsigned)f2bf(cq[4 * g2 + 2]) | ((unsigned)f2bf(cq[4 * g2 + 3]) << 16);
            const int co = t * 32 + 8 * g2 + 4 * hi;
            *reinterpret_cast<uint2*>(Pr + co) = up;
            *reinterpret_cast<uint2*>(Qr + co) = uq;
        }
    }
}

// ---------------- EdgeConv layer-2: wave = 32 sorted edges ----------------
__global__ __launch_bounds__(256) void edgeconv_kernel(
    const unsigned short* __restrict__ P, const unsigned short* __restrict__ Q,
    const int2* __restrict__ sedge,
    const unsigned short* __restrict__ w2frag,
    const float* __restrict__ b2,
    float* __restrict__ out, int* __restrict__ recd, float* __restrict__ recv)
{
    __shared__ unsigned short wlds[4096];
    {
        const uint4* wsrc = reinterpret_cast<const uint4*>(w2frag);
        uint4* wdst = reinterpret_cast<uint4*>(wlds);
        #pragma unroll
        for (int i = 0; i < 2; ++i) wdst[threadIdx.x + i * 256] = wsrc[threadIdx.x + i * 256];
    }
    __syncthreads();

    const int wid  = threadIdx.x >> 6;
    const int lane = threadIdx.x & 63;
    const int hi   = lane >> 5;
    const int ln32 = lane & 31;
    const int tile = blockIdx.x * 4 + wid;
    if (tile >= NTILES) return;

    const int2 sd = sedge[tile * 32 + ln32];
    const int s = sd.x, d = sd.y;
    const unsigned short* __restrict__ Pr = P + (long)d * 64;
    const unsigned short* __restrict__ Qr = Q + (long)s * 64;

    f32x16 c2a, c2b;
    #pragma unroll
    for (int r = 0; r < 16; ++r) {
        const int row = (r & 3) + 8 * (r >> 2) + 4 * hi;
        c2a[r] = b2[row];
        c2b[r] = b2[32 + row];
    }

    #pragma unroll
    for (int ks = 0; ks < 4; ++ks) {
        const int co = ks * 16 + hi * 8;
        const uint4 pu = *reinterpret_cast<const uint4*>(Pr + co);
        const uint4 qu = *reinterpret_cast<const uint4*>(Qr + co);
        uint4 hr;
        hr.x = addrelu_pack(pu.x, qu.x);
        hr.y = addrelu_pack(pu.y, qu.y);
        hr.z = addrelu_pack(pu.z, qu.z);
        hr.w = addrelu_pack(pu.w, qu.w);
        const bf16x8 bfr = __builtin_bit_cast(bf16x8, hr);
        const bf16x8 a0 = *reinterpret_cast<const bf16x8*>(&wlds[(0 * 4 + ks) * 512 + lane * 8]);
        const bf16x8 a1 = *reinterpret_cast<const bf16x8*>(&wlds[(1 * 4 + ks) * 512 + lane * 8]);
        c2a = __builtin_amdgcn_mfma_f32_32x32x16_bf16(a0, bfr, c2a, 0, 0, 0);
        c2b = __builtin_amdgcn_mfma_f32_32x32x16_bf16(a1, bfr, c2b, 0, 0, 0);
    }

    #pragma unroll
    for (int r = 0; r < 16; ++r) {
        c2a[r] = fmaxf(c2a[r], 0.f);
        c2b[r] = fmaxf(c2b[r], 0.f);
    }

    // segmented max over edges within each 32-lane half (keys = d, sorted)
    #pragma unroll
    for (int st = 1; st < 32; st <<= 1) {
        const int dn = __shfl_down(d, st, 32);
        const bool take = (ln32 + st < 32) && (dn == d);
        #pragma unroll
        for (int r = 0; r < 16; ++r) {
            const float oa = __shfl_down(c2a[r], st, 32);
            const float ob = __shfl_down(c2b[r], st, 32);
            if (take) { c2a[r] = fmaxf(c2a[r], oa); c2b[r] = fmaxf(c2b[r], ob); }
        }
    }
    const int dprev = __shfl_up(d, 1, 32);
    const bool leader = (ln32 == 0) || (d != dprev);
    const unsigned lm = (unsigned)(__ballot(leader) & 0xffffffffull);
    const int L31 = 31 - __builtin_clz(lm);

    if (leader) {
        float4 va[4], vb[4];
        #pragma unroll
        for (int q = 0; q < 4; ++q) {
            va[q].x = c2a[4 * q]; va[q].y = c2a[4 * q + 1];
            va[q].z = c2a[4 * q + 2]; va[q].w = c2a[4 * q + 3];
            vb[q].x = c2b[4 * q]; vb[q].y = c2b[4 * q + 1];
            vb[q].z = c2b[4 * q + 2]; vb[q].w = c2b[4 * q + 3];
        }
        if (ln32 != 0 && ln32 != L31) {
            float* row = out + (long)d * 64;
            #pragma unroll
            for (int q = 0; q < 4; ++q) {
                *reinterpret_cast<float4*>(row + 8 * q + 4 * hi) = va[q];
                *reinterpret_cast<float4*>(row + 32 + 8 * q + 4 * hi) = vb[q];
            }
        }
        if (ln32 == 0) {
            float* row = recv + (long)(tile * 2) * 64;
            #pragma unroll
            for (int q = 0; q < 4; ++q) {
                *reinterpret_cast<float4*>(row + 8 * q + 4 * hi) = va[q];
                *reinterpret_cast<float4*>(row + 32 + 8 * q + 4 * hi) = vb[q];
            }
            if (hi == 0) recd[tile * 2] = d;
        }
        if (ln32 == L31) {
            float* row = recv + (long)(tile * 2 + 1) * 64;
            #pragma unroll
            for (int q = 0; q < 4; ++q) {
                *reinterpret_cast<float4*>(row + 8 * q + 4 * hi) = va[q];
                *reinterpret_cast<float4*>(row + 32 + 8 * q + 4 * hi) = vb[q];
            }
            if (hi == 0) recd[tile * 2 + 1] = d;
        }
    }
}

// ---------------- fixup: combine boundary records (runs of equal dst) ----------------
__global__ __launch_bounds__(256) void fixup_kernel(
    const int* __restrict__ recd, const float* __restrict__ recv,
    float* __restrict__ out)
{
    const int wid = threadIdx.x >> 6, lane = threadIdx.x & 63;
    const int r = blockIdx.x * 4 + wid;
    if (r >= NREC) return;
    const int d = recd[r];
    int lo = r, hi = r;
    while (lo > 0 && recd[lo - 1] == d) --lo;
    while (hi + 1 < NREC && recd[hi + 1] == d) ++hi;
    float m = 0.f;
    for (int rr = lo; rr <= hi; ++rr) m = fmaxf(m, recv[(long)rr * 64 + lane]);
    out[(long)d * 64 + lane] = m;
}

// ---------------- BN stats: deterministic two-stage ----------------
__global__ __launch_bounds__(256) void stats_kernel(
    const float* __restrict__ h, float* __restrict__ partial)
{
    __shared__ float red[2][256];
    const int tid = threadIdx.x;
    const int c = tid & 63, r = tid >> 6;
    float s = 0.f, ss = 0.f;
    for (int v = blockIdx.x * 4 + r; v < NN; v += 256 * 4) {
        const float val = h[(long)v * 64 + c];
        s += val; ss += val * val;
    }
    red[0][tid] = s; red[1][tid] = ss;
    __syncthreads();
    if (r == 0) {
        float S = 0.f, SS = 0.f;
        #pragma unroll
        for (int q = 0; q < 4; ++q) { S += red[0][c + q * 64]; SS += red[1][c + q * 64]; }
        partial[blockIdx.x * 128 + c] = S;
        partial[blockIdx.x * 128 + 64 + c] = SS;
    }
}

__global__ void bn_finalize_kernel(
    const float* __restrict__ partial,
    const float* __restrict__ g, const float* __restrict__ b,
    float* __restrict__ scale, float* __restrict__ shift)
{
    const int c = threadIdx.x;
    float S = 0.f, SS = 0.f;
    for (int bb = 0; bb < 256; ++bb) {
        S += partial[bb * 128 + c];
        SS += partial[bb * 128 + 64 + c];
    }
    const float invN = 1.0f / (float)NN;
    const float mu = S * invN;
    const float var = SS * invN - mu * mu;
    const float sc = g[c] * rsqrtf(var + BN_EPS);
    scale[c] = sc;
    shift[c] = b[c] - mu * sc;
}

// ---------------- node pass: BN2 normalize in place + segmented pooling ----------------
constexpr int NPB = 512;
__global__ __launch_bounds__(256) void nodepass_kernel(
    float* __restrict__ xn, const int* __restrict__ batch,
    const float* __restrict__ scale, const float* __restrict__ shift,
    float* __restrict__ poolsum, unsigned* __restrict__ poolmax, int* __restrict__ counts)
{
    const int base = blockIdx.x * NPB;
    const int r = threadIdx.x >> 6, c = threadIdx.x & 63;
    int curg = -1; float rs = 0.f, rm = -INFINITY; int rc = 0;
    const int vend = (base + NPB < NN) ? base + NPB : NN;
    for (int v = base + r; v < vend; v += 4) {
        const long idx = (long)v * 64 + c;
        const float val = fmaf(xn[idx], scale[c], shift[c]);
        xn[idx] = val;
        const int g = batch[v];
        if (g != curg) {
            if (curg >= 0) {
                atomicAdd(poolsum + curg * 64 + c, rs);
                atomicMax(poolmax + curg * 64 + c, fenc(rm));
                if (c == 0) atomicAdd(counts + curg, rc);
            }
            curg = g; rs = 0.f; rm = -INFINITY; rc = 0;
        }
        rs += val; rm = fmaxf(rm, val); ++rc;
    }
    if (curg >= 0) {
        atomicAdd(poolsum + curg * 64 + c, rs);
        atomicMax(poolmax + curg * 64 + c, fenc(rm));
        if (c == 0) atomicAdd(counts + curg, rc);
    }
}

// ---------------- final: x_graph + projector MLP + BN + out ----------------
__global__ __launch_bounds__(512) void final_kernel(
    const float* __restrict__ poolsum, const unsigned* __restrict__ poolmax,
    const int* __restrict__ counts,
    const float* __restrict__ p_w1, const float* __restrict__ p_b1,
    const float* __restrict__ p_bng, const float* __restrict__ p_bnb,
    const float* __restrict__ p_w2, const float* __restrict__ p_b2,
    float* __restrict__ out)
{
    __shared__ float xg[64][128];
    __shared__ float znl[64 * 129];
    __shared__ float red[2][512];
    __shared__ float scsh[2][128];
    const int tid = threadIdx.x;

    #pragma unroll
    for (int i = 0; i < 16; ++i) {
        const int e2 = tid + i * 512;
        const int g = e2 >> 7, col = e2 & 127;
        float val;
        if (col < 64) {
            const float cnt = fmaxf((float)counts[g], 1.f);
            val = poolsum[g * 64 + col] / cnt;
        } else {
            const unsigned u = poolmax[g * 64 + col - 64];
            val = (u == 0u) ? 0.f : fdec(u);
        }
        xg[g][col] = val;
        out[OUT_XG + e2] = val;
    }
    __syncthreads();

    const int gg = tid >> 7, t = tid & 127;
    float z[16];
    #pragma unroll
    for (int gi = 0; gi < 16; ++gi) z[gi] = p_b1[t];
    for (int j = 0; j < 128; ++j) {
        const float wv = p_w1[j * 128 + t];
        #pragma unroll
        for (int gi = 0; gi < 16; ++gi) z[gi] = fmaf(xg[gg * 16 + gi][j], wv, z[gi]);
    }

    float s = 0.f, ss = 0.f;
    #pragma unroll
    for (int gi = 0; gi < 16; ++gi) { s += z[gi]; ss += z[gi] * z[gi]; }
    red[0][tid] = s; red[1][tid] = ss;
    __syncthreads();
    if (gg == 0) {
        float S = 0.f, SS = 0.f;
        #pragma unroll
        for (int q = 0; q < 4; ++q) { S += red[0][t + q * 128]; SS += red[1][t + q * 128]; }
        const float mu = S / 64.f;
        const float var = SS / 64.f - mu * mu;
        const float sc = p_bng[t] * rsqrtf(var + BN_EPS);
        scsh[0][t] = sc;
        scsh[1][t] = p_bnb[t] - mu * sc;
    }
    __syncthreads();
    const float sc = scsh[0][t], sh = scsh[1][t];
    #pragma unroll
    for (int gi = 0; gi < 16; ++gi) {
        const float zn = fmaxf(fmaf(z[gi], sc, sh), 0.f);
        znl[(gg * 16 + gi) * 129 + t] = zn;
    }
    __syncthreads();

    float zp[16];
    #pragma unroll
    for (int gi = 0; gi < 16; ++gi) zp[gi] = p_b2[t];
    for (int c = 0; c < 128; ++c) {
        const float wv = p_w2[c * 128 + t];
        #pragma unroll
        for (int gi = 0; gi < 16; ++gi) zp[gi] = fmaf(znl[(gg * 16 + gi) * 129 + c], wv, zp[gi]);
    }
    #pragma unroll
    for (int gi = 0; gi < 16; ++gi) out[(gg * 16 + gi) * 128 + t] = zp[gi];
}

// ---------------- launch ----------------
extern "C" void kernel_launch(void* const* d_in, const int* in_sizes, int n_in,
                              void* d_out, int out_size, void* d_ws, size_t ws_size,
                              hipStream_t stream)
{
    const float* x     = (const float*)d_in[0];
    const int*   eidx  = (const int*)d_in[1];
    const int*   batch = (const int*)d_in[2];
    const float* c1w1  = (const float*)d_in[3];
    const float* c1b1  = (const float*)d_in[4];
    const float* c1w2  = (const float*)d_in[5];
    const float* c1b2  = (const float*)d_in[6];
    const float* bn1g  = (const float*)d_in[7];
    const float* bn1b  = (const float*)d_in[8];
    const float* c2w1  = (const float*)d_in[9];
    const float* c2b1  = (const float*)d_in[10];
    const float* c2w2  = (const float*)d_in[11];
    const float* c2b2  = (const float*)d_in[12];
    const float* bn2g  = (const float*)d_in[13];
    const float* bn2b  = (const float*)d_in[14];
    const float* pw1   = (const float*)d_in[15];
    const float* pb1   = (const float*)d_in[16];
    const float* pbng  = (const float*)d_in[17];
    const float* pbnb  = (const float*)d_in[18];
    const float* pw2   = (const float*)d_in[19];
    const float* pb2   = (const float*)d_in[20];

    const int* src = eidx;
    const int* dst = eidx + NE;

    float* ws  = (float*)d_ws;
    float* o   = (float*)d_out;
    float* h1  = ws + H1_OFF;
    float* xnode = o + OUT_XNODE;
    int* tab   = (int*)(ws + TAB_OFF);
    int2* ebin  = (int2*)(ws + H1_OFF);     // staging, lives before h1 is zeroed
    int2* sedge = (int2*)(ws + SEDG_OFF);
    unsigned short* wf1 = (unsigned short*)(ws + WF1_OFF);
    unsigned short* wf2 = (unsigned short*)(ws + WF2_OFF);
    int* recd  = (int*)(ws + RECD_OFF);
    float* recv = ws + RECV_OFF;
    unsigned short* Pb = (unsigned short*)(ws + P_OFF);
    unsigned short* Qb = (unsigned short*)(ws + Q_OFF);

    // weight prep (both convs)
    prep_weights<<<48, 256, 0, stream>>>(c1w1, c1w2, wf1);
    prep_weights<<<48, 256, 0, stream>>>(c2w1, c2w2, wf2);

    // two-level binned counting sort by dst -> sedge
    bin_hist_kernel<<<BINB, 256, 0, stream>>>(dst, tab);
    scan_tab_kernel<<<1, 1024, 0, stream>>>(tab);
    bin_scatter_kernel<<<BINB, 256, 0, stream>>>(src, dst, tab, ebin);
    bucket_sort_kernel<<<NBUK, 256, 0, stream>>>(ebin, tab, sedge);

    // zero accumulators (h1 AFTER sort: ebin staged in its region)
    hipMemsetAsync(h1, 0, (size_t)NN * 64 * 4, stream);
    hipMemsetAsync(xnode, 0, (size_t)NN * 64 * 4, stream);
    hipMemsetAsync(ws + PSUM_OFF, 0, (4096 + 4096 + 64) * 4, stream);

    const int ngGrid   = (NNTILES + 3) / 4;
    const int convGrid = (NTILES + 3) / 4;
    const int fixGrid  = (NREC + 3) / 4;

    // conv1: node GEMM (P,Q) then edge pass -> h1
    nodegemm_kernel<false><<<ngGrid, 256, 0, stream>>>(
        x, wf1, c1b1, nullptr, nullptr, Pb, Qb);
    edgeconv_kernel<<<convGrid, 256, 0, stream>>>(
        Pb, Qb, sedge, wf1 + 8192, c1b2, h1, recd, recv);
    fixup_kernel<<<fixGrid, 256, 0, stream>>>(recd, recv, h1);
    // BN1 stats
    stats_kernel<<<256, 256, 0, stream>>>(h1, ws + PART_OFF);
    bn_finalize_kernel<<<1, 64, 0, stream>>>(ws + PART_OFF, bn1g, bn1b,
                                             ws + SC1_OFF, ws + SH1_OFF);
    // conv2: node GEMM on normalized h1, then edge pass -> xnode
    nodegemm_kernel<true><<<ngGrid, 256, 0, stream>>>(
        h1, wf2, c2b1, ws + SC1_OFF, ws + SH1_OFF, Pb, Qb);
    edgeconv_kernel<<<convGrid, 256, 0, stream>>>(
        Pb, Qb, sedge, wf2 + 8192, c2b2, xnode, recd, recv);
    fixup_kernel<<<fixGrid, 256, 0, stream>>>(recd, recv, xnode);
    // BN2 stats
    stats_kernel<<<256, 256, 0, stream>>>(xnode, ws + PART_OFF);
    bn_finalize_kernel<<<1, 64, 0, stream>>>(ws + PART_OFF, bn2g, bn2b,
                                             ws + SC2_OFF, ws + SH2_OFF);
    // normalize x_node + pooling
    nodepass_kernel<<<(NN + NPB - 1) / NPB, 256, 0, stream>>>(
        xnode, batch, ws + SC2_OFF, ws + SH2_OFF,
        ws + PSUM_OFF, (unsigned*)(ws + PMAX_OFF), (int*)(ws + CNT_OFF));
    // x_graph + projector
    final_kernel<<<1, 512, 0, stream>>>(
        ws + PSUM_OFF, (unsigned*)(ws + PMAX_OFF), (int*)(ws + CNT_OFF),
        pw1, pb1, pbng, pbnb, pw2, pb2, o);
}

// Round 7
// 420.866 us; speedup vs baseline: 14.6609x; 1.0446x over previous
//
#include <hip/hip_runtime.h>
#include <hip/hip_fp16.h>

// ---------------- problem constants ----------------
constexpr int NN = 100000;   // nodes
constexpr int NE = 1000000;  // edges
constexpr int NG = 64;       // graphs
constexpr float BN_EPS = 1e-5f;
constexpr int NTILES = NE / 32;      // 31250 wave-tiles of 32 edges
constexpr int NNTILES = NN / 32;     // 3125 node tiles
constexpr int NREC = NTILES * 2;     // 62500 boundary records

// two-level binned counting sort
constexpr int NBUK = 98;             // buckets of 1024 nodes (dst >> 10)
constexpr int BINB = 256;            // binning blocks
constexpr int BCHUNK = (NE + BINB - 1) / BINB;  // 3907 edges per block
constexpr int TABN = NBUK * BINB;    // 25088 scan-table entries

// ws layout (in floats)
constexpr long H1_OFF   = 0;                       // [NN*64] conv1 out; first 2M = ebin staging
constexpr long PART_OFF = 6400000;                 // [256*128] BN stat partials
constexpr long SC1_OFF  = PART_OFF + 32768;        // [64]
constexpr long SH1_OFF  = SC1_OFF + 64;
constexpr long SC2_OFF  = SH1_OFF + 64;
constexpr long SH2_OFF  = SC2_OFF + 64;
constexpr long PSUM_OFF = SH2_OFF + 64;            // [64*64]
constexpr long PMAX_OFF = PSUM_OFF + 4096;         // [64*64]
constexpr long CNT_OFF  = PMAX_OFF + 4096;         // [64]
constexpr long TAB_OFF  = CNT_OFF + 64;            // [25088] bin scan table (int)
constexpr long SEDG_OFF = TAB_OFF + 100000;        // [NE int2] sorted (src,dst) = 2M floats
constexpr long WF1_OFF  = SEDG_OFF + 2000000;      // 12288 u16 = 6144 float slots
constexpr long WF2_OFF  = WF1_OFF + 6144;          // 12288 u16
constexpr long RECD_OFF = WF2_OFF + 6144;          // [62500] record dst (int), pad->62528
constexpr long RECV_OFF = RECD_OFF + 62528;        // [62500*64] record values
constexpr long P_OFF    = RECV_OFF + 4000000;      // [NN*64 f16] = 3.2M floats
constexpr long Q_OFF    = P_OFF + 3200000;         // [NN*64 f16]

// d_out layout (floats): z_proj [64*128] | x_node [NN*64] | x_graph [64*128]
constexpr long OUT_XNODE = 8192;
constexpr long OUT_XG    = 8192 + 6400000L;

using f16x2 = __attribute__((ext_vector_type(2))) _Float16;
using f16x8 = __attribute__((ext_vector_type(8))) _Float16;
using f32x16 = __attribute__((ext_vector_type(16))) float;

__device__ __forceinline__ unsigned short f2h(float f) {
    return __builtin_bit_cast(unsigned short, (_Float16)f);
}
// pack two f32 -> dword of two f16 (round-toward-zero, single instr)
__device__ __forceinline__ unsigned pkrtz(float a, float b) {
    return __builtin_bit_cast(unsigned, __builtin_amdgcn_cvt_pkrtz(a, b));
}
__device__ __forceinline__ unsigned pk_add_f16(unsigned a, unsigned b) {
    unsigned d;
    asm("v_pk_add_f16 %0, %1, %2" : "=v"(d) : "v"(a), "v"(b));
    return d;
}
__device__ __forceinline__ unsigned pk_max_f16(unsigned a, unsigned b) {
    unsigned d;
    asm("v_pk_max_f16 %0, %1, %2" : "=v"(d) : "v"(a), "v"(b));
    return d;
}
__device__ __forceinline__ float h2f_lo(unsigned u) {
    return (float)__builtin_bit_cast(_Float16, (unsigned short)(u & 0xffffu));
}
__device__ __forceinline__ float h2f_hi(unsigned u) {
    return (float)__builtin_bit_cast(_Float16, (unsigned short)(u >> 16));
}
__device__ __forceinline__ unsigned fenc(float f) {
    unsigned u = __float_as_uint(f);
    return (u & 0x80000000u) ? ~u : (u | 0x80000000u);
}
__device__ __forceinline__ float fdec(unsigned u) {
    return (u & 0x80000000u) ? __uint_as_float(u & 0x7fffffffu) : __uint_as_float(~u);
}

// ---------------- two-level binned counting sort ----------------
__global__ __launch_bounds__(256) void bin_hist_kernel(
    const int* __restrict__ dst, int* __restrict__ tab)
{
    __shared__ int cnt[NBUK];
    const int t = threadIdx.x, b = blockIdx.x;
    if (t < NBUK) cnt[t] = 0;
    __syncthreads();
    const int lo = b * BCHUNK;
    const int hi = (lo + BCHUNK < NE) ? lo + BCHUNK : NE;
    for (int e = lo + t; e < hi; e += 256) atomicAdd(&cnt[dst[e] >> 10], 1);
    __syncthreads();
    if (t < NBUK) tab[t * BINB + b] = cnt[t];
}

__global__ __launch_bounds__(1024) void scan_tab_kernel(int* __restrict__ tab)
{
    __shared__ int part[1024];
    const int t = threadIdx.x;
    constexpr int VPT = 25;  // 1024*25 >= TABN
    int vals[VPT];
    const int base = t * VPT;
    int s = 0;
    #pragma unroll
    for (int i = 0; i < VPT; ++i) {
        const int idx = base + i;
        const int v = (idx < TABN) ? tab[idx] : 0;
        vals[i] = v; s += v;
    }
    part[t] = s;
    __syncthreads();
    for (int off = 1; off < 1024; off <<= 1) {
        const int u = (t >= off) ? part[t - off] : 0;
        __syncthreads();
        part[t] += u;
        __syncthreads();
    }
    int run = (t == 0) ? 0 : part[t - 1];
    #pragma unroll
    for (int i = 0; i < VPT; ++i) {
        const int idx = base + i;
        if (idx < TABN) { const int v = vals[i]; tab[idx] = run; run += v; }
    }
}

__global__ __launch_bounds__(256) void bin_scatter_kernel(
    const int* __restrict__ src, const int* __restrict__ dst,
    const int* __restrict__ tab, int2* __restrict__ ebin)
{
    __shared__ int basec[NBUK];
    __shared__ int cur[NBUK];
    const int t = threadIdx.x, b = blockIdx.x;
    if (t < NBUK) { basec[t] = tab[t * BINB + b]; cur[t] = 0; }
    __syncthreads();
    const int lo = b * BCHUNK;
    const int hi = (lo + BCHUNK < NE) ? lo + BCHUNK : NE;
    for (int e = lo + t; e < hi; e += 256) {
        const int d = dst[e];
        const int k = d >> 10;
        const int pos = basec[k] + atomicAdd(&cur[k], 1);
        ebin[pos] = make_int2(src[e], d);
    }
}

__global__ __launch_bounds__(256) void bucket_sort_kernel(
    const int2* __restrict__ ebin, const int* __restrict__ tab,
    int2* __restrict__ sedge)
{
    __shared__ int hist[1024];
    __shared__ int part[256];
    const int t = threadIdx.x, k = blockIdx.x;
    const int start = tab[k * BINB];
    const int end = (k == NBUK - 1) ? NE : tab[(k + 1) * BINB];
    #pragma unroll
    for (int i = 0; i < 4; ++i) hist[t * 4 + i] = 0;
    __syncthreads();
    for (int e = start + t; e < end; e += 256) atomicAdd(&hist[ebin[e].y & 1023], 1);
    __syncthreads();
    const int v0 = hist[t*4], v1 = hist[t*4+1], v2 = hist[t*4+2], v3 = hist[t*4+3];
    part[t] = v0 + v1 + v2 + v3;
    __syncthreads();
    for (int off = 1; off < 256; off <<= 1) {
        const int u = (t >= off) ? part[t - off] : 0;
        __syncthreads();
        part[t] += u;
        __syncthreads();
    }
    int run = (t == 0) ? 0 : part[t - 1];
    hist[t*4]   = run;
    hist[t*4+1] = run + v0;
    hist[t*4+2] = run + v0 + v1;
    hist[t*4+3] = run + v0 + v1 + v2;
    __syncthreads();
    for (int e = start + t; e < end; e += 256) {
        const int2 v = ebin[e];
        const int pos = start + atomicAdd(&hist[v.y & 1023], 1);
        sedge[pos] = v;
    }
}

// ---------------- weight prep: fragment-ordered f16 ----------------
// sec 0: Wp = W1a - W1b (8 frags), sec 1: Wq = W1b (8), sec 2: W2 (8)
__global__ __launch_bounds__(256) void prep_weights(
    const float* __restrict__ w1, const float* __restrict__ w2,
    unsigned short* __restrict__ wf)
{
    const int idx = blockIdx.x * 256 + threadIdx.x;
    if (idx >= 12288) return;
    const int sec = idx >> 12;
    const int j = idx & 4095;
    const int f = j >> 9, rem = j & 511, ln = rem >> 3, i = rem & 7;
    const int t = f >> 2, ks = f & 3;
    const int k = ks * 16 + (ln >> 5) * 8 + i, c = t * 32 + (ln & 31);
    float v;
    if (sec == 0)      v = w1[k * 64 + c] - w1[(64 + k) * 64 + c];
    else if (sec == 1) v = w1[(64 + k) * 64 + c];
    else               v = w2[k * 64 + c];
    wf[idx] = f2h(v);
}

// ---------------- node GEMM: P = (W1a-W1b)x + b1, Q = W1b x  (f16 out) -------------
template<bool NORM>
__global__ __launch_bounds__(256) void nodegemm_kernel(
    const float* __restrict__ x,
    const unsigned short* __restrict__ wfrag,
    const float* __restrict__ b1,
    const float* __restrict__ scale, const float* __restrict__ shift,
    unsigned short* __restrict__ P, unsigned short* __restrict__ Q)
{
    __shared__ unsigned short wlds[8192];
    {
        const uint4* wsrc = reinterpret_cast<const uint4*>(wfrag);
        uint4* wdst = reinterpret_cast<uint4*>(wlds);
        #pragma unroll
        for (int i = 0; i < 4; ++i) wdst[threadIdx.x + i * 256] = wsrc[threadIdx.x + i * 256];
    }
    __syncthreads();

    const int wid = threadIdx.x >> 6, lane = threadIdx.x & 63;
    const int hi = lane >> 5, ln32 = lane & 31;
    const int tile = blockIdx.x * 4 + wid;
    if (tile >= NNTILES) return;
    const int node = tile * 32 + ln32;
    const float* __restrict__ xr = x + (long)node * 64;

    f32x16 cpa, cpb, cqa, cqb;
    #pragma unroll
    for (int r = 0; r < 16; ++r) {
        const int row = (r & 3) + 8 * (r >> 2) + 4 * hi;
        cpa[r] = b1[row]; cpb[r] = b1[32 + row];
        cqa[r] = 0.f;     cqb[r] = 0.f;
    }

    #pragma unroll
    for (int ks = 0; ks < 4; ++ks) {
        const int off = ks * 16 + hi * 8;
        float4 a = *reinterpret_cast<const float4*>(xr + off);
        float4 b = *reinterpret_cast<const float4*>(xr + off + 4);
        if (NORM) {
            const float4 s0 = *reinterpret_cast<const float4*>(scale + off);
            const float4 s1 = *reinterpret_cast<const float4*>(scale + off + 4);
            const float4 h0 = *reinterpret_cast<const float4*>(shift + off);
            const float4 h1 = *reinterpret_cast<const float4*>(shift + off + 4);
            a.x = fmaf(a.x, s0.x, h0.x); a.y = fmaf(a.y, s0.y, h0.y);
            a.z = fmaf(a.z, s0.z, h0.z); a.w = fmaf(a.w, s0.w, h0.w);
            b.x = fmaf(b.x, s1.x, h1.x); b.y = fmaf(b.y, s1.y, h1.y);
            b.z = fmaf(b.z, s1.z, h1.z); b.w = fmaf(b.w, s1.w, h1.w);
        }
        uint4 uu;
        uu.x = pkrtz(a.x, a.y); uu.y = pkrtz(a.z, a.w);
        uu.z = pkrtz(b.x, b.y); uu.w = pkrtz(b.z, b.w);
        const f16x8 bfr = __builtin_bit_cast(f16x8, uu);
        const f16x8 ap0 = *reinterpret_cast<const f16x8*>(&wlds[(0 * 4 + ks) * 512 + lane * 8]);
        const f16x8 ap1 = *reinterpret_cast<const f16x8*>(&wlds[(1 * 4 + ks) * 512 + lane * 8]);
        const f16x8 aq0 = *reinterpret_cast<const f16x8*>(&wlds[4096 + (0 * 4 + ks) * 512 + lane * 8]);
        const f16x8 aq1 = *reinterpret_cast<const f16x8*>(&wlds[4096 + (1 * 4 + ks) * 512 + lane * 8]);
        cpa = __builtin_amdgcn_mfma_f32_32x32x16_f16(ap0, bfr, cpa, 0, 0, 0);
        cpb = __builtin_amdgcn_mfma_f32_32x32x16_f16(ap1, bfr, cpb, 0, 0, 0);
        cqa = __builtin_amdgcn_mfma_f32_32x32x16_f16(aq0, bfr, cqa, 0, 0, 0);
        cqb = __builtin_amdgcn_mfma_f32_32x32x16_f16(aq1, bfr, cqb, 0, 0, 0);
    }

    unsigned short* Pr = P + (long)node * 64;
    unsigned short* Qr = Q + (long)node * 64;
    #pragma unroll
    for (int t = 0; t < 2; ++t) {
        const f32x16 cp = t ? cpb : cpa;
        const f32x16 cq = t ? cqb : cqa;
        #pragma unroll
        for (int g2 = 0; g2 < 4; ++g2) {
            uint2 up, uq;
            up.x = pkrtz(cp[4 * g2 + 0], cp[4 * g2 + 1]);
            up.y = pkrtz(cp[4 * g2 + 2], cp[4 * g2 + 3]);
            uq.x = pkrtz(cq[4 * g2 + 0], cq[4 * g2 + 1]);
            uq.y = pkrtz(cq[4 * g2 + 2], cq[4 * g2 + 3]);
            const int co = t * 32 + 8 * g2 + 4 * hi;
            *reinterpret_cast<uint2*>(Pr + co) = up;
            *reinterpret_cast<uint2*>(Qr + co) = uq;
        }
    }
}

// ---------------- EdgeConv layer-2: wave = 32 sorted edges ----------------
__global__ __launch_bounds__(256) void edgeconv_kernel(
    const unsigned short* __restrict__ P, const unsigned short* __restrict__ Q,
    const int2* __restrict__ sedge,
    const unsigned short* __restrict__ w2frag,
    const float* __restrict__ b2,
    float* __restrict__ out, int* __restrict__ recd, float* __restrict__ recv)
{
    __shared__ unsigned short wlds[4096];
    {
        const uint4* wsrc = reinterpret_cast<const uint4*>(w2frag);
        uint4* wdst = reinterpret_cast<uint4*>(wlds);
        #pragma unroll
        for (int i = 0; i < 2; ++i) wdst[threadIdx.x + i * 256] = wsrc[threadIdx.x + i * 256];
    }
    __syncthreads();

    const int wid  = threadIdx.x >> 6;
    const int lane = threadIdx.x & 63;
    const int hi   = lane >> 5;
    const int ln32 = lane & 31;
    const int tile = blockIdx.x * 4 + wid;
    if (tile >= NTILES) return;

    const int2 sd = sedge[tile * 32 + ln32];
    const int s = sd.x, d = sd.y;
    const unsigned short* __restrict__ Pr = P + (long)d * 64;
    const unsigned short* __restrict__ Qr = Q + (long)s * 64;

    f32x16 c2a, c2b;
    #pragma unroll
    for (int r = 0; r < 16; ++r) {
        const int row = (r & 3) + 8 * (r >> 2) + 4 * hi;
        c2a[r] = b2[row];
        c2b[r] = b2[32 + row];
    }

    #pragma unroll
    for (int ks = 0; ks < 4; ++ks) {
        const int co = ks * 16 + hi * 8;
        const uint4 pu = *reinterpret_cast<const uint4*>(Pr + co);
        const uint4 qu = *reinterpret_cast<const uint4*>(Qr + co);
        uint4 hh;   // relu(P+Q) in packed f16: 2 VALU per dword
        hh.x = pk_max_f16(pk_add_f16(pu.x, qu.x), 0u);
        hh.y = pk_max_f16(pk_add_f16(pu.y, qu.y), 0u);
        hh.z = pk_max_f16(pk_add_f16(pu.z, qu.z), 0u);
        hh.w = pk_max_f16(pk_add_f16(pu.w, qu.w), 0u);
        const f16x8 bfr = __builtin_bit_cast(f16x8, hh);
        const f16x8 a0 = *reinterpret_cast<const f16x8*>(&wlds[(0 * 4 + ks) * 512 + lane * 8]);
        const f16x8 a1 = *reinterpret_cast<const f16x8*>(&wlds[(1 * 4 + ks) * 512 + lane * 8]);
        c2a = __builtin_amdgcn_mfma_f32_32x32x16_f16(a0, bfr, c2a, 0, 0, 0);
        c2b = __builtin_amdgcn_mfma_f32_32x32x16_f16(a1, bfr, c2b, 0, 0, 0);
    }

    // relu + pack to 16 f16-pair dwords (max commutes with monotone f16 rounding)
    unsigned pkc[16];
    #pragma unroll
    for (int q = 0; q < 8; ++q) {
        pkc[q]     = pk_max_f16(pkrtz(c2a[2 * q], c2a[2 * q + 1]), 0u);
        pkc[8 + q] = pk_max_f16(pkrtz(c2b[2 * q], c2b[2 * q + 1]), 0u);
    }

    // segmented max over edges within each 32-lane half (keys = d, sorted), packed f16
    #pragma unroll
    for (int st = 1; st < 32; st <<= 1) {
        const int dn = __shfl_down(d, st, 32);
        const bool take = (ln32 + st < 32) && (dn == d);
        #pragma unroll
        for (int i = 0; i < 16; ++i) {
            const unsigned o = __shfl_down(pkc[i], st, 32);
            const unsigned m = pk_max_f16(pkc[i], o);
            pkc[i] = take ? m : pkc[i];
        }
    }
    const int dprev = __shfl_up(d, 1, 32);
    const bool leader = (ln32 == 0) || (d != dprev);
    const unsigned lm = (unsigned)(__ballot(leader) & 0xffffffffull);
    const int L31 = 31 - __builtin_clz(lm);

    if (leader) {
        float4 va[4], vb[4];
        #pragma unroll
        for (int q = 0; q < 4; ++q) {
            va[q].x = h2f_lo(pkc[2 * q]);     va[q].y = h2f_hi(pkc[2 * q]);
            va[q].z = h2f_lo(pkc[2 * q + 1]); va[q].w = h2f_hi(pkc[2 * q + 1]);
            vb[q].x = h2f_lo(pkc[8 + 2 * q]);     vb[q].y = h2f_hi(pkc[8 + 2 * q]);
            vb[q].z = h2f_lo(pkc[8 + 2 * q + 1]); vb[q].w = h2f_hi(pkc[8 + 2 * q + 1]);
        }
        if (ln32 != 0 && ln32 != L31) {
            float* row = out + (long)d * 64;
            #pragma unroll
            for (int q = 0; q < 4; ++q) {
                *reinterpret_cast<float4*>(row + 8 * q + 4 * hi) = va[q];
                *reinterpret_cast<float4*>(row + 32 + 8 * q + 4 * hi) = vb[q];
            }
        }
        if (ln32 == 0) {
            float* row = recv + (long)(tile * 2) * 64;
            #pragma unroll
            for (int q = 0; q < 4; ++q) {
                *reinterpret_cast<float4*>(row + 8 * q + 4 * hi) = va[q];
                *reinterpret_cast<float4*>(row + 32 + 8 * q + 4 * hi) = vb[q];
            }
            if (hi == 0) recd[tile * 2] = d;
        }
        if (ln32 == L31) {
            float* row = recv + (long)(tile * 2 + 1) * 64;
            #pragma unroll
            for (int q = 0; q < 4; ++q) {
                *reinterpret_cast<float4*>(row + 8 * q + 4 * hi) = va[q];
                *reinterpret_cast<float4*>(row + 32 + 8 * q + 4 * hi) = vb[q];
            }
            if (hi == 0) recd[tile * 2 + 1] = d;
        }
    }
}

// ---------------- fixup: combine boundary records (runs of equal dst) ----------------
__global__ __launch_bounds__(256) void fixup_kernel(
    const int* __restrict__ recd, const float* __restrict__ recv,
    float* __restrict__ out)
{
    const int wid = threadIdx.x >> 6, lane = threadIdx.x & 63;
    const int r = blockIdx.x * 4 + wid;
    if (r >= NREC) return;
    const int d = recd[r];
    int lo = r, hi = r;
    while (lo > 0 && recd[lo - 1] == d) --lo;
    while (hi + 1 < NREC && recd[hi + 1] == d) ++hi;
    float m = 0.f;
    for (int rr = lo; rr <= hi; ++rr) m = fmaxf(m, recv[(long)rr * 64 + lane]);
    out[(long)d * 64 + lane] = m;
}

// ---------------- BN stats: deterministic two-stage ----------------
__global__ __launch_bounds__(256) void stats_kernel(
    const float* __restrict__ h, float* __restrict__ partial)
{
    __shared__ float red[2][256];
    const int tid = threadIdx.x;
    const int c = tid & 63, r = tid >> 6;
    float s = 0.f, ss = 0.f;
    for (int v = blockIdx.x * 4 + r; v < NN; v += 256 * 4) {
        const float val = h[(long)v * 64 + c];
        s += val; ss += val * val;
    }
    red[0][tid] = s; red[1][tid] = ss;
    __syncthreads();
    if (r == 0) {
        float S = 0.f, SS = 0.f;
        #pragma unroll
        for (int q = 0; q < 4; ++q) { S += red[0][c + q * 64]; SS += red[1][c + q * 64]; }
        partial[blockIdx.x * 128 + c] = S;
        partial[blockIdx.x * 128 + 64 + c] = SS;
    }
}

__global__ __launch_bounds__(256) void bn_finalize_kernel(
    const float* __restrict__ partial,
    const float* __restrict__ g, const float* __restrict__ b,
    float* __restrict__ scale, float* __restrict__ shift)
{
    __shared__ float red[2][256];
    const int tid = threadIdx.x;
    const int c = tid & 63, q = tid >> 6;   // 4 threads per channel
    float S = 0.f, SS = 0.f;
    for (int bb = q * 64; bb < q * 64 + 64; ++bb) {
        S += partial[bb * 128 + c];
        SS += partial[bb * 128 + 64 + c];
    }
    red[0][tid] = S; red[1][tid] = SS;
    __syncthreads();
    if (q == 0) {
        #pragma unroll
        for (int p = 1; p < 4; ++p) { S += red[0][c + p * 64]; SS += red[1][c + p * 64]; }
        const float invN = 1.0f / (float)NN;
        const float mu = S * invN;
        const float var = SS * invN - mu * mu;
        const float sc = g[c] * rsqrtf(var + BN_EPS);
        scale[c] = sc;
        shift[c] = b[c] - mu * sc;
    }
}

// ---------------- node pass: BN2 normalize in place + segmented pooling ----------------
constexpr int NPB = 512;
__global__ __launch_bounds__(256) void nodepass_kernel(
    float* __restrict__ xn, const int* __restrict__ batch,
    const float* __restrict__ scale, const float* __restrict__ shift,
    float* __restrict__ poolsum, unsigned* __restrict__ poolmax, int* __restrict__ counts)
{
    const int base = blockIdx.x * NPB;
    const int r = threadIdx.x >> 6, c = threadIdx.x & 63;
    int curg = -1; float rs = 0.f, rm = -INFINITY; int rc = 0;
    const int vend = (base + NPB < NN) ? base + NPB : NN;
    for (int v = base + r; v < vend; v += 4) {
        const long idx = (long)v * 64 + c;
        const float val = fmaf(xn[idx], scale[c], shift[c]);
        xn[idx] = val;
        const int g = batch[v];
        if (g != curg) {
            if (curg >= 0) {
                atomicAdd(poolsum + curg * 64 + c, rs);
                atomicMax(poolmax + curg * 64 + c, fenc(rm));
                if (c == 0) atomicAdd(counts + curg, rc);
            }
            curg = g; rs = 0.f; rm = -INFINITY; rc = 0;
        }
        rs += val; rm = fmaxf(rm, val); ++rc;
    }
    if (curg >= 0) {
        atomicAdd(poolsum + curg * 64 + c, rs);
        atomicMax(poolmax + curg * 64 + c, fenc(rm));
        if (c == 0) atomicAdd(counts + curg, rc);
    }
}

// ---------------- final: x_graph + projector MLP + BN + out ----------------
__global__ __launch_bounds__(512) void final_kernel(
    const float* __restrict__ poolsum, const unsigned* __restrict__ poolmax,
    const int* __restrict__ counts,
    const float* __restrict__ p_w1, const float* __restrict__ p_b1,
    const float* __restrict__ p_bng, const float* __restrict__ p_bnb,
    const float* __restrict__ p_w2, const float* __restrict__ p_b2,
    float* __restrict__ out)
{
    __shared__ float xg[64][128];
    __shared__ float znl[64 * 129];
    __shared__ float red[2][512];
    __shared__ float scsh[2][128];
    const int tid = threadIdx.x;

    #pragma unroll
    for (int i = 0; i < 16; ++i) {
        const int e2 = tid + i * 512;
        const int g = e2 >> 7, col = e2 & 127;
        float val;
        if (col < 64) {
            const float cnt = fmaxf((float)counts[g], 1.f);
            val = poolsum[g * 64 + col] / cnt;
        } else {
            const unsigned u = poolmax[g * 64 + col - 64];
            val = (u == 0u) ? 0.f : fdec(u);
        }
        xg[g][col] = val;
        out[OUT_XG + e2] = val;
    }
    __syncthreads();

    const int gg = tid >> 7, t = tid & 127;
    float z[16];
    #pragma unroll
    for (int gi = 0; gi < 16; ++gi) z[gi] = p_b1[t];
    for (int j = 0; j < 128; ++j) {
        const float wv = p_w1[j * 128 + t];
        #pragma unroll
        for (int gi = 0; gi < 16; ++gi) z[gi] = fmaf(xg[gg * 16 + gi][j], wv, z[gi]);
    }

    float s = 0.f, ss = 0.f;
    #pragma unroll
    for (int gi = 0; gi < 16; ++gi) { s += z[gi]; ss += z[gi] * z[gi]; }
    red[0][tid] = s; red[1][tid] = ss;
    __syncthreads();
    if (gg == 0) {
        float S = 0.f, SS = 0.f;
        #pragma unroll
        for (int q = 0; q < 4; ++q) { S += red[0][t + q * 128]; SS += red[1][t + q * 128]; }
        const float mu = S / 64.f;
        const float var = SS / 64.f - mu * mu;
        const float sc = p_bng[t] * rsqrtf(var + BN_EPS);
        scsh[0][t] = sc;
        scsh[1][t] = p_bnb[t] - mu * sc;
    }
    __syncthreads();
    const float sc = scsh[0][t], sh = scsh[1][t];
    #pragma unroll
    for (int gi = 0; gi < 16; ++gi) {
        const float zn = fmaxf(fmaf(z[gi], sc, sh), 0.f);
        znl[(gg * 16 + gi) * 129 + t] = zn;
    }
    __syncthreads();

    float zp[16];
    #pragma unroll
    for (int gi = 0; gi < 16; ++gi) zp[gi] = p_b2[t];
    for (int c = 0; c < 128; ++c) {
        const float wv = p_w2[c * 128 + t];
        #pragma unroll
        for (int gi = 0; gi < 16; ++gi) zp[gi] = fmaf(znl[(gg * 16 + gi) * 129 + c], wv, zp[gi]);
    }
    #pragma unroll
    for (int gi = 0; gi < 16; ++gi) out[(gg * 16 + gi) * 128 + t] = zp[gi];
}

// ---------------- launch ----------------
extern "C" void kernel_launch(void* const* d_in, const int* in_sizes, int n_in,
                              void* d_out, int out_size, void* d_ws, size_t ws_size,
                              hipStream_t stream)
{
    const float* x     = (const float*)d_in[0];
    const int*   eidx  = (const int*)d_in[1];
    const int*   batch = (const int*)d_in[2];
    const float* c1w1  = (const float*)d_in[3];
    const float* c1b1  = (const float*)d_in[4];
    const float* c1w2  = (const float*)d_in[5];
    const float* c1b2  = (const float*)d_in[6];
    const float* bn1g  = (const float*)d_in[7];
    const float* bn1b  = (const float*)d_in[8];
    const float* c2w1  = (const float*)d_in[9];
    const float* c2b1  = (const float*)d_in[10];
    const float* c2w2  = (const float*)d_in[11];
    const float* c2b2  = (const float*)d_in[12];
    const float* bn2g  = (const float*)d_in[13];
    const float* bn2b  = (const float*)d_in[14];
    const float* pw1   = (const float*)d_in[15];
    const float* pb1   = (const float*)d_in[16];
    const float* pbng  = (const float*)d_in[17];
    const float* pbnb  = (const float*)d_in[18];
    const float* pw2   = (const float*)d_in[19];
    const float* pb2   = (const float*)d_in[20];

    const int* src = eidx;
    const int* dst = eidx + NE;

    float* ws  = (float*)d_ws;
    float* o   = (float*)d_out;
    float* h1  = ws + H1_OFF;
    float* xnode = o + OUT_XNODE;
    int* tab   = (int*)(ws + TAB_OFF);
    int2* ebin  = (int2*)(ws + H1_OFF);     // staging, lives before h1 is zeroed
    int2* sedge = (int2*)(ws + SEDG_OFF);
    unsigned short* wf1 = (unsigned short*)(ws + WF1_OFF);
    unsigned short* wf2 = (unsigned short*)(ws + WF2_OFF);
    int* recd  = (int*)(ws + RECD_OFF);
    float* recv = ws + RECV_OFF;
    unsigned short* Pb = (unsigned short*)(ws + P_OFF);
    unsigned short* Qb = (unsigned short*)(ws + Q_OFF);

    // weight prep (both convs)
    prep_weights<<<48, 256, 0, stream>>>(c1w1, c1w2, wf1);
    prep_weights<<<48, 256, 0, stream>>>(c2w1, c2w2, wf2);

    // two-level binned counting sort by dst -> sedge
    bin_hist_kernel<<<BINB, 256, 0, stream>>>(dst, tab);
    scan_tab_kernel<<<1, 1024, 0, stream>>>(tab);
    bin_scatter_kernel<<<BINB, 256, 0, stream>>>(src, dst, tab, ebin);
    bucket_sort_kernel<<<NBUK, 256, 0, stream>>>(ebin, tab, sedge);

    // zero accumulators (h1 AFTER sort: ebin staged in its region)
    hipMemsetAsync(h1, 0, (size_t)NN * 64 * 4, stream);
    hipMemsetAsync(xnode, 0, (size_t)NN * 64 * 4, stream);
    hipMemsetAsync(ws + PSUM_OFF, 0, (4096 + 4096 + 64) * 4, stream);

    const int ngGrid   = (NNTILES + 3) / 4;
    const int convGrid = (NTILES + 3) / 4;
    const int fixGrid  = (NREC + 3) / 4;

    // conv1: node GEMM (P,Q) then edge pass -> h1
    nodegemm_kernel<false><<<ngGrid, 256, 0, stream>>>(
        x, wf1, c1b1, nullptr, nullptr, Pb, Qb);
    edgeconv_kernel<<<convGrid, 256, 0, stream>>>(
        Pb, Qb, sedge, wf1 + 8192, c1b2, h1, recd, recv);
    fixup_kernel<<<fixGrid, 256, 0, stream>>>(recd, recv, h1);
    // BN1 stats
    stats_kernel<<<256, 256, 0, stream>>>(h1, ws + PART_OFF);
    bn_finalize_kernel<<<1, 256, 0, stream>>>(ws + PART_OFF, bn1g, bn1b,
                                              ws + SC1_OFF, ws + SH1_OFF);
    // conv2: node GEMM on normalized h1, then edge pass -> xnode
    nodegemm_kernel<true><<<ngGrid, 256, 0, stream>>>(
        h1, wf2, c2b1, ws + SC1_OFF, ws + SH1_OFF, Pb, Qb);
    edgeconv_kernel<<<convGrid, 256, 0, stream>>>(
        Pb, Qb, sedge, wf2 + 8192, c2b2, xnode, recd, recv);
    fixup_kernel<<<fixGrid, 256, 0, stream>>>(recd, recv, xnode);
    // BN2 stats
    stats_kernel<<<256, 256, 0, stream>>>(xnode, ws + PART_OFF);
    bn_finalize_kernel<<<1, 256, 0, stream>>>(ws + PART_OFF, bn2g, bn2b,
                                              ws + SC2_OFF, ws + SH2_OFF);
    // normalize x_node + pooling
    nodepass_kernel<<<(NN + NPB - 1) / NPB, 256, 0, stream>>>(
        xnode, batch, ws + SC2_OFF, ws + SH2_OFF,
        ws + PSUM_OFF, (unsigned*)(ws + PMAX_OFF), (int*)(ws + CNT_OFF));
    // x_graph + projector
    final_kernel<<<1, 512, 0, stream>>>(
        ws + PSUM_OFF, (unsigned*)(ws + PMAX_OFF), (int*)(ws + CNT_OFF),
        pw1, pb1, pbng, pbnb, pw2, pb2, o);
}

// Round 8
// 356.004 us; speedup vs baseline: 17.3321x; 1.1822x over previous
//
#include <hip/hip_runtime.h>
#include <hip/hip_fp16.h>

// ---------------- problem constants ----------------
constexpr int NN = 100000;   // nodes
constexpr int NE = 1000000;  // edges
constexpr int NG = 64;       // graphs
constexpr float BN_EPS = 1e-5f;
constexpr int NTILES = NE / 32;      // 31250 wave-tiles of 32 edges
constexpr int NNTILES = NN / 32;     // 3125 node tiles
constexpr int NREC = NTILES * 2;     // 62500 boundary records

// two-level binned counting sort (512-node buckets -> 196 blocks in pass D)
constexpr int NBUK = 196;            // buckets of 512 nodes (dst >> 9)
constexpr int BINB = 256;            // binning blocks
constexpr int BCHUNK = (NE + BINB - 1) / BINB;  // 3907 edges per block
constexpr int TABN = NBUK * BINB;    // 50176 scan-table entries

// ws layout (in floats)
constexpr long H1R_OFF  = 0;                       // [NN*64 f16] = 3.2M; first 2M = ebin staging
constexpr long XNR_OFF  = 3200000;                 // [NN*64 f16] = 3.2M
constexpr long PART_OFF = 6400000;                 // [256*128] BN stat partials
constexpr long SC1_OFF  = PART_OFF + 32768;        // [64]
constexpr long SH1_OFF  = SC1_OFF + 64;
constexpr long SC2_OFF  = SH1_OFF + 64;
constexpr long SH2_OFF  = SC2_OFF + 64;
constexpr long PSUM_OFF = SH2_OFF + 64;            // [64*64]
constexpr long PMAX_OFF = PSUM_OFF + 4096;         // [64*64]
constexpr long CNT_OFF  = PMAX_OFF + 4096;         // [64]
constexpr long TAB_OFF  = CNT_OFF + 64;            // [50176] bin scan table (int)
constexpr long SEDG_OFF = TAB_OFF + 50176;         // [NE int2] sorted (src,dst) = 2M floats
constexpr long WF1_OFF  = SEDG_OFF + 2000000;      // 12288 u16 = 6144 float slots
constexpr long WF2_OFF  = WF1_OFF + 6144;          // 12288 u16
constexpr long RECD_OFF = WF2_OFF + 6144;          // [62500] record dst (int), pad->62528
constexpr long RECV_OFF = RECD_OFF + 62528;        // [62500*32 u32 f16-pairs] = 2M floats
constexpr long P_OFF    = RECV_OFF + 2000000;      // [NN*64 f16] = 3.2M floats
constexpr long Q_OFF    = P_OFF + 3200000;         // [NN*64 f16]

// d_out layout (floats): z_proj [64*128] | x_node [NN*64] | x_graph [64*128]
constexpr long OUT_XNODE = 8192;
constexpr long OUT_XG    = 8192 + 6400000L;

using f16x8 = __attribute__((ext_vector_type(8))) _Float16;
using f32x16 = __attribute__((ext_vector_type(16))) float;

__device__ __forceinline__ unsigned short f2h(float f) {
    return __builtin_bit_cast(unsigned short, (_Float16)f);
}
__device__ __forceinline__ unsigned pkrtz(float a, float b) {
    return __builtin_bit_cast(unsigned, __builtin_amdgcn_cvt_pkrtz(a, b));
}
__device__ __forceinline__ unsigned pk_add_f16(unsigned a, unsigned b) {
    unsigned d;
    asm("v_pk_add_f16 %0, %1, %2" : "=v"(d) : "v"(a), "v"(b));
    return d;
}
__device__ __forceinline__ unsigned pk_max_f16(unsigned a, unsigned b) {
    unsigned d;
    asm("v_pk_max_f16 %0, %1, %2" : "=v"(d) : "v"(a), "v"(b));
    return d;
}
__device__ __forceinline__ float h2f_lo(unsigned u) {
    return (float)__builtin_bit_cast(_Float16, (unsigned short)(u & 0xffffu));
}
__device__ __forceinline__ float h2f_hi(unsigned u) {
    return (float)__builtin_bit_cast(_Float16, (unsigned short)(u >> 16));
}
__device__ __forceinline__ unsigned fenc(float f) {
    unsigned u = __float_as_uint(f);
    return (u & 0x80000000u) ? ~u : (u | 0x80000000u);
}
__device__ __forceinline__ float fdec(unsigned u) {
    return (u & 0x80000000u) ? __uint_as_float(u & 0x7fffffffu) : __uint_as_float(~u);
}
// bijective XCD-aware block swizzle (m204 variant)
__device__ __forceinline__ int xcd_swz(int bid, int nwg) {
    const int q = nwg >> 3, r = nwg & 7;
    const int x = bid & 7, i = bid >> 3;
    return (x < r ? x * (q + 1) : r * (q + 1) + (x - r) * q) + i;
}

// ---------------- two-level binned counting sort ----------------
__global__ __launch_bounds__(256) void bin_hist_kernel(
    const int* __restrict__ dst, int* __restrict__ tab)
{
    __shared__ int cnt[NBUK];
    const int t = threadIdx.x, b = blockIdx.x;
    if (t < NBUK) cnt[t] = 0;
    __syncthreads();
    const int lo = b * BCHUNK;
    const int hi = (lo + BCHUNK < NE) ? lo + BCHUNK : NE;
    for (int e = lo + t; e < hi; e += 256) atomicAdd(&cnt[dst[e] >> 9], 1);
    __syncthreads();
    if (t < NBUK) tab[t * BINB + b] = cnt[t];
}

__global__ __launch_bounds__(1024) void scan_tab_kernel(int* __restrict__ tab)
{
    __shared__ int part[1024];
    const int t = threadIdx.x;
    constexpr int VPT = 49;  // 1024*49 = 50176 = TABN
    int vals[VPT];
    const int base = t * VPT;
    int s = 0;
    #pragma unroll
    for (int i = 0; i < VPT; ++i) {
        const int idx = base + i;
        const int v = (idx < TABN) ? tab[idx] : 0;
        vals[i] = v; s += v;
    }
    part[t] = s;
    __syncthreads();
    for (int off = 1; off < 1024; off <<= 1) {
        const int u = (t >= off) ? part[t - off] : 0;
        __syncthreads();
        part[t] += u;
        __syncthreads();
    }
    int run = (t == 0) ? 0 : part[t - 1];
    #pragma unroll
    for (int i = 0; i < VPT; ++i) {
        const int idx = base + i;
        if (idx < TABN) { const int v = vals[i]; tab[idx] = run; run += v; }
    }
}

__global__ __launch_bounds__(256) void bin_scatter_kernel(
    const int* __restrict__ src, const int* __restrict__ dst,
    const int* __restrict__ tab, int2* __restrict__ ebin)
{
    __shared__ int basec[NBUK];
    __shared__ int cur[NBUK];
    const int t = threadIdx.x, b = blockIdx.x;
    if (t < NBUK) { basec[t] = tab[t * BINB + b]; cur[t] = 0; }
    __syncthreads();
    const int lo = b * BCHUNK;
    const int hi = (lo + BCHUNK < NE) ? lo + BCHUNK : NE;
    for (int e = lo + t; e < hi; e += 256) {
        const int d = dst[e];
        const int k = d >> 9;
        const int pos = basec[k] + atomicAdd(&cur[k], 1);
        ebin[pos] = make_int2(src[e], d);
    }
}

__global__ __launch_bounds__(256) void bucket_sort_kernel(
    const int2* __restrict__ ebin, const int* __restrict__ tab,
    int2* __restrict__ sedge)
{
    __shared__ int hist[512];
    __shared__ int part[256];
    const int t = threadIdx.x, k = blockIdx.x;
    const int start = tab[k * BINB];
    const int end = (k == NBUK - 1) ? NE : tab[(k + 1) * BINB];
    hist[t * 2] = 0; hist[t * 2 + 1] = 0;
    __syncthreads();
    for (int e = start + t; e < end; e += 256) atomicAdd(&hist[ebin[e].y & 511], 1);
    __syncthreads();
    const int v0 = hist[t * 2], v1 = hist[t * 2 + 1];
    part[t] = v0 + v1;
    __syncthreads();
    for (int off = 1; off < 256; off <<= 1) {
        const int u = (t >= off) ? part[t - off] : 0;
        __syncthreads();
        part[t] += u;
        __syncthreads();
    }
    int run = (t == 0) ? 0 : part[t - 1];
    hist[t * 2] = run;
    hist[t * 2 + 1] = run + v0;
    __syncthreads();
    for (int e = start + t; e < end; e += 256) {
        const int2 v = ebin[e];
        const int pos = start + atomicAdd(&hist[v.y & 511], 1);
        sedge[pos] = v;
    }
}

// ---------------- weight prep: fragment-ordered f16 ----------------
// sec 0: Wp = W1a - W1b (8 frags), sec 1: Wq = W1b (8), sec 2: W2 (8)
__global__ __launch_bounds__(256) void prep_weights(
    const float* __restrict__ w1, const float* __restrict__ w2,
    unsigned short* __restrict__ wf)
{
    const int idx = blockIdx.x * 256 + threadIdx.x;
    if (idx >= 12288) return;
    const int sec = idx >> 12;
    const int j = idx & 4095;
    const int f = j >> 9, rem = j & 511, ln = rem >> 3, i = rem & 7;
    const int t = f >> 2, ks = f & 3;
    const int k = ks * 16 + (ln >> 5) * 8 + i, c = t * 32 + (ln & 31);
    float v;
    if (sec == 0)      v = w1[k * 64 + c] - w1[(64 + k) * 64 + c];
    else if (sec == 1) v = w1[(64 + k) * 64 + c];
    else               v = w2[k * 64 + c];
    wf[idx] = f2h(v);
}

// ---------------- node GEMM: P = (W1a-W1b)x + b1, Q = W1b x  (f16 out) -------------
// NORM=false: xin is f32 [NN,64]; NORM=true: xin is f16 [NN,64] + scale/shift applied.
template<bool NORM>
__global__ __launch_bounds__(256) void nodegemm_kernel(
    const void* __restrict__ xin,
    const unsigned short* __restrict__ wfrag,
    const float* __restrict__ b1,
    const float* __restrict__ scale, const float* __restrict__ shift,
    unsigned short* __restrict__ P, unsigned short* __restrict__ Q)
{
    __shared__ unsigned short wlds[8192];
    {
        const uint4* wsrc = reinterpret_cast<const uint4*>(wfrag);
        uint4* wdst = reinterpret_cast<uint4*>(wlds);
        #pragma unroll
        for (int i = 0; i < 4; ++i) wdst[threadIdx.x + i * 256] = wsrc[threadIdx.x + i * 256];
    }
    __syncthreads();

    const int wid = threadIdx.x >> 6, lane = threadIdx.x & 63;
    const int hi = lane >> 5, ln32 = lane & 31;
    const int tile = blockIdx.x * 4 + wid;
    if (tile >= NNTILES) return;
    const int node = tile * 32 + ln32;

    f32x16 cpa, cpb, cqa, cqb;
    #pragma unroll
    for (int r = 0; r < 16; ++r) {
        const int row = (r & 3) + 8 * (r >> 2) + 4 * hi;
        cpa[r] = b1[row]; cpb[r] = b1[32 + row];
        cqa[r] = 0.f;     cqb[r] = 0.f;
    }

    #pragma unroll
    for (int ks = 0; ks < 4; ++ks) {
        const int off = ks * 16 + hi * 8;
        float4 a, b;
        if constexpr (!NORM) {
            const float* xr = reinterpret_cast<const float*>(xin) + (long)node * 64;
            a = *reinterpret_cast<const float4*>(xr + off);
            b = *reinterpret_cast<const float4*>(xr + off + 4);
        } else {
            const unsigned* xr = reinterpret_cast<const unsigned*>(xin) + (long)node * 32;
            const uint4 u = *reinterpret_cast<const uint4*>(xr + ks * 8 + hi * 4);
            a.x = h2f_lo(u.x); a.y = h2f_hi(u.x); a.z = h2f_lo(u.y); a.w = h2f_hi(u.y);
            b.x = h2f_lo(u.z); b.y = h2f_hi(u.z); b.z = h2f_lo(u.w); b.w = h2f_hi(u.w);
            const float4 s0 = *reinterpret_cast<const float4*>(scale + off);
            const float4 s1 = *reinterpret_cast<const float4*>(scale + off + 4);
            const float4 h0 = *reinterpret_cast<const float4*>(shift + off);
            const float4 h1 = *reinterpret_cast<const float4*>(shift + off + 4);
            a.x = fmaf(a.x, s0.x, h0.x); a.y = fmaf(a.y, s0.y, h0.y);
            a.z = fmaf(a.z, s0.z, h0.z); a.w = fmaf(a.w, s0.w, h0.w);
            b.x = fmaf(b.x, s1.x, h1.x); b.y = fmaf(b.y, s1.y, h1.y);
            b.z = fmaf(b.z, s1.z, h1.z); b.w = fmaf(b.w, s1.w, h1.w);
        }
        uint4 uu;
        uu.x = pkrtz(a.x, a.y); uu.y = pkrtz(a.z, a.w);
        uu.z = pkrtz(b.x, b.y); uu.w = pkrtz(b.z, b.w);
        const f16x8 bfr = __builtin_bit_cast(f16x8, uu);
        const f16x8 ap0 = *reinterpret_cast<const f16x8*>(&wlds[(0 * 4 + ks) * 512 + lane * 8]);
        const f16x8 ap1 = *reinterpret_cast<const f16x8*>(&wlds[(1 * 4 + ks) * 512 + lane * 8]);
        const f16x8 aq0 = *reinterpret_cast<const f16x8*>(&wlds[4096 + (0 * 4 + ks) * 512 + lane * 8]);
        const f16x8 aq1 = *reinterpret_cast<const f16x8*>(&wlds[4096 + (1 * 4 + ks) * 512 + lane * 8]);
        cpa = __builtin_amdgcn_mfma_f32_32x32x16_f16(ap0, bfr, cpa, 0, 0, 0);
        cpb = __builtin_amdgcn_mfma_f32_32x32x16_f16(ap1, bfr, cpb, 0, 0, 0);
        cqa = __builtin_amdgcn_mfma_f32_32x32x16_f16(aq0, bfr, cqa, 0, 0, 0);
        cqb = __builtin_amdgcn_mfma_f32_32x32x16_f16(aq1, bfr, cqb, 0, 0, 0);
    }

    unsigned short* Pr = P + (long)node * 64;
    unsigned short* Qr = Q + (long)node * 64;
    #pragma unroll
    for (int t = 0; t < 2; ++t) {
        const f32x16 cp = t ? cpb : cpa;
        const f32x16 cq = t ? cqb : cqa;
        #pragma unroll
        for (int g2 = 0; g2 < 4; ++g2) {
            uint2 up, uq;
            up.x = pkrtz(cp[4 * g2 + 0], cp[4 * g2 + 1]);
            up.y = pkrtz(cp[4 * g2 + 2], cp[4 * g2 + 3]);
            uq.x = pkrtz(cq[4 * g2 + 0], cq[4 * g2 + 1]);
            uq.y = pkrtz(cq[4 * g2 + 2], cq[4 * g2 + 3]);
            const int co = t * 32 + 8 * g2 + 4 * hi;
            *reinterpret_cast<uint2*>(Pr + co) = up;
            *reinterpret_cast<uint2*>(Qr + co) = uq;
        }
    }
}

// ---------------- EdgeConv layer-2: wave = 32 sorted edges, f16 output ------------
__global__ __launch_bounds__(256) void edgeconv_kernel(
    const unsigned short* __restrict__ P, const unsigned short* __restrict__ Q,
    const int2* __restrict__ sedge,
    const unsigned short* __restrict__ w2frag,
    const float* __restrict__ b2,
    unsigned* __restrict__ out,              // [NN][32] f16-pair dwords
    int* __restrict__ recd, unsigned* __restrict__ recv)  // recv [NREC][32]
{
    __shared__ unsigned short wlds[4096];
    {
        const uint4* wsrc = reinterpret_cast<const uint4*>(w2frag);
        uint4* wdst = reinterpret_cast<uint4*>(wlds);
        #pragma unroll
        for (int i = 0; i < 2; ++i) wdst[threadIdx.x + i * 256] = wsrc[threadIdx.x + i * 256];
    }
    __syncthreads();

    const int wid  = threadIdx.x >> 6;
    const int lane = threadIdx.x & 63;
    const int hi   = lane >> 5;
    const int ln32 = lane & 31;
    const int tile = xcd_swz(blockIdx.x, gridDim.x) * 4 + wid;  // XCD-chunked for P L2 locality
    if (tile >= NTILES) return;

    const int2 sd = sedge[tile * 32 + ln32];
    const int s = sd.x, d = sd.y;
    const unsigned short* __restrict__ Pr = P + (long)d * 64;
    const unsigned short* __restrict__ Qr = Q + (long)s * 64;

    f32x16 c2a, c2b;
    #pragma unroll
    for (int r = 0; r < 16; ++r) {
        const int row = (r & 3) + 8 * (r >> 2) + 4 * hi;
        c2a[r] = b2[row];
        c2b[r] = b2[32 + row];
    }

    #pragma unroll
    for (int ks = 0; ks < 4; ++ks) {
        const int co = ks * 16 + hi * 8;
        const uint4 pu = *reinterpret_cast<const uint4*>(Pr + co);
        const uint4 qu = *reinterpret_cast<const uint4*>(Qr + co);
        uint4 hh;   // relu(P+Q) in packed f16
        hh.x = pk_max_f16(pk_add_f16(pu.x, qu.x), 0u);
        hh.y = pk_max_f16(pk_add_f16(pu.y, qu.y), 0u);
        hh.z = pk_max_f16(pk_add_f16(pu.z, qu.z), 0u);
        hh.w = pk_max_f16(pk_add_f16(pu.w, qu.w), 0u);
        const f16x8 bfr = __builtin_bit_cast(f16x8, hh);
        const f16x8 a0 = *reinterpret_cast<const f16x8*>(&wlds[(0 * 4 + ks) * 512 + lane * 8]);
        const f16x8 a1 = *reinterpret_cast<const f16x8*>(&wlds[(1 * 4 + ks) * 512 + lane * 8]);
        c2a = __builtin_amdgcn_mfma_f32_32x32x16_f16(a0, bfr, c2a, 0, 0, 0);
        c2b = __builtin_amdgcn_mfma_f32_32x32x16_f16(a1, bfr, c2b, 0, 0, 0);
    }

    // relu + pack to 16 f16-pair dwords
    unsigned pkc[16];
    #pragma unroll
    for (int q = 0; q < 8; ++q) {
        pkc[q]     = pk_max_f16(pkrtz(c2a[2 * q], c2a[2 * q + 1]), 0u);
        pkc[8 + q] = pk_max_f16(pkrtz(c2b[2 * q], c2b[2 * q + 1]), 0u);
    }

    // segmented max over edges within each 32-lane half (keys = d, sorted)
    #pragma unroll
    for (int st = 1; st < 32; st <<= 1) {
        const int dn = __shfl_down(d, st, 32);
        const bool take = (ln32 + st < 32) && (dn == d);
        #pragma unroll
        for (int i = 0; i < 16; ++i) {
            const unsigned o = __shfl_down(pkc[i], st, 32);
            const unsigned m = pk_max_f16(pkc[i], o);
            pkc[i] = take ? m : pkc[i];
        }
    }
    const int dprev = __shfl_up(d, 1, 32);
    const bool leader = (ln32 == 0) || (d != dprev);
    const unsigned lm = (unsigned)(__ballot(leader) & 0xffffffffull);
    const int L31 = 31 - __builtin_clz(lm);

    if (leader) {
        // dword layout: c2a pair (2g2, 2g2+1) -> dwords 4g2+2hi..+1; c2b -> +16
        if (ln32 != 0 && ln32 != L31) {
            unsigned* row = out + (long)d * 32;
            #pragma unroll
            for (int g2 = 0; g2 < 4; ++g2) {
                *reinterpret_cast<uint2*>(row + 4 * g2 + 2 * hi) =
                    make_uint2(pkc[2 * g2], pkc[2 * g2 + 1]);
                *reinterpret_cast<uint2*>(row + 16 + 4 * g2 + 2 * hi) =
                    make_uint2(pkc[8 + 2 * g2], pkc[8 + 2 * g2 + 1]);
            }
        }
        if (ln32 == 0) {
            unsigned* row = recv + (long)(tile * 2) * 32;
            #pragma unroll
            for (int g2 = 0; g2 < 4; ++g2) {
                *reinterpret_cast<uint2*>(row + 4 * g2 + 2 * hi) =
                    make_uint2(pkc[2 * g2], pkc[2 * g2 + 1]);
                *reinterpret_cast<uint2*>(row + 16 + 4 * g2 + 2 * hi) =
                    make_uint2(pkc[8 + 2 * g2], pkc[8 + 2 * g2 + 1]);
            }
            if (hi == 0) recd[tile * 2] = d;
        }
        if (ln32 == L31) {
            unsigned* row = recv + (long)(tile * 2 + 1) * 32;
            #pragma unroll
            for (int g2 = 0; g2 < 4; ++g2) {
                *reinterpret_cast<uint2*>(row + 4 * g2 + 2 * hi) =
                    make_uint2(pkc[2 * g2], pkc[2 * g2 + 1]);
                *reinterpret_cast<uint2*>(row + 16 + 4 * g2 + 2 * hi) =
                    make_uint2(pkc[8 + 2 * g2], pkc[8 + 2 * g2 + 1]);
            }
            if (hi == 0) recd[tile * 2 + 1] = d;
        }
    }
}

// ---------------- fixup: combine boundary records, 2 records per wave -------------
__global__ __launch_bounds__(256) void fixup_kernel(
    const int* __restrict__ recd, const unsigned* __restrict__ recv,
    unsigned* __restrict__ out)
{
    const int wid = threadIdx.x >> 6;
    const int half = (threadIdx.x >> 5) & 1;
    const int c2 = threadIdx.x & 31;
    const int r = blockIdx.x * 8 + wid * 2 + half;
    if (r >= NREC) return;
    const int d = recd[r];
    int lo = r, hi = r;
    while (lo > 0 && recd[lo - 1] == d) --lo;
    while (hi + 1 < NREC && recd[hi + 1] == d) ++hi;
    unsigned m = 0u;   // relu outputs >= 0 -> packed {+0,+0} identity
    for (int rr = lo; rr <= hi; ++rr) m = pk_max_f16(m, recv[(long)rr * 32 + c2]);
    out[(long)d * 32 + c2] = m;
}

// ---------------- BN stats over f16 rows: deterministic two-stage -----------------
__global__ __launch_bounds__(256) void stats_kernel(
    const unsigned* __restrict__ h, float* __restrict__ partial)
{
    __shared__ float red[4][256];
    const int tid = threadIdx.x;
    const int c2 = tid & 31, r = tid >> 5;   // 8 rows in flight
    float s0 = 0.f, ss0 = 0.f, s1 = 0.f, ss1 = 0.f;
    for (int v = blockIdx.x * 8 + r; v < NN; v += 256 * 8) {
        const unsigned u = h[(long)v * 32 + c2];
        const float a = h2f_lo(u), b = h2f_hi(u);
        s0 += a; ss0 += a * a; s1 += b; ss1 += b * b;
    }
    red[0][tid] = s0; red[1][tid] = ss0; red[2][tid] = s1; red[3][tid] = ss1;
    __syncthreads();
    if (r == 0) {
        float S0 = 0.f, SS0 = 0.f, S1 = 0.f, SS1 = 0.f;
        #pragma unroll
        for (int q = 0; q < 8; ++q) {
            S0 += red[0][c2 + q * 32]; SS0 += red[1][c2 + q * 32];
            S1 += red[2][c2 + q * 32]; SS1 += red[3][c2 + q * 32];
        }
        partial[blockIdx.x * 128 + 2 * c2]     = S0;
        partial[blockIdx.x * 128 + 2 * c2 + 1] = S1;
        partial[blockIdx.x * 128 + 64 + 2 * c2]     = SS0;
        partial[blockIdx.x * 128 + 64 + 2 * c2 + 1] = SS1;
    }
}

__global__ __launch_bounds__(256) void bn_finalize_kernel(
    const float* __restrict__ partial,
    const float* __restrict__ g, const float* __restrict__ b,
    float* __restrict__ scale, float* __restrict__ shift)
{
    __shared__ float red[2][256];
    const int tid = threadIdx.x;
    const int c = tid & 63, q = tid >> 6;   // 4 threads per channel
    float S = 0.f, SS = 0.f;
    for (int bb = q * 64; bb < q * 64 + 64; ++bb) {
        S += partial[bb * 128 + c];
        SS += partial[bb * 128 + 64 + c];
    }
    red[0][tid] = S; red[1][tid] = SS;
    __syncthreads();
    if (q == 0) {
        #pragma unroll
        for (int p = 1; p < 4; ++p) { S += red[0][c + p * 64]; SS += red[1][c + p * 64]; }
        const float invN = 1.0f / (float)NN;
        const float mu = S * invN;
        const float var = SS * invN - mu * mu;
        const float sc = g[c] * rsqrtf(var + BN_EPS);
        scale[c] = sc;
        shift[c] = b[c] - mu * sc;
    }
}

// ---------------- node pass: BN2 normalize f16->f32 + segmented pooling -----------
constexpr int NPB = 512;
__global__ __launch_bounds__(256) void nodepass_kernel(
    const unsigned* __restrict__ xnr, float* __restrict__ xn,
    const int* __restrict__ batch,
    const float* __restrict__ scale, const float* __restrict__ shift,
    float* __restrict__ poolsum, unsigned* __restrict__ poolmax, int* __restrict__ counts)
{
    const int base = blockIdx.x * NPB;
    const int r = threadIdx.x >> 5, c2 = threadIdx.x & 31;   // 8 rows x 32 dwords
    const float sc0 = scale[2 * c2], sc1 = scale[2 * c2 + 1];
    const float sh0 = shift[2 * c2], sh1 = shift[2 * c2 + 1];
    int curg = -1; float rs0 = 0.f, rs1 = 0.f, rm0 = -INFINITY, rm1 = -INFINITY; int rc = 0;
    const int vend = (base + NPB < NN) ? base + NPB : NN;
    for (int v = base + r; v < vend; v += 8) {
        const unsigned u = xnr[(long)v * 32 + c2];
        const float v0 = fmaf(h2f_lo(u), sc0, sh0);
        const float v1 = fmaf(h2f_hi(u), sc1, sh1);
        *reinterpret_cast<float2*>(xn + (long)v * 64 + 2 * c2) = make_float2(v0, v1);
        const int g = batch[v];
        if (g != curg) {
            if (curg >= 0) {
                atomicAdd(poolsum + curg * 64 + 2 * c2, rs0);
                atomicAdd(poolsum + curg * 64 + 2 * c2 + 1, rs1);
                atomicMax(poolmax + curg * 64 + 2 * c2, fenc(rm0));
                atomicMax(poolmax + curg * 64 + 2 * c2 + 1, fenc(rm1));
                if (c2 == 0) atomicAdd(counts + curg, rc);
            }
            curg = g; rs0 = rs1 = 0.f; rm0 = rm1 = -INFINITY; rc = 0;
        }
        rs0 += v0; rs1 += v1; rm0 = fmaxf(rm0, v0); rm1 = fmaxf(rm1, v1); ++rc;
    }
    if (curg >= 0) {
        atomicAdd(poolsum + curg * 64 + 2 * c2, rs0);
        atomicAdd(poolsum + curg * 64 + 2 * c2 + 1, rs1);
        atomicMax(poolmax + curg * 64 + 2 * c2, fenc(rm0));
        atomicMax(poolmax + curg * 64 + 2 * c2 + 1, fenc(rm1));
        if (c2 == 0) atomicAdd(counts + curg, rc);
    }
}

// ---------------- final: x_graph + projector MLP + BN + out ----------------
__global__ __launch_bounds__(512) void final_kernel(
    const float* __restrict__ poolsum, const unsigned* __restrict__ poolmax,
    const int* __restrict__ counts,
    const float* __restrict__ p_w1, const float* __restrict__ p_b1,
    const float* __restrict__ p_bng, const float* __restrict__ p_bnb,
    const float* __restrict__ p_w2, const float* __restrict__ p_b2,
    float* __restrict__ out)
{
    __shared__ float xg[64][128];
    __shared__ float znl[64 * 129];
    __shared__ float red[2][512];
    __shared__ float scsh[2][128];
    const int tid = threadIdx.x;

    #pragma unroll
    for (int i = 0; i < 16; ++i) {
        const int e2 = tid + i * 512;
        const int g = e2 >> 7, col = e2 & 127;
        float val;
        if (col < 64) {
            const float cnt = fmaxf((float)counts[g], 1.f);
            val = poolsum[g * 64 + col] / cnt;
        } else {
            const unsigned u = poolmax[g * 64 + col - 64];
            val = (u == 0u) ? 0.f : fdec(u);
        }
        xg[g][col] = val;
        out[OUT_XG + e2] = val;
    }
    __syncthreads();

    const int gg = tid >> 7, t = tid & 127;
    float z[16];
    #pragma unroll
    for (int gi = 0; gi < 16; ++gi) z[gi] = p_b1[t];
    for (int j = 0; j < 128; ++j) {
        const float wv = p_w1[j * 128 + t];
        #pragma unroll
        for (int gi = 0; gi < 16; ++gi) z[gi] = fmaf(xg[gg * 16 + gi][j], wv, z[gi]);
    }

    float s = 0.f, ss = 0.f;
    #pragma unroll
    for (int gi = 0; gi < 16; ++gi) { s += z[gi]; ss += z[gi] * z[gi]; }
    red[0][tid] = s; red[1][tid] = ss;
    __syncthreads();
    if (gg == 0) {
        float S = 0.f, SS = 0.f;
        #pragma unroll
        for (int q = 0; q < 4; ++q) { S += red[0][t + q * 128]; SS += red[1][t + q * 128]; }
        const float mu = S / 64.f;
        const float var = SS / 64.f - mu * mu;
        const float sc = p_bng[t] * rsqrtf(var + BN_EPS);
        scsh[0][t] = sc;
        scsh[1][t] = p_bnb[t] - mu * sc;
    }
    __syncthreads();
    const float sc = scsh[0][t], sh = scsh[1][t];
    #pragma unroll
    for (int gi = 0; gi < 16; ++gi) {
        const float zn = fmaxf(fmaf(z[gi], sc, sh), 0.f);
        znl[(gg * 16 + gi) * 129 + t] = zn;
    }
    __syncthreads();

    float zp[16];
    #pragma unroll
    for (int gi = 0; gi < 16; ++gi) zp[gi] = p_b2[t];
    for (int c = 0; c < 128; ++c) {
        const float wv = p_w2[c * 128 + t];
        #pragma unroll
        for (int gi = 0; gi < 16; ++gi) zp[gi] = fmaf(znl[(gg * 16 + gi) * 129 + c], wv, zp[gi]);
    }
    #pragma unroll
    for (int gi = 0; gi < 16; ++gi) out[(gg * 16 + gi) * 128 + t] = zp[gi];
}

// ---------------- launch ----------------
extern "C" void kernel_launch(void* const* d_in, const int* in_sizes, int n_in,
                              void* d_out, int out_size, void* d_ws, size_t ws_size,
                              hipStream_t stream)
{
    const float* x     = (const float*)d_in[0];
    const int*   eidx  = (const int*)d_in[1];
    const int*   batch = (const int*)d_in[2];
    const float* c1w1  = (const float*)d_in[3];
    const float* c1b1  = (const float*)d_in[4];
    const float* c1w2  = (const float*)d_in[5];
    const float* c1b2  = (const float*)d_in[6];
    const float* bn1g  = (const float*)d_in[7];
    const float* bn1b  = (const float*)d_in[8];
    const float* c2w1  = (const float*)d_in[9];
    const float* c2b1  = (const float*)d_in[10];
    const float* c2w2  = (const float*)d_in[11];
    const float* c2b2  = (const float*)d_in[12];
    const float* bn2g  = (const float*)d_in[13];
    const float* bn2b  = (const float*)d_in[14];
    const float* pw1   = (const float*)d_in[15];
    const float* pb1   = (const float*)d_in[16];
    const float* pbng  = (const float*)d_in[17];
    const float* pbnb  = (const float*)d_in[18];
    const float* pw2   = (const float*)d_in[19];
    const float* pb2   = (const float*)d_in[20];

    const int* src = eidx;
    const int* dst = eidx + NE;

    float* ws  = (float*)d_ws;
    float* o   = (float*)d_out;
    unsigned* h1r = (unsigned*)(ws + H1R_OFF);   // f16 rows as dwords
    unsigned* xnr = (unsigned*)(ws + XNR_OFF);
    float* xnode = o + OUT_XNODE;
    int* tab   = (int*)(ws + TAB_OFF);
    int2* ebin  = (int2*)(ws + H1R_OFF);    // staging, consumed before h1r memset
    int2* sedge = (int2*)(ws + SEDG_OFF);
    unsigned short* wf1 = (unsigned short*)(ws + WF1_OFF);
    unsigned short* wf2 = (unsigned short*)(ws + WF2_OFF);
    int* recd  = (int*)(ws + RECD_OFF);
    unsigned* recv = (unsigned*)(ws + RECV_OFF);
    unsigned short* Pb = (unsigned short*)(ws + P_OFF);
    unsigned short* Qb = (unsigned short*)(ws + Q_OFF);

    // weight prep (both convs)
    prep_weights<<<48, 256, 0, stream>>>(c1w1, c1w2, wf1);
    prep_weights<<<48, 256, 0, stream>>>(c2w1, c2w2, wf2);

    // two-level binned counting sort by dst -> sedge
    bin_hist_kernel<<<BINB, 256, 0, stream>>>(dst, tab);
    scan_tab_kernel<<<1, 1024, 0, stream>>>(tab);
    bin_scatter_kernel<<<BINB, 256, 0, stream>>>(src, dst, tab, ebin);
    bucket_sort_kernel<<<NBUK, 256, 0, stream>>>(ebin, tab, sedge);

    // zero f16 accumulators (AFTER sort: ebin staged in h1r region) + pools
    hipMemsetAsync(h1r, 0, (size_t)NN * 64 * 2, stream);
    hipMemsetAsync(xnr, 0, (size_t)NN * 64 * 2, stream);
    hipMemsetAsync(ws + PSUM_OFF, 0, (4096 + 4096 + 64) * 4, stream);

    const int ngGrid   = (NNTILES + 3) / 4;
    const int convGrid = (NTILES + 3) / 4;
    const int fixGrid  = (NREC + 7) / 8;

    // conv1: node GEMM (P,Q) then edge pass -> h1r (f16)
    nodegemm_kernel<false><<<ngGrid, 256, 0, stream>>>(
        x, wf1, c1b1, nullptr, nullptr, Pb, Qb);
    edgeconv_kernel<<<convGrid, 256, 0, stream>>>(
        Pb, Qb, sedge, wf1 + 8192, c1b2, h1r, recd, recv);
    fixup_kernel<<<fixGrid, 256, 0, stream>>>(recd, recv, h1r);
    // BN1 stats
    stats_kernel<<<256, 256, 0, stream>>>(h1r, ws + PART_OFF);
    bn_finalize_kernel<<<1, 256, 0, stream>>>(ws + PART_OFF, bn1g, bn1b,
                                              ws + SC1_OFF, ws + SH1_OFF);
    // conv2: node GEMM on normalized h1r (f16 in), edge pass -> xnr (f16)
    nodegemm_kernel<true><<<ngGrid, 256, 0, stream>>>(
        h1r, wf2, c2b1, ws + SC1_OFF, ws + SH1_OFF, Pb, Qb);
    edgeconv_kernel<<<convGrid, 256, 0, stream>>>(
        Pb, Qb, sedge, wf2 + 8192, c2b2, xnr, recd, recv);
    fixup_kernel<<<fixGrid, 256, 0, stream>>>(recd, recv, xnr);
    // BN2 stats
    stats_kernel<<<256, 256, 0, stream>>>(xnr, ws + PART_OFF);
    bn_finalize_kernel<<<1, 256, 0, stream>>>(ws + PART_OFF, bn2g, bn2b,
                                              ws + SC2_OFF, ws + SH2_OFF);
    // normalize xnr -> x_node (f32, d_out) + pooling
    nodepass_kernel<<<(NN + NPB - 1) / NPB, 256, 0, stream>>>(
        xnr, xnode, batch, ws + SC2_OFF, ws + SH2_OFF,
        ws + PSUM_OFF, (unsigned*)(ws + PMAX_OFF), (int*)(ws + CNT_OFF));
    // x_graph + projector
    final_kernel<<<1, 512, 0, stream>>>(
        ws + PSUM_OFF, (unsigned*)(ws + PMAX_OFF), (int*)(ws + CNT_OFF),
        pw1, pb1, pbng, pbnb, pw2, pb2, o);
}